// Round 1
// 536.314 us; speedup vs baseline: 1.0808x; 1.0808x over previous
//
#include <hip/hip_runtime.h>
#include <hip/hip_bf16.h>

// DCSA block, round 11: launch-graph merge. The two mconvs, the two
// self-attention pipelines (ln/qkv-gemm/attn/proj-gemm/ln), and the three
// cross-attn projection GEMMs are mutually independent but each runs at only
// ~2 blocks/CU (19% occupancy, MfmaUtil 14%). Merge them via blockIdx.z
// dispatch into single launches to double/triple resident waves and cut
// launch count 28 -> 17. Kernel math is unchanged from the verified r10.

using bf16 = __hip_bfloat16;
typedef short v8s __attribute__((ext_vector_type(8)));
typedef float v4f  __attribute__((ext_vector_type(4)));

static __device__ __forceinline__ float bf2f(bf16 x) { return __bfloat162float(x); }
static __device__ __forceinline__ float us2f(unsigned short u)
{ union { unsigned int i; float f; } x; x.i = ((unsigned)u) << 16; return x.f; }
static __device__ __forceinline__ unsigned short f2us(float f)
{ bf16 h = __float2bfloat16(f); return *(unsigned short*)&h; }
static __device__ __forceinline__ float ldi(const void* p, size_t i, int isbf)
{ return isbf ? bf2f(((const bf16*)p)[i]) : ((const float*)p)[i]; }

// ---------------------------------------------------------------------------
__global__ void detect_kernel(const unsigned short* p, int* flag)
{
    if (threadIdx.x == 0 && blockIdx.x == 0)
        *flag = (p[0] == 0x3F80) ? 1 : 0;
}

// ---------------------------------------------------------------------------
struct CvtArgs { const void* src[20]; unsigned off[21]; };

__global__ __launch_bounds__(256) void cvt_lin(CvtArgs a, const int* __restrict__ flag,
                                               bf16* __restrict__ dst)
{
    unsigned e = blockIdx.x * 256u + threadIdx.x;
    int isbf = *flag;
    int s = 0;
    while (e >= a.off[s + 1]) ++s;
    dst[e] = __float2bfloat16(ldi(a.src[s], e - a.off[s], isbf));
}

// ---------------------------------------------------------------------------
// merged NCHW->NHWC transpose for both feature maps (z<8: aop, z>=8: dop)
__global__ __launch_bounds__(256) void tcvt2(const void* __restrict__ s0,
                                             const void* __restrict__ s1,
                                             const int* __restrict__ flag,
                                             bf16* __restrict__ d0,
                                             bf16* __restrict__ d1)
{
    __shared__ float T[64][65];
    const void* src = (blockIdx.z < 8) ? s0 : s1;
    bf16* dst       = (blockIdx.z < 8) ? d0 : d1;
    int hw0 = blockIdx.x * 64, c0 = blockIdx.y * 64, b = blockIdx.z & 7;
    int t = threadIdx.x, isbf = *flag;
    int c = t >> 2, x16 = (t & 3) * 16;
    size_t sbase = ((size_t)b * 256 + c0 + c) * 1024 + hw0 + x16;
#pragma unroll
    for (int j = 0; j < 16; ++j) T[c][x16 + j] = ldi(src, sbase + j, isbf);
    __syncthreads();
    int hw = t >> 2, c16 = (t & 3) * 16;
    bf16* dp = dst + ((size_t)(b << 10) + hw0 + hw) * 256 + c0 + c16;
#pragma unroll
    for (int j = 0; j < 16; ++j) dp[j] = __float2bfloat16(T[c16 + j][hw]);
}

// ---------------------------------------------------------------------------
// merged weight repack: conv3 (589824) + conv5 (1638400) + dw (9216)
__global__ __launch_bounds__(256) void repack_all(
    const void* __restrict__ W3, const void* __restrict__ W5,
    const void* __restrict__ Wdw, const int* __restrict__ flag,
    bf16* __restrict__ R3, bf16* __restrict__ R5, bf16* __restrict__ Rdw)
{
    int idx = blockIdx.x * 256 + threadIdx.x;
    int isbf = *flag;
    if (idx < 589824) {
        int ci = idx & 255, o = (idx >> 8) & 255, khkw = idx >> 16;
        int kh = khkw / 3, kw = khkw % 3;
        R3[idx] = __float2bfloat16(
            ldi(W3, (((size_t)o * 256 + ci) * 3 + kh) * 3 + kw, isbf));
    } else if (idx < 2228224) {
        int j = idx - 589824;
        int ci = j & 255, o = (j >> 8) & 255, khkw = j >> 16;
        int kh = khkw / 5, kw = khkw % 5;
        R5[j] = __float2bfloat16(
            ldi(W5, (((size_t)o * 256 + ci) * 5 + kh) * 5 + kw, isbf));
    } else {
        int j = idx - 2228224;
        int c = j & 1023, tap = j >> 10;
        Rdw[j] = __float2bfloat16(ldi(Wdw, (size_t)c * 9 + tap, isbf));
    }
}

// ---------------------------------------------------------------------------
// MFMA GEMM core, 64x64 tile, BK=64, 4 waves, register-prefetch pipeline.
// MA:[M][K], MB:[N][K] k-contig.
// modes: 0 NHWC(+R) / 1 CHW / 2 CHW-fp32+R / 3 qkv-split / 4 QK col-offset
// ---------------------------------------------------------------------------
static __device__ __forceinline__ void mgemm_core(
    const short* __restrict__ MA, const short* __restrict__ MB,
    bf16* __restrict__ Yb, float* __restrict__ Yf, bf16* __restrict__ Y2,
    const bf16* __restrict__ R, int K, int mode, int Ochan,
    short As[64][72], short Bs[64][72])
{
    int m0 = blockIdx.x * 64, n0 = blockIdx.y * 64;
    int t = threadIdx.x, lane = t & 63, wv = t >> 6;
    int l15 = lane & 15, quad = lane >> 4;
    int srow = t >> 2, scol = (t & 3) * 16;

    const short* pa = &MA[(size_t)(m0 + srow) * K + scol];
    const short* pb = &MB[(size_t)(n0 + srow) * K + scol];

    v4f acc[4] = {};
    v8s ra0 = *(const v8s*)&pa[0], ra1 = *(const v8s*)&pa[8];
    v8s rb0 = *(const v8s*)&pb[0], rb1 = *(const v8s*)&pb[8];

    for (int k0 = 0; k0 < K; k0 += 64) {
        if (k0) __syncthreads();
        *(v8s*)&As[srow][scol]     = ra0;
        *(v8s*)&As[srow][scol + 8] = ra1;
        *(v8s*)&Bs[srow][scol]     = rb0;
        *(v8s*)&Bs[srow][scol + 8] = rb1;
        __syncthreads();
        if (k0 + 64 < K) {
            ra0 = *(const v8s*)&pa[k0 + 64];
            ra1 = *(const v8s*)&pa[k0 + 72];
            rb0 = *(const v8s*)&pb[k0 + 64];
            rb1 = *(const v8s*)&pb[k0 + 72];
        }
#pragma unroll
        for (int kk = 0; kk < 2; ++kk) {
            v8s a = *(const v8s*)&As[wv * 16 + l15][kk * 32 + quad * 8];
#pragma unroll
            for (int nt = 0; nt < 4; ++nt) {
                v8s b = *(const v8s*)&Bs[nt * 16 + l15][kk * 32 + quad * 8];
                acc[nt] = __builtin_amdgcn_mfma_f32_16x16x32_bf16(a, b, acc[nt], 0, 0, 0);
            }
        }
    }

#pragma unroll
    for (int nt = 0; nt < 4; ++nt)
#pragma unroll
        for (int r = 0; r < 4; ++r) {
            int mm = m0 + wv * 16 + quad * 4 + r;
            int nn = n0 + nt * 16 + l15;
            float v = acc[nt][r];
            if (mode == 0) {
                size_t off = (size_t)mm * Ochan + nn;
                if (R) v += bf2f(R[off]);
                Yb[off] = __float2bfloat16(v);
            } else if (mode == 1) {
                Yb[((size_t)(nn >> 10) * Ochan + mm) * 1024 + (nn & 1023)] =
                    __float2bfloat16(v);
            } else if (mode == 2) {
                Yf[((size_t)(nn >> 10) * Ochan + mm) * 1024 + (nn & 1023)] =
                    v + bf2f(R[(size_t)nn * 256 + mm]);
            } else if (mode == 3) {
                if (mm < 512) Yb[(size_t)nn * 512 + mm] = __float2bfloat16(v);
                else Y2[((size_t)(nn >> 10) * 256 + (mm - 512)) * 1024 + (nn & 1023)] =
                         __float2bfloat16(v);
            } else {
                Yb[(size_t)nn * 512 + Ochan + mm] = __float2bfloat16(v);
            }
        }
}

__global__ __launch_bounds__(256) void mgemm(
    const short* __restrict__ MA, const short* __restrict__ MB,
    bf16* __restrict__ Yb, float* __restrict__ Yf, bf16* __restrict__ Y2,
    const bf16* __restrict__ R, int K, int mode, int Ochan)
{
    __shared__ short As[64][72], Bs[64][72];
    mgemm_core(MA, MB, Yb, Yf, Y2, R, K, mode, Ochan, As, Bs);
}

// z-dispatched merged GEMM (up to 3 independent problems, same x/y grid)
struct GA { const short* A; const short* B; bf16* Yb; float* Yf; bf16* Y2;
            const bf16* R; int K; int mode; int Oc; };
struct GA3 { GA g[3]; };

__global__ __launch_bounds__(256) void mgemm_z(GA3 P)
{
    __shared__ short As[64][72], Bs[64][72];
    const GA& a = P.g[blockIdx.z];
    mgemm_core(a.A, a.B, a.Yb, a.Yf, a.Y2, a.R, a.K, a.mode, a.Oc, As, Bs);
}

// ---------------------------------------------------------------------------
// MFMA conv core, same 64x64 / BK=64 prefetch skeleton, im2col A staging.
// ---------------------------------------------------------------------------
template <int KS, int PAD>
static __device__ __forceinline__ void mconv_core(
    const short* __restrict__ Xn, const short* __restrict__ Wr,
    bf16* __restrict__ Y, short As[64][72], short Bs[64][72])
{
    const int K = 256 * KS * KS;
    int p0 = blockIdx.x * 64, o0 = blockIdx.y * 64;
    int t = threadIdx.x, lane = t & 63, wv = t >> 6;
    int l15 = lane & 15, quad = lane >> 4;
    int srow = t >> 2, scol = (t & 3) * 16;

    int p  = p0 + srow;
    int hw = p & 1023, hh = hw >> 5, ww = hw & 31;
    size_t ib = ((size_t)(p >> 10)) << 10;

    v4f acc[4] = {};
    v8s ra0, ra1, rb0, rb1;

    {
        int hi = hh - PAD, wi = ww - PAD;
        v8s z = {0, 0, 0, 0, 0, 0, 0, 0};
        ra0 = z; ra1 = z;
        if ((unsigned)hi < 32u && (unsigned)wi < 32u) {
            const short* sa = &Xn[(ib + (hi << 5) + wi) * 256 + scol];
            ra0 = *(const v8s*)&sa[0];
            ra1 = *(const v8s*)&sa[8];
        }
        const short* sb = &Wr[((size_t)0 * 256 + o0 + srow) * 256 + scol];
        rb0 = *(const v8s*)&sb[0];
        rb1 = *(const v8s*)&sb[8];
    }

    for (int k0 = 0; k0 < K; k0 += 64) {
        if (k0) __syncthreads();
        *(v8s*)&As[srow][scol]     = ra0;
        *(v8s*)&As[srow][scol + 8] = ra1;
        *(v8s*)&Bs[srow][scol]     = rb0;
        *(v8s*)&Bs[srow][scol + 8] = rb1;
        __syncthreads();
        int kn = k0 + 64;
        if (kn < K) {
            int khkw = kn >> 8;
            int kh = khkw / KS, kw = khkw % KS;
            int hi = hh + kh - PAD, wi = ww + kw - PAD;
            int aci = (kn & 255) + scol;
            v8s z = {0, 0, 0, 0, 0, 0, 0, 0};
            ra0 = z; ra1 = z;
            if ((unsigned)hi < 32u && (unsigned)wi < 32u) {
                const short* sa = &Xn[(ib + (hi << 5) + wi) * 256 + aci];
                ra0 = *(const v8s*)&sa[0];
                ra1 = *(const v8s*)&sa[8];
            }
            const short* sb = &Wr[((size_t)khkw * 256 + o0 + srow) * 256 + (kn & 255) + scol];
            rb0 = *(const v8s*)&sb[0];
            rb1 = *(const v8s*)&sb[8];
        }
#pragma unroll
        for (int kk = 0; kk < 2; ++kk) {
            v8s a = *(const v8s*)&As[wv * 16 + l15][kk * 32 + quad * 8];
#pragma unroll
            for (int nt = 0; nt < 4; ++nt) {
                v8s b = *(const v8s*)&Bs[nt * 16 + l15][kk * 32 + quad * 8];
                acc[nt] = __builtin_amdgcn_mfma_f32_16x16x32_bf16(a, b, acc[nt], 0, 0, 0);
            }
        }
    }

#pragma unroll
    for (int nt = 0; nt < 4; ++nt)
#pragma unroll
        for (int r = 0; r < 4; ++r) {
            int pp = p0 + wv * 16 + quad * 4 + r;
            int oo = o0 + nt * 16 + l15;
            Y[(size_t)pp * 256 + oo] = __float2bfloat16(acc[nt][r]);
        }
}

// merged conv: z=0 -> 3x3 (q branch), z=1 -> 5x5 (kv branch)
__global__ __launch_bounds__(256) void mconv2(
    const short* __restrict__ Xa, const short* __restrict__ Wa, bf16* __restrict__ Ya,
    const short* __restrict__ Xb, const short* __restrict__ Wb, bf16* __restrict__ Yb)
{
    __shared__ short As[64][72], Bs[64][72];
    if (blockIdx.z == 0) mconv_core<3, 1>(Xa, Wa, Ya, As, Bs);
    else                 mconv_core<5, 2>(Xb, Wb, Yb, As, Bs);
}

// ---------------------------------------------------------------------------
// MFMA flash attention core (verified math unchanged).
// ---------------------------------------------------------------------------
static __device__ __forceinline__ void attn_core(
    const bf16* __restrict__ QK, const bf16* __restrict__ V,
    bf16* __restrict__ Out, int b, short Ps[4][16][72])
{
    int h = blockIdx.y, n0 = blockIdx.x * 64;
    int t = threadIdx.x, lane = t & 63, wv = t >> 6;
    int l15 = lane & 15, quad = lane >> 4;

    const short* qk = (const short*)QK;
    const short* vp = (const short*)V + ((size_t)b * 256 + h * 64) * 1024;

    size_t qrow = ((size_t)b * 1024 + n0 + wv * 16 + l15) * 512 + h * 64;
    v8s qf0 = *(const v8s*)&qk[qrow + quad * 8];
    v8s qf1 = *(const v8s*)&qk[qrow + 32 + quad * 8];

    v4f oacc[4] = {};
    float mi[4], li[4];
#pragma unroll
    for (int r = 0; r < 4; ++r) { mi[r] = -1e30f; li[r] = 0.f; }
    const float LOG2E = 1.4426950408889634f;

    for (int m0 = 0; m0 < 1024; m0 += 64) {
        v4f sacc[4];
#pragma unroll
        for (int ct = 0; ct < 4; ++ct) {
            size_t krow = ((size_t)b * 1024 + m0 + ct * 16 + l15) * 512 + 256 + h * 64;
            v8s kf0 = *(const v8s*)&qk[krow + quad * 8];
            v8s kf1 = *(const v8s*)&qk[krow + 32 + quad * 8];
            v4f z = {0.f, 0.f, 0.f, 0.f};
            z = __builtin_amdgcn_mfma_f32_16x16x32_bf16(qf0, kf0, z, 0, 0, 0);
            z = __builtin_amdgcn_mfma_f32_16x16x32_bf16(qf1, kf1, z, 0, 0, 0);
            sacc[ct] = z;
        }

        float rmax[4];
#pragma unroll
        for (int r = 0; r < 4; ++r)
            rmax[r] = 0.125f * fmaxf(fmaxf(sacc[0][r], sacc[1][r]),
                                     fmaxf(sacc[2][r], sacc[3][r]));
#pragma unroll
        for (int mk = 1; mk <= 8; mk <<= 1)
#pragma unroll
            for (int r = 0; r < 4; ++r)
                rmax[r] = fmaxf(rmax[r], __shfl_xor(rmax[r], mk));

        float al[4];
#pragma unroll
        for (int r = 0; r < 4; ++r) {
            float mn = fmaxf(mi[r], rmax[r]);
            al[r] = exp2f((mi[r] - mn) * LOG2E);
            mi[r] = mn;
        }

        float psum[4] = {};
#pragma unroll
        for (int ct = 0; ct < 4; ++ct)
#pragma unroll
            for (int r = 0; r < 4; ++r) {
                float pvv = exp2f((sacc[ct][r] * 0.125f - mi[r]) * LOG2E);
                psum[r] += pvv;
                Ps[wv][quad * 4 + r][ct * 16 + l15] = (short)f2us(pvv);
            }
#pragma unroll
        for (int mk = 1; mk <= 8; mk <<= 1)
#pragma unroll
            for (int r = 0; r < 4; ++r)
                psum[r] += __shfl_xor(psum[r], mk);
#pragma unroll
        for (int r = 0; r < 4; ++r) {
            li[r] = li[r] * al[r] + psum[r];
#pragma unroll
            for (int dt = 0; dt < 4; ++dt) oacc[dt][r] *= al[r];
        }

        v8s pf0 = *(const v8s*)&Ps[wv][l15][quad * 8];
        v8s pf1 = *(const v8s*)&Ps[wv][l15][32 + quad * 8];
#pragma unroll
        for (int dt = 0; dt < 4; ++dt) {
            const short* vr = vp + (size_t)(dt * 16 + l15) * 1024 + m0;
            v8s vf0 = *(const v8s*)&vr[quad * 8];
            v8s vf1 = *(const v8s*)&vr[32 + quad * 8];
            oacc[dt] = __builtin_amdgcn_mfma_f32_16x16x32_bf16(pf0, vf0, oacc[dt], 0, 0, 0);
            oacc[dt] = __builtin_amdgcn_mfma_f32_16x16x32_bf16(pf1, vf1, oacc[dt], 0, 0, 0);
        }
    }

    float linv[4];
#pragma unroll
    for (int r = 0; r < 4; ++r) linv[r] = 1.0f / li[r];
    size_t pb = (size_t)b * 1024 + n0 + wv * 16;
#pragma unroll
    for (int dt = 0; dt < 4; ++dt)
#pragma unroll
        for (int r = 0; r < 4; ++r)
            Out[(pb + quad * 4 + r) * 256 + h * 64 + dt * 16 + l15] =
                __float2bfloat16(oacc[dt][r] * linv[r]);
}

__global__ __launch_bounds__(256) void attn_mfma(
    const bf16* __restrict__ QK, const bf16* __restrict__ V,
    bf16* __restrict__ Out)
{
    __shared__ short Ps[4][16][72];
    attn_core(QK, V, Out, blockIdx.z, Ps);
}

// merged attention for both SA branches (z<8: branch0, z>=8: branch1)
__global__ __launch_bounds__(256) void attn_mfma2(
    const bf16* __restrict__ QK0, const bf16* __restrict__ V0, bf16* __restrict__ O0,
    const bf16* __restrict__ QK1, const bf16* __restrict__ V1, bf16* __restrict__ O1)
{
    __shared__ short Ps[4][16][72];
    int b = blockIdx.z & 7;
    if (blockIdx.z < 8) attn_core(QK0, V0, O0, b, Ps);
    else                attn_core(QK1, V1, O1, b, Ps);
}

// ---------------------------------------------------------------------------
static __device__ __forceinline__ void ln_row(
    const bf16* __restrict__ X, const bf16* __restrict__ g,
    const bf16* __restrict__ be, bf16* __restrict__ Y, size_t p)
{
    int lane = threadIdx.x & 63;
    const ushort4 u = *(const ushort4*)(X + p * 256 + lane * 4);
    float v0 = us2f(u.x), v1 = us2f(u.y), v2 = us2f(u.z), v3 = us2f(u.w);
    float s = v0 + v1 + v2 + v3;
    float ss = v0 * v0 + v1 * v1 + v2 * v2 + v3 * v3;
#pragma unroll
    for (int off = 32; off; off >>= 1) {
        s  += __shfl_xor(s, off);
        ss += __shfl_xor(ss, off);
    }
    float mu   = s * (1.0f / 256.0f);
    float var  = ss * (1.0f / 256.0f) - mu * mu;
    float rstd = rsqrtf(fmaxf(var, 0.0f) + 1e-5f);
    const ushort4 gu = *(const ushort4*)((const unsigned short*)g + lane * 4);
    const ushort4 bu = *(const ushort4*)((const unsigned short*)be + lane * 4);
    ushort4 o;
    o.x = f2us((v0 - mu) * rstd * us2f(gu.x) + us2f(bu.x));
    o.y = f2us((v1 - mu) * rstd * us2f(gu.y) + us2f(bu.y));
    o.z = f2us((v2 - mu) * rstd * us2f(gu.z) + us2f(bu.z));
    o.w = f2us((v3 - mu) * rstd * us2f(gu.w) + us2f(bu.w));
    *(ushort4*)(Y + p * 256 + lane * 4) = o;
}

__global__ __launch_bounds__(256) void ln_nhwc(
    const bf16* __restrict__ X, const bf16* __restrict__ g,
    const bf16* __restrict__ be, bf16* __restrict__ Y)
{
    int wv = threadIdx.x >> 6;
    ln_row(X, g, be, Y, (size_t)blockIdx.x * 4 + wv);
}

// merged LN for both branches: blocks [0,2048) -> set0, [2048,4096) -> set1
__global__ __launch_bounds__(256) void ln_nhwc2(
    const bf16* __restrict__ X0, const bf16* __restrict__ g0,
    const bf16* __restrict__ b0, bf16* __restrict__ Y0,
    const bf16* __restrict__ X1, const bf16* __restrict__ g1,
    const bf16* __restrict__ b1, bf16* __restrict__ Y1)
{
    int wv = threadIdx.x >> 6;
    int sel = blockIdx.x >> 11;
    size_t p = (size_t)(blockIdx.x & 2047) * 4 + wv;
    if (sel == 0) ln_row(X0, g0, b0, Y0, p);
    else          ln_row(X1, g1, b1, Y1, p);
}

// ---------------------------------------------------------------------------
__global__ __launch_bounds__(256) void dwgelu_nhwc(
    const bf16* __restrict__ H, const bf16* __restrict__ Wr,
    bf16* __restrict__ Y)
{
    int idx = blockIdx.x * 256 + threadIdx.x;
    int p = idx >> 7, c8 = (idx & 127) * 8;
    int hw = p & 1023, hh = hw >> 5, ww = hw & 31;
    size_t ib = ((size_t)(p >> 10)) << 10;
    float acc[8] = {};
#pragma unroll
    for (int kh = 0; kh < 3; ++kh)
#pragma unroll
        for (int kw = 0; kw < 3; ++kw) {
            int hi = hh + kh - 1, wi = ww + kw - 1;
            if ((unsigned)hi < 32u && (unsigned)wi < 32u) {
                v8s hv = *(const v8s*)((const short*)H + (ib + (hi << 5) + wi) * 1024 + c8);
                v8s wvv = *(const v8s*)((const short*)Wr + (kh * 3 + kw) * 1024 + c8);
#pragma unroll
                for (int j = 0; j < 8; ++j)
                    acc[j] = fmaf(us2f((unsigned short)wvv[j]),
                                  us2f((unsigned short)hv[j]), acc[j]);
            }
        }
    short ov[8];
#pragma unroll
    for (int j = 0; j < 8; ++j) {
        float x = acc[j];
        ov[j] = (short)f2us(0.5f * x * (1.0f + erff(x * 0.70710678118654752f)));
    }
    v8s o = {ov[0], ov[1], ov[2], ov[3], ov[4], ov[5], ov[6], ov[7]};
    *(v8s*)((short*)Y + (size_t)p * 1024 + c8) = o;
}

// ---------------------------------------------------------------------------
extern "C" void kernel_launch(void* const* d_in, const int* in_sizes, int n_in,
                              void* d_out, int out_size, void* d_ws, size_t ws_size,
                              hipStream_t stream)
{
    static const int  lidx[20] = {4,5,6,7,8,9,10,11,12,13,14,15,16,17,18,19,20,21,22,24};
    static const unsigned lsz[20] = {256,256,256,256,256,256,256,256,256,256,
                                     196608,65536,196608,65536,
                                     65536,65536,65536,65536,262144,262144};
    CvtArgs args;
    unsigned pre[21]; pre[0] = 0;
    for (int i = 0; i < 20; ++i) {
        args.src[i] = d_in[lidx[i]];
        pre[i + 1] = pre[i] + lsz[i];
    }
    for (int i = 0; i < 21; ++i) args.off[i] = pre[i];
    const unsigned ltot = pre[20];

    int*  flag  = (int*)d_ws;
    bf16* canon = (bf16*)d_ws + 128;
    bf16* cn[25];
    for (int i = 0; i < 20; ++i) cn[lidx[i]] = canon + pre[i];

    bf16* Wr3  = canon + ltot;
    bf16* Wr5  = Wr3 + 589824;
    bf16* Wdwr = Wr5 + 1638400;
    const size_t SZ = 2097152;
    bf16* slab = Wdwr + 9216;
    bf16* qb   = slab + 0 * SZ;                    // q_branch -> x (NHWC)
    bf16* kvb  = slab + 1 * SZ;
    bf16* t0   = slab + 2 * SZ;                    // branch-0 scratch
    bf16* q    = slab + 3 * SZ;
    bf16* kv   = slab + 4 * SZ;
    bf16* QKb  = slab + 5 * SZ;                    // 2 slots: [8192][512]
    bf16* Vb   = slab + 7 * SZ;                    // 1 slot: CHW
    bf16* t1   = slab + 8 * SZ;                    // branch-1 scratch
    bf16* QK2  = slab + 9 * SZ;                    // 2 slots (branch 1)
    bf16* V2   = slab + 11 * SZ;                   // 1 slot (branch 1)
    bf16* aopT = slab + 9 * SZ;                    // pre-SA reuse of QK2
    bf16* dopT = slab + 10 * SZ;
    bf16* hb   = slab + 3 * SZ;                    // LeFF: slots 3-6 (q..QKb dead)
    bf16* h2   = slab + 7 * SZ;                    // LeFF: slots 7-10 (Vb..QK2 dead)
    float* out = (float*)d_out;

    dim3 blk(256);
    auto S = [](const bf16* p) { return (const short*)p; };

    detect_kernel<<<1, 64, 0, stream>>>((const unsigned short*)d_in[4], flag);
    cvt_lin<<<ltot / 256, blk, 0, stream>>>(args, flag, canon);
    tcvt2<<<dim3(16, 4, 16), blk, 0, stream>>>(d_in[0], d_in[1], flag, aopT, dopT);
    repack_all<<<8740, blk, 0, stream>>>(d_in[2], d_in[3], d_in[23], flag, Wr3, Wr5, Wdwr);

    // both branch convs in one launch (z=0: 3x3->qb, z=1: 5x5->kvb)
    mconv2<<<dim3(128, 4, 2), blk, 0, stream>>>(S(aopT), (const short*)Wr3, qb,
                                                S(dopT), (const short*)Wr5, kvb);

    // merged self-attention pipelines (q branch = set0, kv branch = set1)
    ln_nhwc2<<<4096, blk, 0, stream>>>(qb, cn[4], cn[5], t0,
                                       kvb, cn[6], cn[7], t1);
    GA3 P;
    P.g[0] = GA{S(cn[14]), S(t0), QKb, nullptr, Vb, nullptr, 256, 3, 0};
    P.g[1] = GA{S(cn[16]), S(t1), QK2, nullptr, V2, nullptr, 256, 3, 0};
    P.g[2] = P.g[1];
    mgemm_z<<<dim3(12, 128, 2), blk, 0, stream>>>(P);

    attn_mfma2<<<dim3(16, 4, 16), blk, 0, stream>>>(QKb, Vb, t0, QK2, V2, t1);

    P.g[0] = GA{S(t0), S(cn[15]), qb, nullptr, nullptr, qb, 256, 0, 256};
    P.g[1] = GA{S(t1), S(cn[17]), kvb, nullptr, nullptr, kvb, 256, 0, 256};
    P.g[2] = P.g[1];
    mgemm_z<<<dim3(128, 4, 2), blk, 0, stream>>>(P);

    ln_nhwc2<<<4096, blk, 0, stream>>>(qb, cn[8], cn[9], q,
                                       kvb, cn[10], cn[11], kv);

    // cross attention: 3 projection GEMMs in one launch
    P.g[0] = GA{S(cn[18]), S(q),  QKb, nullptr, nullptr, nullptr, 256, 4, 0};
    P.g[1] = GA{S(cn[19]), S(kv), QKb, nullptr, nullptr, nullptr, 256, 4, 256};
    P.g[2] = GA{S(cn[20]), S(kv), Vb,  nullptr, nullptr, nullptr, 256, 1, 256};
    mgemm_z<<<dim3(4, 128, 3), blk, 0, stream>>>(P);

    attn_mfma<<<dim3(16, 4, 8), blk, 0, stream>>>(QKb, Vb, t0);
    mgemm<<<dim3(128, 4), blk, 0, stream>>>(S(t0), S(cn[21]), qb, nullptr, nullptr, qb, 256, 0, 256);

    // LeFF
    ln_nhwc<<<2048, blk, 0, stream>>>(qb, cn[12], cn[13], t0);
    mgemm<<<dim3(128, 16), blk, 0, stream>>>(S(t0), S(cn[22]), hb, nullptr, nullptr, nullptr, 256, 0, 1024);
    dwgelu_nhwc<<<4096, blk, 0, stream>>>(hb, Wdwr, h2);
    mgemm<<<dim3(4, 128), blk, 0, stream>>>(S(cn[24]), S(h2), nullptr, out, nullptr, qb, 1024, 2, 256);
}

// Round 2
// 530.064 us; speedup vs baseline: 1.0936x; 1.0118x over previous
//
#include <hip/hip_runtime.h>
#include <hip/hip_bf16.h>

// DCSA block, round 12: attention latency attack.
// r11 counters: attn_mfma2 = 130.8us, MfmaUtil 5.2%, VALUBusy 30%, HBM 7.6%,
// FETCH 69.7MB (unique ~24MB) -> latency-bound with L2 thrash.
// Changes: (1) register-prefetch pipeline in attn_core (K double-buffered
// across m0 iterations, V issued before softmax), (2) XCD-aware block swizzle
// so all 16 n0-tiles of one (b,h) share one XCD's L2, (3) softmax exp arg as
// single fmaf with folded 0.125*log2e. Everything else unchanged from r11.

using bf16 = __hip_bfloat16;
typedef short v8s __attribute__((ext_vector_type(8)));
typedef float v4f  __attribute__((ext_vector_type(4)));

static __device__ __forceinline__ float bf2f(bf16 x) { return __bfloat162float(x); }
static __device__ __forceinline__ float us2f(unsigned short u)
{ union { unsigned int i; float f; } x; x.i = ((unsigned)u) << 16; return x.f; }
static __device__ __forceinline__ unsigned short f2us(float f)
{ bf16 h = __float2bfloat16(f); return *(unsigned short*)&h; }
static __device__ __forceinline__ float ldi(const void* p, size_t i, int isbf)
{ return isbf ? bf2f(((const bf16*)p)[i]) : ((const float*)p)[i]; }

// ---------------------------------------------------------------------------
__global__ void detect_kernel(const unsigned short* p, int* flag)
{
    if (threadIdx.x == 0 && blockIdx.x == 0)
        *flag = (p[0] == 0x3F80) ? 1 : 0;
}

// ---------------------------------------------------------------------------
struct CvtArgs { const void* src[20]; unsigned off[21]; };

__global__ __launch_bounds__(256) void cvt_lin(CvtArgs a, const int* __restrict__ flag,
                                               bf16* __restrict__ dst)
{
    unsigned e = blockIdx.x * 256u + threadIdx.x;
    int isbf = *flag;
    int s = 0;
    while (e >= a.off[s + 1]) ++s;
    dst[e] = __float2bfloat16(ldi(a.src[s], e - a.off[s], isbf));
}

// ---------------------------------------------------------------------------
// merged NCHW->NHWC transpose for both feature maps (z<8: aop, z>=8: dop)
__global__ __launch_bounds__(256) void tcvt2(const void* __restrict__ s0,
                                             const void* __restrict__ s1,
                                             const int* __restrict__ flag,
                                             bf16* __restrict__ d0,
                                             bf16* __restrict__ d1)
{
    __shared__ float T[64][65];
    const void* src = (blockIdx.z < 8) ? s0 : s1;
    bf16* dst       = (blockIdx.z < 8) ? d0 : d1;
    int hw0 = blockIdx.x * 64, c0 = blockIdx.y * 64, b = blockIdx.z & 7;
    int t = threadIdx.x, isbf = *flag;
    int c = t >> 2, x16 = (t & 3) * 16;
    size_t sbase = ((size_t)b * 256 + c0 + c) * 1024 + hw0 + x16;
#pragma unroll
    for (int j = 0; j < 16; ++j) T[c][x16 + j] = ldi(src, sbase + j, isbf);
    __syncthreads();
    int hw = t >> 2, c16 = (t & 3) * 16;
    bf16* dp = dst + ((size_t)(b << 10) + hw0 + hw) * 256 + c0 + c16;
#pragma unroll
    for (int j = 0; j < 16; ++j) dp[j] = __float2bfloat16(T[c16 + j][hw]);
}

// ---------------------------------------------------------------------------
// merged weight repack: conv3 (589824) + conv5 (1638400) + dw (9216)
__global__ __launch_bounds__(256) void repack_all(
    const void* __restrict__ W3, const void* __restrict__ W5,
    const void* __restrict__ Wdw, const int* __restrict__ flag,
    bf16* __restrict__ R3, bf16* __restrict__ R5, bf16* __restrict__ Rdw)
{
    int idx = blockIdx.x * 256 + threadIdx.x;
    int isbf = *flag;
    if (idx < 589824) {
        int ci = idx & 255, o = (idx >> 8) & 255, khkw = idx >> 16;
        int kh = khkw / 3, kw = khkw % 3;
        R3[idx] = __float2bfloat16(
            ldi(W3, (((size_t)o * 256 + ci) * 3 + kh) * 3 + kw, isbf));
    } else if (idx < 2228224) {
        int j = idx - 589824;
        int ci = j & 255, o = (j >> 8) & 255, khkw = j >> 16;
        int kh = khkw / 5, kw = khkw % 5;
        R5[j] = __float2bfloat16(
            ldi(W5, (((size_t)o * 256 + ci) * 5 + kh) * 5 + kw, isbf));
    } else {
        int j = idx - 2228224;
        int c = j & 1023, tap = j >> 10;
        Rdw[j] = __float2bfloat16(ldi(Wdw, (size_t)c * 9 + tap, isbf));
    }
}

// ---------------------------------------------------------------------------
// MFMA GEMM core, 64x64 tile, BK=64, 4 waves, register-prefetch pipeline.
// MA:[M][K], MB:[N][K] k-contig.
// modes: 0 NHWC(+R) / 1 CHW / 2 CHW-fp32+R / 3 qkv-split / 4 QK col-offset
// ---------------------------------------------------------------------------
static __device__ __forceinline__ void mgemm_core(
    const short* __restrict__ MA, const short* __restrict__ MB,
    bf16* __restrict__ Yb, float* __restrict__ Yf, bf16* __restrict__ Y2,
    const bf16* __restrict__ R, int K, int mode, int Ochan,
    short As[64][72], short Bs[64][72])
{
    int m0 = blockIdx.x * 64, n0 = blockIdx.y * 64;
    int t = threadIdx.x, lane = t & 63, wv = t >> 6;
    int l15 = lane & 15, quad = lane >> 4;
    int srow = t >> 2, scol = (t & 3) * 16;

    const short* pa = &MA[(size_t)(m0 + srow) * K + scol];
    const short* pb = &MB[(size_t)(n0 + srow) * K + scol];

    v4f acc[4] = {};
    v8s ra0 = *(const v8s*)&pa[0], ra1 = *(const v8s*)&pa[8];
    v8s rb0 = *(const v8s*)&pb[0], rb1 = *(const v8s*)&pb[8];

    for (int k0 = 0; k0 < K; k0 += 64) {
        if (k0) __syncthreads();
        *(v8s*)&As[srow][scol]     = ra0;
        *(v8s*)&As[srow][scol + 8] = ra1;
        *(v8s*)&Bs[srow][scol]     = rb0;
        *(v8s*)&Bs[srow][scol + 8] = rb1;
        __syncthreads();
        if (k0 + 64 < K) {
            ra0 = *(const v8s*)&pa[k0 + 64];
            ra1 = *(const v8s*)&pa[k0 + 72];
            rb0 = *(const v8s*)&pb[k0 + 64];
            rb1 = *(const v8s*)&pb[k0 + 72];
        }
#pragma unroll
        for (int kk = 0; kk < 2; ++kk) {
            v8s a = *(const v8s*)&As[wv * 16 + l15][kk * 32 + quad * 8];
#pragma unroll
            for (int nt = 0; nt < 4; ++nt) {
                v8s b = *(const v8s*)&Bs[nt * 16 + l15][kk * 32 + quad * 8];
                acc[nt] = __builtin_amdgcn_mfma_f32_16x16x32_bf16(a, b, acc[nt], 0, 0, 0);
            }
        }
    }

#pragma unroll
    for (int nt = 0; nt < 4; ++nt)
#pragma unroll
        for (int r = 0; r < 4; ++r) {
            int mm = m0 + wv * 16 + quad * 4 + r;
            int nn = n0 + nt * 16 + l15;
            float v = acc[nt][r];
            if (mode == 0) {
                size_t off = (size_t)mm * Ochan + nn;
                if (R) v += bf2f(R[off]);
                Yb[off] = __float2bfloat16(v);
            } else if (mode == 1) {
                Yb[((size_t)(nn >> 10) * Ochan + mm) * 1024 + (nn & 1023)] =
                    __float2bfloat16(v);
            } else if (mode == 2) {
                Yf[((size_t)(nn >> 10) * Ochan + mm) * 1024 + (nn & 1023)] =
                    v + bf2f(R[(size_t)nn * 256 + mm]);
            } else if (mode == 3) {
                if (mm < 512) Yb[(size_t)nn * 512 + mm] = __float2bfloat16(v);
                else Y2[((size_t)(nn >> 10) * 256 + (mm - 512)) * 1024 + (nn & 1023)] =
                         __float2bfloat16(v);
            } else {
                Yb[(size_t)nn * 512 + Ochan + mm] = __float2bfloat16(v);
            }
        }
}

__global__ __launch_bounds__(256) void mgemm(
    const short* __restrict__ MA, const short* __restrict__ MB,
    bf16* __restrict__ Yb, float* __restrict__ Yf, bf16* __restrict__ Y2,
    const bf16* __restrict__ R, int K, int mode, int Ochan)
{
    __shared__ short As[64][72], Bs[64][72];
    mgemm_core(MA, MB, Yb, Yf, Y2, R, K, mode, Ochan, As, Bs);
}

// z-dispatched merged GEMM (up to 3 independent problems, same x/y grid)
struct GA { const short* A; const short* B; bf16* Yb; float* Yf; bf16* Y2;
            const bf16* R; int K; int mode; int Oc; };
struct GA3 { GA g[3]; };

__global__ __launch_bounds__(256) void mgemm_z(GA3 P)
{
    __shared__ short As[64][72], Bs[64][72];
    const GA& a = P.g[blockIdx.z];
    mgemm_core(a.A, a.B, a.Yb, a.Yf, a.Y2, a.R, a.K, a.mode, a.Oc, As, Bs);
}

// ---------------------------------------------------------------------------
// MFMA conv core, same 64x64 / BK=64 prefetch skeleton, im2col A staging.
// ---------------------------------------------------------------------------
template <int KS, int PAD>
static __device__ __forceinline__ void mconv_core(
    const short* __restrict__ Xn, const short* __restrict__ Wr,
    bf16* __restrict__ Y, short As[64][72], short Bs[64][72])
{
    const int K = 256 * KS * KS;
    int p0 = blockIdx.x * 64, o0 = blockIdx.y * 64;
    int t = threadIdx.x, lane = t & 63, wv = t >> 6;
    int l15 = lane & 15, quad = lane >> 4;
    int srow = t >> 2, scol = (t & 3) * 16;

    int p  = p0 + srow;
    int hw = p & 1023, hh = hw >> 5, ww = hw & 31;
    size_t ib = ((size_t)(p >> 10)) << 10;

    v4f acc[4] = {};
    v8s ra0, ra1, rb0, rb1;

    {
        int hi = hh - PAD, wi = ww - PAD;
        v8s z = {0, 0, 0, 0, 0, 0, 0, 0};
        ra0 = z; ra1 = z;
        if ((unsigned)hi < 32u && (unsigned)wi < 32u) {
            const short* sa = &Xn[(ib + (hi << 5) + wi) * 256 + scol];
            ra0 = *(const v8s*)&sa[0];
            ra1 = *(const v8s*)&sa[8];
        }
        const short* sb = &Wr[((size_t)0 * 256 + o0 + srow) * 256 + scol];
        rb0 = *(const v8s*)&sb[0];
        rb1 = *(const v8s*)&sb[8];
    }

    for (int k0 = 0; k0 < K; k0 += 64) {
        if (k0) __syncthreads();
        *(v8s*)&As[srow][scol]     = ra0;
        *(v8s*)&As[srow][scol + 8] = ra1;
        *(v8s*)&Bs[srow][scol]     = rb0;
        *(v8s*)&Bs[srow][scol + 8] = rb1;
        __syncthreads();
        int kn = k0 + 64;
        if (kn < K) {
            int khkw = kn >> 8;
            int kh = khkw / KS, kw = khkw % KS;
            int hi = hh + kh - PAD, wi = ww + kw - PAD;
            int aci = (kn & 255) + scol;
            v8s z = {0, 0, 0, 0, 0, 0, 0, 0};
            ra0 = z; ra1 = z;
            if ((unsigned)hi < 32u && (unsigned)wi < 32u) {
                const short* sa = &Xn[(ib + (hi << 5) + wi) * 256 + aci];
                ra0 = *(const v8s*)&sa[0];
                ra1 = *(const v8s*)&sa[8];
            }
            const short* sb = &Wr[((size_t)khkw * 256 + o0 + srow) * 256 + (kn & 255) + scol];
            rb0 = *(const v8s*)&sb[0];
            rb1 = *(const v8s*)&sb[8];
        }
#pragma unroll
        for (int kk = 0; kk < 2; ++kk) {
            v8s a = *(const v8s*)&As[wv * 16 + l15][kk * 32 + quad * 8];
#pragma unroll
            for (int nt = 0; nt < 4; ++nt) {
                v8s b = *(const v8s*)&Bs[nt * 16 + l15][kk * 32 + quad * 8];
                acc[nt] = __builtin_amdgcn_mfma_f32_16x16x32_bf16(a, b, acc[nt], 0, 0, 0);
            }
        }
    }

#pragma unroll
    for (int nt = 0; nt < 4; ++nt)
#pragma unroll
        for (int r = 0; r < 4; ++r) {
            int pp = p0 + wv * 16 + quad * 4 + r;
            int oo = o0 + nt * 16 + l15;
            Y[(size_t)pp * 256 + oo] = __float2bfloat16(acc[nt][r]);
        }
}

// merged conv: z=0 -> 3x3 (q branch), z=1 -> 5x5 (kv branch)
__global__ __launch_bounds__(256) void mconv2(
    const short* __restrict__ Xa, const short* __restrict__ Wa, bf16* __restrict__ Ya,
    const short* __restrict__ Xb, const short* __restrict__ Wb, bf16* __restrict__ Yb)
{
    __shared__ short As[64][72], Bs[64][72];
    if (blockIdx.z == 0) mconv_core<3, 1>(Xa, Wa, Ya, As, Bs);
    else                 mconv_core<5, 2>(Xb, Wb, Yb, As, Bs);
}

// ---------------------------------------------------------------------------
// MFMA flash attention core, register-prefetch pipeline:
//  - K tile double-buffered across m0 iterations (next-K issued right after
//    QK^T consumes current K)
//  - V loads for the current tile issued before softmax
//  - exp arg as single fmaf with folded 0.125*log2e (max tracked unscaled)
// ---------------------------------------------------------------------------
static __device__ __forceinline__ void attn_core(
    const bf16* __restrict__ QK, const bf16* __restrict__ V,
    bf16* __restrict__ Out, int b, int h, int n0, short Ps[4][16][72])
{
    int t = threadIdx.x, lane = t & 63, wv = t >> 6;
    int l15 = lane & 15, quad = lane >> 4;

    const short* qk = (const short*)QK;
    const short* vp = (const short*)V + ((size_t)b * 256 + h * 64) * 1024;

    size_t qrow = ((size_t)b * 1024 + n0 + wv * 16 + l15) * 512 + h * 64;
    v8s qf0 = *(const v8s*)&qk[qrow + quad * 8];
    v8s qf1 = *(const v8s*)&qk[qrow + 32 + quad * 8];

    v4f oacc[4] = {};
    float mi[4], li[4];
#pragma unroll
    for (int r = 0; r < 4; ++r) { mi[r] = -1e30f; li[r] = 0.f; }
    const float SC = 0.18033688011112042f;  // 0.125 * log2(e)

    // preload K tile for m0 = 0
    v8s k0[4], k1[4];
#pragma unroll
    for (int ct = 0; ct < 4; ++ct) {
        size_t krow = ((size_t)b * 1024 + ct * 16 + l15) * 512 + 256 + h * 64;
        k0[ct] = *(const v8s*)&qk[krow + quad * 8];
        k1[ct] = *(const v8s*)&qk[krow + 32 + quad * 8];
    }

    for (int m0 = 0; m0 < 1024; m0 += 64) {
        // 1) QK^T from current K regs
        v4f sacc[4];
#pragma unroll
        for (int ct = 0; ct < 4; ++ct) {
            v4f z = {0.f, 0.f, 0.f, 0.f};
            z = __builtin_amdgcn_mfma_f32_16x16x32_bf16(qf0, k0[ct], z, 0, 0, 0);
            z = __builtin_amdgcn_mfma_f32_16x16x32_bf16(qf1, k1[ct], z, 0, 0, 0);
            sacc[ct] = z;
        }

        // 2) issue V loads for THIS tile (consumed after softmax)
        v8s vf0[4], vf1[4];
#pragma unroll
        for (int dt = 0; dt < 4; ++dt) {
            const short* vr = vp + (size_t)(dt * 16 + l15) * 1024 + m0;
            vf0[dt] = *(const v8s*)&vr[quad * 8];
            vf1[dt] = *(const v8s*)&vr[32 + quad * 8];
        }

        // 3) issue K loads for NEXT tile (consumed next iteration)
        if (m0 + 64 < 1024) {
#pragma unroll
            for (int ct = 0; ct < 4; ++ct) {
                size_t krow = ((size_t)b * 1024 + m0 + 64 + ct * 16 + l15) * 512 + 256 + h * 64;
                k0[ct] = *(const v8s*)&qk[krow + quad * 8];
                k1[ct] = *(const v8s*)&qk[krow + 32 + quad * 8];
            }
        }

        // 4) softmax (unscaled running max; covers latency of 2) and 3))
        float rmax[4];
#pragma unroll
        for (int r = 0; r < 4; ++r)
            rmax[r] = fmaxf(fmaxf(sacc[0][r], sacc[1][r]),
                            fmaxf(sacc[2][r], sacc[3][r]));
#pragma unroll
        for (int mk = 1; mk <= 8; mk <<= 1)
#pragma unroll
            for (int r = 0; r < 4; ++r)
                rmax[r] = fmaxf(rmax[r], __shfl_xor(rmax[r], mk));

        float al[4], miSC[4];
#pragma unroll
        for (int r = 0; r < 4; ++r) {
            float mn = fmaxf(mi[r], rmax[r]);
            al[r] = exp2f((mi[r] - mn) * SC);
            mi[r] = mn;
            miSC[r] = mn * SC;
        }

        float psum[4] = {};
#pragma unroll
        for (int ct = 0; ct < 4; ++ct)
#pragma unroll
            for (int r = 0; r < 4; ++r) {
                float pvv = exp2f(fmaf(sacc[ct][r], SC, -miSC[r]));
                psum[r] += pvv;
                Ps[wv][quad * 4 + r][ct * 16 + l15] = (short)f2us(pvv);
            }
#pragma unroll
        for (int mk = 1; mk <= 8; mk <<= 1)
#pragma unroll
            for (int r = 0; r < 4; ++r)
                psum[r] += __shfl_xor(psum[r], mk);
#pragma unroll
        for (int r = 0; r < 4; ++r) {
            li[r] = li[r] * al[r] + psum[r];
#pragma unroll
            for (int dt = 0; dt < 4; ++dt) oacc[dt][r] *= al[r];
        }

        // 5) PV from prefetched V regs
        v8s pf0 = *(const v8s*)&Ps[wv][l15][quad * 8];
        v8s pf1 = *(const v8s*)&Ps[wv][l15][32 + quad * 8];
#pragma unroll
        for (int dt = 0; dt < 4; ++dt) {
            oacc[dt] = __builtin_amdgcn_mfma_f32_16x16x32_bf16(pf0, vf0[dt], oacc[dt], 0, 0, 0);
            oacc[dt] = __builtin_amdgcn_mfma_f32_16x16x32_bf16(pf1, vf1[dt], oacc[dt], 0, 0, 0);
        }
    }

    float linv[4];
#pragma unroll
    for (int r = 0; r < 4; ++r) linv[r] = 1.0f / li[r];
    size_t pb = (size_t)b * 1024 + n0 + wv * 16;
#pragma unroll
    for (int dt = 0; dt < 4; ++dt)
#pragma unroll
        for (int r = 0; r < 4; ++r)
            Out[(pb + quad * 4 + r) * 256 + h * 64 + dt * 16 + l15] =
                __float2bfloat16(oacc[dt][r] * linv[r]);
}

// XCD-swizzled attention: flat 1D grid of NG*16 blocks; all 16 n0-tiles of
// one (b,h[,branch]) group land on one XCD so its 256KB K/V stays L2-hot.
// NG = number of (h, b[, branch]) groups (must be divisible by 8).
template <int NG>
__global__ __launch_bounds__(256) void attn_swz(
    const bf16* __restrict__ QK0, const bf16* __restrict__ V0, bf16* __restrict__ O0,
    const bf16* __restrict__ QK1, const bf16* __restrict__ V1, bf16* __restrict__ O1)
{
    __shared__ short Ps[4][16][72];
    int i = blockIdx.x;
    int xcd = i & 7, idx = i >> 3;
    int g = xcd * (NG / 8) + (idx >> 4);     // group id, bijective remap
    int n0 = (idx & 15) * 64;
    int h = g & 3, zz = g >> 2;
    int b = zz & 7;
    if (zz < 8) attn_core(QK0, V0, O0, b, h, n0, Ps);
    else        attn_core(QK1, V1, O1, b, h, n0, Ps);
}

// ---------------------------------------------------------------------------
static __device__ __forceinline__ void ln_row(
    const bf16* __restrict__ X, const bf16* __restrict__ g,
    const bf16* __restrict__ be, bf16* __restrict__ Y, size_t p)
{
    int lane = threadIdx.x & 63;
    const ushort4 u = *(const ushort4*)(X + p * 256 + lane * 4);
    float v0 = us2f(u.x), v1 = us2f(u.y), v2 = us2f(u.z), v3 = us2f(u.w);
    float s = v0 + v1 + v2 + v3;
    float ss = v0 * v0 + v1 * v1 + v2 * v2 + v3 * v3;
#pragma unroll
    for (int off = 32; off; off >>= 1) {
        s  += __shfl_xor(s, off);
        ss += __shfl_xor(ss, off);
    }
    float mu   = s * (1.0f / 256.0f);
    float var  = ss * (1.0f / 256.0f) - mu * mu;
    float rstd = rsqrtf(fmaxf(var, 0.0f) + 1e-5f);
    const ushort4 gu = *(const ushort4*)((const unsigned short*)g + lane * 4);
    const ushort4 bu = *(const ushort4*)((const unsigned short*)be + lane * 4);
    ushort4 o;
    o.x = f2us((v0 - mu) * rstd * us2f(gu.x) + us2f(bu.x));
    o.y = f2us((v1 - mu) * rstd * us2f(gu.y) + us2f(bu.y));
    o.z = f2us((v2 - mu) * rstd * us2f(gu.z) + us2f(bu.z));
    o.w = f2us((v3 - mu) * rstd * us2f(gu.w) + us2f(bu.w));
    *(ushort4*)(Y + p * 256 + lane * 4) = o;
}

__global__ __launch_bounds__(256) void ln_nhwc(
    const bf16* __restrict__ X, const bf16* __restrict__ g,
    const bf16* __restrict__ be, bf16* __restrict__ Y)
{
    int wv = threadIdx.x >> 6;
    ln_row(X, g, be, Y, (size_t)blockIdx.x * 4 + wv);
}

// merged LN for both branches: blocks [0,2048) -> set0, [2048,4096) -> set1
__global__ __launch_bounds__(256) void ln_nhwc2(
    const bf16* __restrict__ X0, const bf16* __restrict__ g0,
    const bf16* __restrict__ b0, bf16* __restrict__ Y0,
    const bf16* __restrict__ X1, const bf16* __restrict__ g1,
    const bf16* __restrict__ b1, bf16* __restrict__ Y1)
{
    int wv = threadIdx.x >> 6;
    int sel = blockIdx.x >> 11;
    size_t p = (size_t)(blockIdx.x & 2047) * 4 + wv;
    if (sel == 0) ln_row(X0, g0, b0, Y0, p);
    else          ln_row(X1, g1, b1, Y1, p);
}

// ---------------------------------------------------------------------------
__global__ __launch_bounds__(256) void dwgelu_nhwc(
    const bf16* __restrict__ H, const bf16* __restrict__ Wr,
    bf16* __restrict__ Y)
{
    int idx = blockIdx.x * 256 + threadIdx.x;
    int p = idx >> 7, c8 = (idx & 127) * 8;
    int hw = p & 1023, hh = hw >> 5, ww = hw & 31;
    size_t ib = ((size_t)(p >> 10)) << 10;
    float acc[8] = {};
#pragma unroll
    for (int kh = 0; kh < 3; ++kh)
#pragma unroll
        for (int kw = 0; kw < 3; ++kw) {
            int hi = hh + kh - 1, wi = ww + kw - 1;
            if ((unsigned)hi < 32u && (unsigned)wi < 32u) {
                v8s hv = *(const v8s*)((const short*)H + (ib + (hi << 5) + wi) * 1024 + c8);
                v8s wvv = *(const v8s*)((const short*)Wr + (kh * 3 + kw) * 1024 + c8);
#pragma unroll
                for (int j = 0; j < 8; ++j)
                    acc[j] = fmaf(us2f((unsigned short)wvv[j]),
                                  us2f((unsigned short)hv[j]), acc[j]);
            }
        }
    short ov[8];
#pragma unroll
    for (int j = 0; j < 8; ++j) {
        float x = acc[j];
        ov[j] = (short)f2us(0.5f * x * (1.0f + erff(x * 0.70710678118654752f)));
    }
    v8s o = {ov[0], ov[1], ov[2], ov[3], ov[4], ov[5], ov[6], ov[7]};
    *(v8s*)((short*)Y + (size_t)p * 1024 + c8) = o;
}

// ---------------------------------------------------------------------------
extern "C" void kernel_launch(void* const* d_in, const int* in_sizes, int n_in,
                              void* d_out, int out_size, void* d_ws, size_t ws_size,
                              hipStream_t stream)
{
    static const int  lidx[20] = {4,5,6,7,8,9,10,11,12,13,14,15,16,17,18,19,20,21,22,24};
    static const unsigned lsz[20] = {256,256,256,256,256,256,256,256,256,256,
                                     196608,65536,196608,65536,
                                     65536,65536,65536,65536,262144,262144};
    CvtArgs args;
    unsigned pre[21]; pre[0] = 0;
    for (int i = 0; i < 20; ++i) {
        args.src[i] = d_in[lidx[i]];
        pre[i + 1] = pre[i] + lsz[i];
    }
    for (int i = 0; i < 21; ++i) args.off[i] = pre[i];
    const unsigned ltot = pre[20];

    int*  flag  = (int*)d_ws;
    bf16* canon = (bf16*)d_ws + 128;
    bf16* cn[25];
    for (int i = 0; i < 20; ++i) cn[lidx[i]] = canon + pre[i];

    bf16* Wr3  = canon + ltot;
    bf16* Wr5  = Wr3 + 589824;
    bf16* Wdwr = Wr5 + 1638400;
    const size_t SZ = 2097152;
    bf16* slab = Wdwr + 9216;
    bf16* qb   = slab + 0 * SZ;                    // q_branch -> x (NHWC)
    bf16* kvb  = slab + 1 * SZ;
    bf16* t0   = slab + 2 * SZ;                    // branch-0 scratch
    bf16* q    = slab + 3 * SZ;
    bf16* kv   = slab + 4 * SZ;
    bf16* QKb  = slab + 5 * SZ;                    // 2 slots: [8192][512]
    bf16* Vb   = slab + 7 * SZ;                    // 1 slot: CHW
    bf16* t1   = slab + 8 * SZ;                    // branch-1 scratch
    bf16* QK2  = slab + 9 * SZ;                    // 2 slots (branch 1)
    bf16* V2   = slab + 11 * SZ;                   // 1 slot (branch 1)
    bf16* aopT = slab + 9 * SZ;                    // pre-SA reuse of QK2
    bf16* dopT = slab + 10 * SZ;
    bf16* hb   = slab + 3 * SZ;                    // LeFF: slots 3-6 (q..QKb dead)
    bf16* h2   = slab + 7 * SZ;                    // LeFF: slots 7-10 (Vb..QK2 dead)
    float* out = (float*)d_out;

    dim3 blk(256);
    auto S = [](const bf16* p) { return (const short*)p; };

    detect_kernel<<<1, 64, 0, stream>>>((const unsigned short*)d_in[4], flag);
    cvt_lin<<<ltot / 256, blk, 0, stream>>>(args, flag, canon);
    tcvt2<<<dim3(16, 4, 16), blk, 0, stream>>>(d_in[0], d_in[1], flag, aopT, dopT);
    repack_all<<<8740, blk, 0, stream>>>(d_in[2], d_in[3], d_in[23], flag, Wr3, Wr5, Wdwr);

    // both branch convs in one launch (z=0: 3x3->qb, z=1: 5x5->kvb)
    mconv2<<<dim3(128, 4, 2), blk, 0, stream>>>(S(aopT), (const short*)Wr3, qb,
                                                S(dopT), (const short*)Wr5, kvb);

    // merged self-attention pipelines (q branch = set0, kv branch = set1)
    ln_nhwc2<<<4096, blk, 0, stream>>>(qb, cn[4], cn[5], t0,
                                       kvb, cn[6], cn[7], t1);
    GA3 P;
    P.g[0] = GA{S(cn[14]), S(t0), QKb, nullptr, Vb, nullptr, 256, 3, 0};
    P.g[1] = GA{S(cn[16]), S(t1), QK2, nullptr, V2, nullptr, 256, 3, 0};
    P.g[2] = P.g[1];
    mgemm_z<<<dim3(12, 128, 2), blk, 0, stream>>>(P);

    attn_swz<64><<<1024, blk, 0, stream>>>(QKb, Vb, t0, QK2, V2, t1);

    P.g[0] = GA{S(t0), S(cn[15]), qb, nullptr, nullptr, qb, 256, 0, 256};
    P.g[1] = GA{S(t1), S(cn[17]), kvb, nullptr, nullptr, kvb, 256, 0, 256};
    P.g[2] = P.g[1];
    mgemm_z<<<dim3(128, 4, 2), blk, 0, stream>>>(P);

    ln_nhwc2<<<4096, blk, 0, stream>>>(qb, cn[8], cn[9], q,
                                       kvb, cn[10], cn[11], kv);

    // cross attention: 3 projection GEMMs in one launch
    P.g[0] = GA{S(cn[18]), S(q),  QKb, nullptr, nullptr, nullptr, 256, 4, 0};
    P.g[1] = GA{S(cn[19]), S(kv), QKb, nullptr, nullptr, nullptr, 256, 4, 256};
    P.g[2] = GA{S(cn[20]), S(kv), Vb,  nullptr, nullptr, nullptr, 256, 1, 256};
    mgemm_z<<<dim3(4, 128, 3), blk, 0, stream>>>(P);

    attn_swz<32><<<512, blk, 0, stream>>>(QKb, Vb, t0, QKb, Vb, t0);
    mgemm<<<dim3(128, 4), blk, 0, stream>>>(S(t0), S(cn[21]), qb, nullptr, nullptr, qb, 256, 0, 256);

    // LeFF
    ln_nhwc<<<2048, blk, 0, stream>>>(qb, cn[12], cn[13], t0);
    mgemm<<<dim3(128, 16), blk, 0, stream>>>(S(t0), S(cn[22]), hb, nullptr, nullptr, nullptr, 256, 0, 1024);
    dwgelu_nhwc<<<4096, blk, 0, stream>>>(hb, Wdwr, h2);
    mgemm<<<dim3(4, 128), blk, 0, stream>>>(S(cn[24]), S(h2), nullptr, out, nullptr, qb, 1024, 2, 256);
}

// Round 3
// 525.694 us; speedup vs baseline: 1.1027x; 1.0083x over previous
//
#include <hip/hip_runtime.h>
#include <hip/hip_bf16.h>

// DCSA block, round 13: attention serial-chain attack.
// r12 post-mortem: swizzle cut FETCH 69.7->12.3MB but time unchanged ->
// bottleneck is the per-iteration serial softmax chain (two 4-step shuffle
// trees) plus occupancy loss from K-prefetch VGPRs (60->88, occ 39->21%).
// Changes (attn_core only, all exact-math):
//  1) revert K/V register prefetch (loads at use; L2-hot via swizzle)
//  2) defer li reduction to after the KV loop (per-lane partials; al is
//     uniform within each 16-lane group so scaling commutes) -> deletes the
//     per-iteration psum shuffle tree
//  3) gate the max-tree + rescale with __any(partial>mi): when no row max
//     grows the old code multiplied by al=1, so skipping is bit-exact
//  4) s_setprio(1) around QK/PV MFMA clusters (T5)

using bf16 = __hip_bfloat16;
typedef short v8s __attribute__((ext_vector_type(8)));
typedef float v4f  __attribute__((ext_vector_type(4)));

static __device__ __forceinline__ float bf2f(bf16 x) { return __bfloat162float(x); }
static __device__ __forceinline__ float us2f(unsigned short u)
{ union { unsigned int i; float f; } x; x.i = ((unsigned)u) << 16; return x.f; }
static __device__ __forceinline__ unsigned short f2us(float f)
{ bf16 h = __float2bfloat16(f); return *(unsigned short*)&h; }
static __device__ __forceinline__ float ldi(const void* p, size_t i, int isbf)
{ return isbf ? bf2f(((const bf16*)p)[i]) : ((const float*)p)[i]; }

// ---------------------------------------------------------------------------
__global__ void detect_kernel(const unsigned short* p, int* flag)
{
    if (threadIdx.x == 0 && blockIdx.x == 0)
        *flag = (p[0] == 0x3F80) ? 1 : 0;
}

// ---------------------------------------------------------------------------
struct CvtArgs { const void* src[20]; unsigned off[21]; };

__global__ __launch_bounds__(256) void cvt_lin(CvtArgs a, const int* __restrict__ flag,
                                               bf16* __restrict__ dst)
{
    unsigned e = blockIdx.x * 256u + threadIdx.x;
    int isbf = *flag;
    int s = 0;
    while (e >= a.off[s + 1]) ++s;
    dst[e] = __float2bfloat16(ldi(a.src[s], e - a.off[s], isbf));
}

// ---------------------------------------------------------------------------
// merged NCHW->NHWC transpose for both feature maps (z<8: aop, z>=8: dop)
__global__ __launch_bounds__(256) void tcvt2(const void* __restrict__ s0,
                                             const void* __restrict__ s1,
                                             const int* __restrict__ flag,
                                             bf16* __restrict__ d0,
                                             bf16* __restrict__ d1)
{
    __shared__ float T[64][65];
    const void* src = (blockIdx.z < 8) ? s0 : s1;
    bf16* dst       = (blockIdx.z < 8) ? d0 : d1;
    int hw0 = blockIdx.x * 64, c0 = blockIdx.y * 64, b = blockIdx.z & 7;
    int t = threadIdx.x, isbf = *flag;
    int c = t >> 2, x16 = (t & 3) * 16;
    size_t sbase = ((size_t)b * 256 + c0 + c) * 1024 + hw0 + x16;
#pragma unroll
    for (int j = 0; j < 16; ++j) T[c][x16 + j] = ldi(src, sbase + j, isbf);
    __syncthreads();
    int hw = t >> 2, c16 = (t & 3) * 16;
    bf16* dp = dst + ((size_t)(b << 10) + hw0 + hw) * 256 + c0 + c16;
#pragma unroll
    for (int j = 0; j < 16; ++j) dp[j] = __float2bfloat16(T[c16 + j][hw]);
}

// ---------------------------------------------------------------------------
// merged weight repack: conv3 (589824) + conv5 (1638400) + dw (9216)
__global__ __launch_bounds__(256) void repack_all(
    const void* __restrict__ W3, const void* __restrict__ W5,
    const void* __restrict__ Wdw, const int* __restrict__ flag,
    bf16* __restrict__ R3, bf16* __restrict__ R5, bf16* __restrict__ Rdw)
{
    int idx = blockIdx.x * 256 + threadIdx.x;
    int isbf = *flag;
    if (idx < 589824) {
        int ci = idx & 255, o = (idx >> 8) & 255, khkw = idx >> 16;
        int kh = khkw / 3, kw = khkw % 3;
        R3[idx] = __float2bfloat16(
            ldi(W3, (((size_t)o * 256 + ci) * 3 + kh) * 3 + kw, isbf));
    } else if (idx < 2228224) {
        int j = idx - 589824;
        int ci = j & 255, o = (j >> 8) & 255, khkw = j >> 16;
        int kh = khkw / 5, kw = khkw % 5;
        R5[j] = __float2bfloat16(
            ldi(W5, (((size_t)o * 256 + ci) * 5 + kh) * 5 + kw, isbf));
    } else {
        int j = idx - 2228224;
        int c = j & 1023, tap = j >> 10;
        Rdw[j] = __float2bfloat16(ldi(Wdw, (size_t)c * 9 + tap, isbf));
    }
}

// ---------------------------------------------------------------------------
// MFMA GEMM core, 64x64 tile, BK=64, 4 waves, register-prefetch pipeline.
// MA:[M][K], MB:[N][K] k-contig.
// modes: 0 NHWC(+R) / 1 CHW / 2 CHW-fp32+R / 3 qkv-split / 4 QK col-offset
// ---------------------------------------------------------------------------
static __device__ __forceinline__ void mgemm_core(
    const short* __restrict__ MA, const short* __restrict__ MB,
    bf16* __restrict__ Yb, float* __restrict__ Yf, bf16* __restrict__ Y2,
    const bf16* __restrict__ R, int K, int mode, int Ochan,
    short As[64][72], short Bs[64][72])
{
    int m0 = blockIdx.x * 64, n0 = blockIdx.y * 64;
    int t = threadIdx.x, lane = t & 63, wv = t >> 6;
    int l15 = lane & 15, quad = lane >> 4;
    int srow = t >> 2, scol = (t & 3) * 16;

    const short* pa = &MA[(size_t)(m0 + srow) * K + scol];
    const short* pb = &MB[(size_t)(n0 + srow) * K + scol];

    v4f acc[4] = {};
    v8s ra0 = *(const v8s*)&pa[0], ra1 = *(const v8s*)&pa[8];
    v8s rb0 = *(const v8s*)&pb[0], rb1 = *(const v8s*)&pb[8];

    for (int k0 = 0; k0 < K; k0 += 64) {
        if (k0) __syncthreads();
        *(v8s*)&As[srow][scol]     = ra0;
        *(v8s*)&As[srow][scol + 8] = ra1;
        *(v8s*)&Bs[srow][scol]     = rb0;
        *(v8s*)&Bs[srow][scol + 8] = rb1;
        __syncthreads();
        if (k0 + 64 < K) {
            ra0 = *(const v8s*)&pa[k0 + 64];
            ra1 = *(const v8s*)&pa[k0 + 72];
            rb0 = *(const v8s*)&pb[k0 + 64];
            rb1 = *(const v8s*)&pb[k0 + 72];
        }
#pragma unroll
        for (int kk = 0; kk < 2; ++kk) {
            v8s a = *(const v8s*)&As[wv * 16 + l15][kk * 32 + quad * 8];
#pragma unroll
            for (int nt = 0; nt < 4; ++nt) {
                v8s b = *(const v8s*)&Bs[nt * 16 + l15][kk * 32 + quad * 8];
                acc[nt] = __builtin_amdgcn_mfma_f32_16x16x32_bf16(a, b, acc[nt], 0, 0, 0);
            }
        }
    }

#pragma unroll
    for (int nt = 0; nt < 4; ++nt)
#pragma unroll
        for (int r = 0; r < 4; ++r) {
            int mm = m0 + wv * 16 + quad * 4 + r;
            int nn = n0 + nt * 16 + l15;
            float v = acc[nt][r];
            if (mode == 0) {
                size_t off = (size_t)mm * Ochan + nn;
                if (R) v += bf2f(R[off]);
                Yb[off] = __float2bfloat16(v);
            } else if (mode == 1) {
                Yb[((size_t)(nn >> 10) * Ochan + mm) * 1024 + (nn & 1023)] =
                    __float2bfloat16(v);
            } else if (mode == 2) {
                Yf[((size_t)(nn >> 10) * Ochan + mm) * 1024 + (nn & 1023)] =
                    v + bf2f(R[(size_t)nn * 256 + mm]);
            } else if (mode == 3) {
                if (mm < 512) Yb[(size_t)nn * 512 + mm] = __float2bfloat16(v);
                else Y2[((size_t)(nn >> 10) * 256 + (mm - 512)) * 1024 + (nn & 1023)] =
                         __float2bfloat16(v);
            } else {
                Yb[(size_t)nn * 512 + Ochan + mm] = __float2bfloat16(v);
            }
        }
}

__global__ __launch_bounds__(256) void mgemm(
    const short* __restrict__ MA, const short* __restrict__ MB,
    bf16* __restrict__ Yb, float* __restrict__ Yf, bf16* __restrict__ Y2,
    const bf16* __restrict__ R, int K, int mode, int Ochan)
{
    __shared__ short As[64][72], Bs[64][72];
    mgemm_core(MA, MB, Yb, Yf, Y2, R, K, mode, Ochan, As, Bs);
}

// z-dispatched merged GEMM (up to 3 independent problems, same x/y grid)
struct GA { const short* A; const short* B; bf16* Yb; float* Yf; bf16* Y2;
            const bf16* R; int K; int mode; int Oc; };
struct GA3 { GA g[3]; };

__global__ __launch_bounds__(256) void mgemm_z(GA3 P)
{
    __shared__ short As[64][72], Bs[64][72];
    const GA& a = P.g[blockIdx.z];
    mgemm_core(a.A, a.B, a.Yb, a.Yf, a.Y2, a.R, a.K, a.mode, a.Oc, As, Bs);
}

// ---------------------------------------------------------------------------
// MFMA conv core, same 64x64 / BK=64 prefetch skeleton, im2col A staging.
// ---------------------------------------------------------------------------
template <int KS, int PAD>
static __device__ __forceinline__ void mconv_core(
    const short* __restrict__ Xn, const short* __restrict__ Wr,
    bf16* __restrict__ Y, short As[64][72], short Bs[64][72])
{
    const int K = 256 * KS * KS;
    int p0 = blockIdx.x * 64, o0 = blockIdx.y * 64;
    int t = threadIdx.x, lane = t & 63, wv = t >> 6;
    int l15 = lane & 15, quad = lane >> 4;
    int srow = t >> 2, scol = (t & 3) * 16;

    int p  = p0 + srow;
    int hw = p & 1023, hh = hw >> 5, ww = hw & 31;
    size_t ib = ((size_t)(p >> 10)) << 10;

    v4f acc[4] = {};
    v8s ra0, ra1, rb0, rb1;

    {
        int hi = hh - PAD, wi = ww - PAD;
        v8s z = {0, 0, 0, 0, 0, 0, 0, 0};
        ra0 = z; ra1 = z;
        if ((unsigned)hi < 32u && (unsigned)wi < 32u) {
            const short* sa = &Xn[(ib + (hi << 5) + wi) * 256 + scol];
            ra0 = *(const v8s*)&sa[0];
            ra1 = *(const v8s*)&sa[8];
        }
        const short* sb = &Wr[((size_t)0 * 256 + o0 + srow) * 256 + scol];
        rb0 = *(const v8s*)&sb[0];
        rb1 = *(const v8s*)&sb[8];
    }

    for (int k0 = 0; k0 < K; k0 += 64) {
        if (k0) __syncthreads();
        *(v8s*)&As[srow][scol]     = ra0;
        *(v8s*)&As[srow][scol + 8] = ra1;
        *(v8s*)&Bs[srow][scol]     = rb0;
        *(v8s*)&Bs[srow][scol + 8] = rb1;
        __syncthreads();
        int kn = k0 + 64;
        if (kn < K) {
            int khkw = kn >> 8;
            int kh = khkw / KS, kw = khkw % KS;
            int hi = hh + kh - PAD, wi = ww + kw - PAD;
            int aci = (kn & 255) + scol;
            v8s z = {0, 0, 0, 0, 0, 0, 0, 0};
            ra0 = z; ra1 = z;
            if ((unsigned)hi < 32u && (unsigned)wi < 32u) {
                const short* sa = &Xn[(ib + (hi << 5) + wi) * 256 + aci];
                ra0 = *(const v8s*)&sa[0];
                ra1 = *(const v8s*)&sa[8];
            }
            const short* sb = &Wr[((size_t)khkw * 256 + o0 + srow) * 256 + (kn & 255) + scol];
            rb0 = *(const v8s*)&sb[0];
            rb1 = *(const v8s*)&sb[8];
        }
#pragma unroll
        for (int kk = 0; kk < 2; ++kk) {
            v8s a = *(const v8s*)&As[wv * 16 + l15][kk * 32 + quad * 8];
#pragma unroll
            for (int nt = 0; nt < 4; ++nt) {
                v8s b = *(const v8s*)&Bs[nt * 16 + l15][kk * 32 + quad * 8];
                acc[nt] = __builtin_amdgcn_mfma_f32_16x16x32_bf16(a, b, acc[nt], 0, 0, 0);
            }
        }
    }

#pragma unroll
    for (int nt = 0; nt < 4; ++nt)
#pragma unroll
        for (int r = 0; r < 4; ++r) {
            int pp = p0 + wv * 16 + quad * 4 + r;
            int oo = o0 + nt * 16 + l15;
            Y[(size_t)pp * 256 + oo] = __float2bfloat16(acc[nt][r]);
        }
}

// merged conv: z=0 -> 3x3 (q branch), z=1 -> 5x5 (kv branch)
__global__ __launch_bounds__(256) void mconv2(
    const short* __restrict__ Xa, const short* __restrict__ Wa, bf16* __restrict__ Ya,
    const short* __restrict__ Xb, const short* __restrict__ Wb, bf16* __restrict__ Yb)
{
    __shared__ short As[64][72], Bs[64][72];
    if (blockIdx.z == 0) mconv_core<3, 1>(Xa, Wa, Ya, As, Bs);
    else                 mconv_core<5, 2>(Xb, Wb, Yb, As, Bs);
}

// ---------------------------------------------------------------------------
// MFMA flash attention core, serial-chain-reduced softmax:
//  - li kept as per-lane partials, reduced once after the KV loop
//  - max-tree + rescale gated by __any(partial > mi): bit-exact skip
//  - setprio(1) around MFMA clusters
// ---------------------------------------------------------------------------
static __device__ __forceinline__ void attn_core(
    const bf16* __restrict__ QK, const bf16* __restrict__ V,
    bf16* __restrict__ Out, int b, int h, int n0, short Ps[4][16][72])
{
    int t = threadIdx.x, lane = t & 63, wv = t >> 6;
    int l15 = lane & 15, quad = lane >> 4;

    const short* qk = (const short*)QK;
    const short* vp = (const short*)V + ((size_t)b * 256 + h * 64) * 1024;

    size_t qrow = ((size_t)b * 1024 + n0 + wv * 16 + l15) * 512 + h * 64;
    v8s qf0 = *(const v8s*)&qk[qrow + quad * 8];
    v8s qf1 = *(const v8s*)&qk[qrow + 32 + quad * 8];

    v4f oacc[4] = {};
    float mi[4], li[4], nmiSC[4];
#pragma unroll
    for (int r = 0; r < 4; ++r) { mi[r] = -1e30f; li[r] = 0.f; nmiSC[r] = 0.f; }
    const float SC = 0.18033688011112042f;  // 0.125 * log2(e)

    for (int m0 = 0; m0 < 1024; m0 += 64) {
        // 1) QK^T
        v4f sacc[4];
        __builtin_amdgcn_s_setprio(1);
#pragma unroll
        for (int ct = 0; ct < 4; ++ct) {
            size_t krow = ((size_t)b * 1024 + m0 + ct * 16 + l15) * 512 + 256 + h * 64;
            v8s kf0 = *(const v8s*)&qk[krow + quad * 8];
            v8s kf1 = *(const v8s*)&qk[krow + 32 + quad * 8];
            v4f z = {0.f, 0.f, 0.f, 0.f};
            z = __builtin_amdgcn_mfma_f32_16x16x32_bf16(qf0, kf0, z, 0, 0, 0);
            z = __builtin_amdgcn_mfma_f32_16x16x32_bf16(qf1, kf1, z, 0, 0, 0);
            sacc[ct] = z;
        }
        __builtin_amdgcn_s_setprio(0);

        // 2) per-lane partial max; full tree + rescale only if any row grows
        float pr[4];
#pragma unroll
        for (int r = 0; r < 4; ++r)
            pr[r] = fmaxf(fmaxf(sacc[0][r], sacc[1][r]),
                          fmaxf(sacc[2][r], sacc[3][r]));
        bool grow = (pr[0] > mi[0]) | (pr[1] > mi[1]) |
                    (pr[2] > mi[2]) | (pr[3] > mi[3]);
        if (__any(grow)) {
#pragma unroll
            for (int mk = 1; mk <= 8; mk <<= 1)
#pragma unroll
                for (int r = 0; r < 4; ++r)
                    pr[r] = fmaxf(pr[r], __shfl_xor(pr[r], mk));
#pragma unroll
            for (int r = 0; r < 4; ++r) {
                float mn = fmaxf(mi[r], pr[r]);
                float al = exp2f((mi[r] - mn) * SC);
                mi[r] = mn;
                nmiSC[r] = -mn * SC;
                li[r] *= al;
#pragma unroll
                for (int dt = 0; dt < 4; ++dt) oacc[dt][r] *= al;
            }
        }

        // 3) exp + accumulate per-lane li partial + stage P to LDS
#pragma unroll
        for (int ct = 0; ct < 4; ++ct)
#pragma unroll
            for (int r = 0; r < 4; ++r) {
                float pvv = exp2f(fmaf(sacc[ct][r], SC, nmiSC[r]));
                li[r] += pvv;
                Ps[wv][quad * 4 + r][ct * 16 + l15] = (short)f2us(pvv);
            }

        // 4) PV
        v8s pf0 = *(const v8s*)&Ps[wv][l15][quad * 8];
        v8s pf1 = *(const v8s*)&Ps[wv][l15][32 + quad * 8];
        __builtin_amdgcn_s_setprio(1);
#pragma unroll
        for (int dt = 0; dt < 4; ++dt) {
            const short* vr = vp + (size_t)(dt * 16 + l15) * 1024 + m0;
            v8s vf0 = *(const v8s*)&vr[quad * 8];
            v8s vf1 = *(const v8s*)&vr[32 + quad * 8];
            oacc[dt] = __builtin_amdgcn_mfma_f32_16x16x32_bf16(pf0, vf0, oacc[dt], 0, 0, 0);
            oacc[dt] = __builtin_amdgcn_mfma_f32_16x16x32_bf16(pf1, vf1, oacc[dt], 0, 0, 0);
        }
        __builtin_amdgcn_s_setprio(0);
    }

    // deferred li reduction (once, instead of per-iteration)
#pragma unroll
    for (int mk = 1; mk <= 8; mk <<= 1)
#pragma unroll
        for (int r = 0; r < 4; ++r)
            li[r] += __shfl_xor(li[r], mk);

    float linv[4];
#pragma unroll
    for (int r = 0; r < 4; ++r) linv[r] = 1.0f / li[r];
    size_t pb = (size_t)b * 1024 + n0 + wv * 16;
#pragma unroll
    for (int dt = 0; dt < 4; ++dt)
#pragma unroll
        for (int r = 0; r < 4; ++r)
            Out[(pb + quad * 4 + r) * 256 + h * 64 + dt * 16 + l15] =
                __float2bfloat16(oacc[dt][r] * linv[r]);
}

// XCD-swizzled attention: flat 1D grid of NG*16 blocks; all 16 n0-tiles of
// one (b,h[,branch]) group land on one XCD so its 256KB K/V stays L2-hot.
// NG = number of (h, b[, branch]) groups (must be divisible by 8).
template <int NG>
__global__ __launch_bounds__(256) void attn_swz(
    const bf16* __restrict__ QK0, const bf16* __restrict__ V0, bf16* __restrict__ O0,
    const bf16* __restrict__ QK1, const bf16* __restrict__ V1, bf16* __restrict__ O1)
{
    __shared__ short Ps[4][16][72];
    int i = blockIdx.x;
    int xcd = i & 7, idx = i >> 3;
    int g = xcd * (NG / 8) + (idx >> 4);     // group id, bijective remap
    int n0 = (idx & 15) * 64;
    int h = g & 3, zz = g >> 2;
    int b = zz & 7;
    if (zz < 8) attn_core(QK0, V0, O0, b, h, n0, Ps);
    else        attn_core(QK1, V1, O1, b, h, n0, Ps);
}

// ---------------------------------------------------------------------------
static __device__ __forceinline__ void ln_row(
    const bf16* __restrict__ X, const bf16* __restrict__ g,
    const bf16* __restrict__ be, bf16* __restrict__ Y, size_t p)
{
    int lane = threadIdx.x & 63;
    const ushort4 u = *(const ushort4*)(X + p * 256 + lane * 4);
    float v0 = us2f(u.x), v1 = us2f(u.y), v2 = us2f(u.z), v3 = us2f(u.w);
    float s = v0 + v1 + v2 + v3;
    float ss = v0 * v0 + v1 * v1 + v2 * v2 + v3 * v3;
#pragma unroll
    for (int off = 32; off; off >>= 1) {
        s  += __shfl_xor(s, off);
        ss += __shfl_xor(ss, off);
    }
    float mu   = s * (1.0f / 256.0f);
    float var  = ss * (1.0f / 256.0f) - mu * mu;
    float rstd = rsqrtf(fmaxf(var, 0.0f) + 1e-5f);
    const ushort4 gu = *(const ushort4*)((const unsigned short*)g + lane * 4);
    const ushort4 bu = *(const ushort4*)((const unsigned short*)be + lane * 4);
    ushort4 o;
    o.x = f2us((v0 - mu) * rstd * us2f(gu.x) + us2f(bu.x));
    o.y = f2us((v1 - mu) * rstd * us2f(gu.y) + us2f(bu.y));
    o.z = f2us((v2 - mu) * rstd * us2f(gu.z) + us2f(bu.z));
    o.w = f2us((v3 - mu) * rstd * us2f(gu.w) + us2f(bu.w));
    *(ushort4*)(Y + p * 256 + lane * 4) = o;
}

__global__ __launch_bounds__(256) void ln_nhwc(
    const bf16* __restrict__ X, const bf16* __restrict__ g,
    const bf16* __restrict__ be, bf16* __restrict__ Y)
{
    int wv = threadIdx.x >> 6;
    ln_row(X, g, be, Y, (size_t)blockIdx.x * 4 + wv);
}

// merged LN for both branches: blocks [0,2048) -> set0, [2048,4096) -> set1
__global__ __launch_bounds__(256) void ln_nhwc2(
    const bf16* __restrict__ X0, const bf16* __restrict__ g0,
    const bf16* __restrict__ b0, bf16* __restrict__ Y0,
    const bf16* __restrict__ X1, const bf16* __restrict__ g1,
    const bf16* __restrict__ b1, bf16* __restrict__ Y1)
{
    int wv = threadIdx.x >> 6;
    int sel = blockIdx.x >> 11;
    size_t p = (size_t)(blockIdx.x & 2047) * 4 + wv;
    if (sel == 0) ln_row(X0, g0, b0, Y0, p);
    else          ln_row(X1, g1, b1, Y1, p);
}

// ---------------------------------------------------------------------------
__global__ __launch_bounds__(256) void dwgelu_nhwc(
    const bf16* __restrict__ H, const bf16* __restrict__ Wr,
    bf16* __restrict__ Y)
{
    int idx = blockIdx.x * 256 + threadIdx.x;
    int p = idx >> 7, c8 = (idx & 127) * 8;
    int hw = p & 1023, hh = hw >> 5, ww = hw & 31;
    size_t ib = ((size_t)(p >> 10)) << 10;
    float acc[8] = {};
#pragma unroll
    for (int kh = 0; kh < 3; ++kh)
#pragma unroll
        for (int kw = 0; kw < 3; ++kw) {
            int hi = hh + kh - 1, wi = ww + kw - 1;
            if ((unsigned)hi < 32u && (unsigned)wi < 32u) {
                v8s hv = *(const v8s*)((const short*)H + (ib + (hi << 5) + wi) * 1024 + c8);
                v8s wvv = *(const v8s*)((const short*)Wr + (kh * 3 + kw) * 1024 + c8);
#pragma unroll
                for (int j = 0; j < 8; ++j)
                    acc[j] = fmaf(us2f((unsigned short)wvv[j]),
                                  us2f((unsigned short)hv[j]), acc[j]);
            }
        }
    short ov[8];
#pragma unroll
    for (int j = 0; j < 8; ++j) {
        float x = acc[j];
        ov[j] = (short)f2us(0.5f * x * (1.0f + erff(x * 0.70710678118654752f)));
    }
    v8s o = {ov[0], ov[1], ov[2], ov[3], ov[4], ov[5], ov[6], ov[7]};
    *(v8s*)((short*)Y + (size_t)p * 1024 + c8) = o;
}

// ---------------------------------------------------------------------------
extern "C" void kernel_launch(void* const* d_in, const int* in_sizes, int n_in,
                              void* d_out, int out_size, void* d_ws, size_t ws_size,
                              hipStream_t stream)
{
    static const int  lidx[20] = {4,5,6,7,8,9,10,11,12,13,14,15,16,17,18,19,20,21,22,24};
    static const unsigned lsz[20] = {256,256,256,256,256,256,256,256,256,256,
                                     196608,65536,196608,65536,
                                     65536,65536,65536,65536,262144,262144};
    CvtArgs args;
    unsigned pre[21]; pre[0] = 0;
    for (int i = 0; i < 20; ++i) {
        args.src[i] = d_in[lidx[i]];
        pre[i + 1] = pre[i] + lsz[i];
    }
    for (int i = 0; i < 21; ++i) args.off[i] = pre[i];
    const unsigned ltot = pre[20];

    int*  flag  = (int*)d_ws;
    bf16* canon = (bf16*)d_ws + 128;
    bf16* cn[25];
    for (int i = 0; i < 20; ++i) cn[lidx[i]] = canon + pre[i];

    bf16* Wr3  = canon + ltot;
    bf16* Wr5  = Wr3 + 589824;
    bf16* Wdwr = Wr5 + 1638400;
    const size_t SZ = 2097152;
    bf16* slab = Wdwr + 9216;
    bf16* qb   = slab + 0 * SZ;                    // q_branch -> x (NHWC)
    bf16* kvb  = slab + 1 * SZ;
    bf16* t0   = slab + 2 * SZ;                    // branch-0 scratch
    bf16* q    = slab + 3 * SZ;
    bf16* kv   = slab + 4 * SZ;
    bf16* QKb  = slab + 5 * SZ;                    // 2 slots: [8192][512]
    bf16* Vb   = slab + 7 * SZ;                    // 1 slot: CHW
    bf16* t1   = slab + 8 * SZ;                    // branch-1 scratch
    bf16* QK2  = slab + 9 * SZ;                    // 2 slots (branch 1)
    bf16* V2   = slab + 11 * SZ;                   // 1 slot (branch 1)
    bf16* aopT = slab + 9 * SZ;                    // pre-SA reuse of QK2
    bf16* dopT = slab + 10 * SZ;
    bf16* hb   = slab + 3 * SZ;                    // LeFF: slots 3-6 (q..QKb dead)
    bf16* h2   = slab + 7 * SZ;                    // LeFF: slots 7-10 (Vb..QK2 dead)
    float* out = (float*)d_out;

    dim3 blk(256);
    auto S = [](const bf16* p) { return (const short*)p; };

    detect_kernel<<<1, 64, 0, stream>>>((const unsigned short*)d_in[4], flag);
    cvt_lin<<<ltot / 256, blk, 0, stream>>>(args, flag, canon);
    tcvt2<<<dim3(16, 4, 16), blk, 0, stream>>>(d_in[0], d_in[1], flag, aopT, dopT);
    repack_all<<<8740, blk, 0, stream>>>(d_in[2], d_in[3], d_in[23], flag, Wr3, Wr5, Wdwr);

    // both branch convs in one launch (z=0: 3x3->qb, z=1: 5x5->kvb)
    mconv2<<<dim3(128, 4, 2), blk, 0, stream>>>(S(aopT), (const short*)Wr3, qb,
                                                S(dopT), (const short*)Wr5, kvb);

    // merged self-attention pipelines (q branch = set0, kv branch = set1)
    ln_nhwc2<<<4096, blk, 0, stream>>>(qb, cn[4], cn[5], t0,
                                       kvb, cn[6], cn[7], t1);
    GA3 P;
    P.g[0] = GA{S(cn[14]), S(t0), QKb, nullptr, Vb, nullptr, 256, 3, 0};
    P.g[1] = GA{S(cn[16]), S(t1), QK2, nullptr, V2, nullptr, 256, 3, 0};
    P.g[2] = P.g[1];
    mgemm_z<<<dim3(12, 128, 2), blk, 0, stream>>>(P);

    attn_swz<64><<<1024, blk, 0, stream>>>(QKb, Vb, t0, QK2, V2, t1);

    P.g[0] = GA{S(t0), S(cn[15]), qb, nullptr, nullptr, qb, 256, 0, 256};
    P.g[1] = GA{S(t1), S(cn[17]), kvb, nullptr, nullptr, kvb, 256, 0, 256};
    P.g[2] = P.g[1];
    mgemm_z<<<dim3(128, 4, 2), blk, 0, stream>>>(P);

    ln_nhwc2<<<4096, blk, 0, stream>>>(qb, cn[8], cn[9], q,
                                       kvb, cn[10], cn[11], kv);

    // cross attention: 3 projection GEMMs in one launch
    P.g[0] = GA{S(cn[18]), S(q),  QKb, nullptr, nullptr, nullptr, 256, 4, 0};
    P.g[1] = GA{S(cn[19]), S(kv), QKb, nullptr, nullptr, nullptr, 256, 4, 256};
    P.g[2] = GA{S(cn[20]), S(kv), Vb,  nullptr, nullptr, nullptr, 256, 1, 256};
    mgemm_z<<<dim3(4, 128, 3), blk, 0, stream>>>(P);

    attn_swz<32><<<512, blk, 0, stream>>>(QKb, Vb, t0, QKb, Vb, t0);
    mgemm<<<dim3(128, 4), blk, 0, stream>>>(S(t0), S(cn[21]), qb, nullptr, nullptr, qb, 256, 0, 256);

    // LeFF
    ln_nhwc<<<2048, blk, 0, stream>>>(qb, cn[12], cn[13], t0);
    mgemm<<<dim3(128, 16), blk, 0, stream>>>(S(t0), S(cn[22]), hb, nullptr, nullptr, nullptr, 256, 0, 1024);
    dwgelu_nhwc<<<4096, blk, 0, stream>>>(hb, Wdwr, h2);
    mgemm<<<dim3(4, 128), blk, 0, stream>>>(S(cn[24]), S(h2), nullptr, out, nullptr, qb, 1024, 2, 256);
}

// Round 5
// 438.161 us; speedup vs baseline: 1.3230x; 1.1998x over previous
//
#include <hip/hip_runtime.h>
#include <hip/hip_bf16.h>

// DCSA block, round 15: r14 staging-coverage bugfix.
// r14 NaN root cause: cooperative K/V staging wrote only ONE v8s (8 shorts)
// per thread per buffer, but 64x64 tile / 256 threads requires 16 shorts
// per thread (two v8s, like mgemm_core's ra0/ra1). Columns scol+8..scol+15
// of every LDS row were uninitialized -> NaN. Fix: rk0/rk1 + rv0/rv1.
// Everything else identical to r14 (LDS-staged K/V, XCD swizzle, r13 softmax).

using bf16 = __hip_bfloat16;
typedef short v8s __attribute__((ext_vector_type(8)));
typedef float v4f  __attribute__((ext_vector_type(4)));

static __device__ __forceinline__ float bf2f(bf16 x) { return __bfloat162float(x); }
static __device__ __forceinline__ float us2f(unsigned short u)
{ union { unsigned int i; float f; } x; x.i = ((unsigned)u) << 16; return x.f; }
static __device__ __forceinline__ unsigned short f2us(float f)
{ bf16 h = __float2bfloat16(f); return *(unsigned short*)&h; }
static __device__ __forceinline__ float ldi(const void* p, size_t i, int isbf)
{ return isbf ? bf2f(((const bf16*)p)[i]) : ((const float*)p)[i]; }

// ---------------------------------------------------------------------------
__global__ void detect_kernel(const unsigned short* p, int* flag)
{
    if (threadIdx.x == 0 && blockIdx.x == 0)
        *flag = (p[0] == 0x3F80) ? 1 : 0;
}

// ---------------------------------------------------------------------------
struct CvtArgs { const void* src[20]; unsigned off[21]; };

__global__ __launch_bounds__(256) void cvt_lin(CvtArgs a, const int* __restrict__ flag,
                                               bf16* __restrict__ dst)
{
    unsigned e = blockIdx.x * 256u + threadIdx.x;
    int isbf = *flag;
    int s = 0;
    while (e >= a.off[s + 1]) ++s;
    dst[e] = __float2bfloat16(ldi(a.src[s], e - a.off[s], isbf));
}

// ---------------------------------------------------------------------------
// merged NCHW->NHWC transpose for both feature maps (z<8: aop, z>=8: dop)
__global__ __launch_bounds__(256) void tcvt2(const void* __restrict__ s0,
                                             const void* __restrict__ s1,
                                             const int* __restrict__ flag,
                                             bf16* __restrict__ d0,
                                             bf16* __restrict__ d1)
{
    __shared__ float T[64][65];
    const void* src = (blockIdx.z < 8) ? s0 : s1;
    bf16* dst       = (blockIdx.z < 8) ? d0 : d1;
    int hw0 = blockIdx.x * 64, c0 = blockIdx.y * 64, b = blockIdx.z & 7;
    int t = threadIdx.x, isbf = *flag;
    int c = t >> 2, x16 = (t & 3) * 16;
    size_t sbase = ((size_t)b * 256 + c0 + c) * 1024 + hw0 + x16;
#pragma unroll
    for (int j = 0; j < 16; ++j) T[c][x16 + j] = ldi(src, sbase + j, isbf);
    __syncthreads();
    int hw = t >> 2, c16 = (t & 3) * 16;
    bf16* dp = dst + ((size_t)(b << 10) + hw0 + hw) * 256 + c0 + c16;
#pragma unroll
    for (int j = 0; j < 16; ++j) dp[j] = __float2bfloat16(T[c16 + j][hw]);
}

// ---------------------------------------------------------------------------
// merged weight repack: conv3 (589824) + conv5 (1638400) + dw (9216)
__global__ __launch_bounds__(256) void repack_all(
    const void* __restrict__ W3, const void* __restrict__ W5,
    const void* __restrict__ Wdw, const int* __restrict__ flag,
    bf16* __restrict__ R3, bf16* __restrict__ R5, bf16* __restrict__ Rdw)
{
    int idx = blockIdx.x * 256 + threadIdx.x;
    int isbf = *flag;
    if (idx < 589824) {
        int ci = idx & 255, o = (idx >> 8) & 255, khkw = idx >> 16;
        int kh = khkw / 3, kw = khkw % 3;
        R3[idx] = __float2bfloat16(
            ldi(W3, (((size_t)o * 256 + ci) * 3 + kh) * 3 + kw, isbf));
    } else if (idx < 2228224) {
        int j = idx - 589824;
        int ci = j & 255, o = (j >> 8) & 255, khkw = j >> 16;
        int kh = khkw / 5, kw = khkw % 5;
        R5[j] = __float2bfloat16(
            ldi(W5, (((size_t)o * 256 + ci) * 5 + kh) * 5 + kw, isbf));
    } else {
        int j = idx - 2228224;
        int c = j & 1023, tap = j >> 10;
        Rdw[j] = __float2bfloat16(ldi(Wdw, (size_t)c * 9 + tap, isbf));
    }
}

// ---------------------------------------------------------------------------
// MFMA GEMM core, 64x64 tile, BK=64, 4 waves, register-prefetch pipeline.
// MA:[M][K], MB:[N][K] k-contig.
// modes: 0 NHWC(+R) / 1 CHW / 2 CHW-fp32+R / 3 qkv-split / 4 QK col-offset
// ---------------------------------------------------------------------------
static __device__ __forceinline__ void mgemm_core(
    const short* __restrict__ MA, const short* __restrict__ MB,
    bf16* __restrict__ Yb, float* __restrict__ Yf, bf16* __restrict__ Y2,
    const bf16* __restrict__ R, int K, int mode, int Ochan,
    short As[64][72], short Bs[64][72])
{
    int m0 = blockIdx.x * 64, n0 = blockIdx.y * 64;
    int t = threadIdx.x, lane = t & 63, wv = t >> 6;
    int l15 = lane & 15, quad = lane >> 4;
    int srow = t >> 2, scol = (t & 3) * 16;

    const short* pa = &MA[(size_t)(m0 + srow) * K + scol];
    const short* pb = &MB[(size_t)(n0 + srow) * K + scol];

    v4f acc[4] = {};
    v8s ra0 = *(const v8s*)&pa[0], ra1 = *(const v8s*)&pa[8];
    v8s rb0 = *(const v8s*)&pb[0], rb1 = *(const v8s*)&pb[8];

    for (int k0 = 0; k0 < K; k0 += 64) {
        if (k0) __syncthreads();
        *(v8s*)&As[srow][scol]     = ra0;
        *(v8s*)&As[srow][scol + 8] = ra1;
        *(v8s*)&Bs[srow][scol]     = rb0;
        *(v8s*)&Bs[srow][scol + 8] = rb1;
        __syncthreads();
        if (k0 + 64 < K) {
            ra0 = *(const v8s*)&pa[k0 + 64];
            ra1 = *(const v8s*)&pa[k0 + 72];
            rb0 = *(const v8s*)&pb[k0 + 64];
            rb1 = *(const v8s*)&pb[k0 + 72];
        }
#pragma unroll
        for (int kk = 0; kk < 2; ++kk) {
            v8s a = *(const v8s*)&As[wv * 16 + l15][kk * 32 + quad * 8];
#pragma unroll
            for (int nt = 0; nt < 4; ++nt) {
                v8s b = *(const v8s*)&Bs[nt * 16 + l15][kk * 32 + quad * 8];
                acc[nt] = __builtin_amdgcn_mfma_f32_16x16x32_bf16(a, b, acc[nt], 0, 0, 0);
            }
        }
    }

#pragma unroll
    for (int nt = 0; nt < 4; ++nt)
#pragma unroll
        for (int r = 0; r < 4; ++r) {
            int mm = m0 + wv * 16 + quad * 4 + r;
            int nn = n0 + nt * 16 + l15;
            float v = acc[nt][r];
            if (mode == 0) {
                size_t off = (size_t)mm * Ochan + nn;
                if (R) v += bf2f(R[off]);
                Yb[off] = __float2bfloat16(v);
            } else if (mode == 1) {
                Yb[((size_t)(nn >> 10) * Ochan + mm) * 1024 + (nn & 1023)] =
                    __float2bfloat16(v);
            } else if (mode == 2) {
                Yf[((size_t)(nn >> 10) * Ochan + mm) * 1024 + (nn & 1023)] =
                    v + bf2f(R[(size_t)nn * 256 + mm]);
            } else if (mode == 3) {
                if (mm < 512) Yb[(size_t)nn * 512 + mm] = __float2bfloat16(v);
                else Y2[((size_t)(nn >> 10) * 256 + (mm - 512)) * 1024 + (nn & 1023)] =
                         __float2bfloat16(v);
            } else {
                Yb[(size_t)nn * 512 + Ochan + mm] = __float2bfloat16(v);
            }
        }
}

__global__ __launch_bounds__(256) void mgemm(
    const short* __restrict__ MA, const short* __restrict__ MB,
    bf16* __restrict__ Yb, float* __restrict__ Yf, bf16* __restrict__ Y2,
    const bf16* __restrict__ R, int K, int mode, int Ochan)
{
    __shared__ short As[64][72], Bs[64][72];
    mgemm_core(MA, MB, Yb, Yf, Y2, R, K, mode, Ochan, As, Bs);
}

// z-dispatched merged GEMM (up to 3 independent problems, same x/y grid)
struct GA { const short* A; const short* B; bf16* Yb; float* Yf; bf16* Y2;
            const bf16* R; int K; int mode; int Oc; };
struct GA3 { GA g[3]; };

__global__ __launch_bounds__(256) void mgemm_z(GA3 P)
{
    __shared__ short As[64][72], Bs[64][72];
    const GA& a = P.g[blockIdx.z];
    mgemm_core(a.A, a.B, a.Yb, a.Yf, a.Y2, a.R, a.K, a.mode, a.Oc, As, Bs);
}

// ---------------------------------------------------------------------------
// MFMA conv core, same 64x64 / BK=64 prefetch skeleton, im2col A staging.
// ---------------------------------------------------------------------------
template <int KS, int PAD>
static __device__ __forceinline__ void mconv_core(
    const short* __restrict__ Xn, const short* __restrict__ Wr,
    bf16* __restrict__ Y, short As[64][72], short Bs[64][72])
{
    const int K = 256 * KS * KS;
    int p0 = blockIdx.x * 64, o0 = blockIdx.y * 64;
    int t = threadIdx.x, lane = t & 63, wv = t >> 6;
    int l15 = lane & 15, quad = lane >> 4;
    int srow = t >> 2, scol = (t & 3) * 16;

    int p  = p0 + srow;
    int hw = p & 1023, hh = hw >> 5, ww = hw & 31;
    size_t ib = ((size_t)(p >> 10)) << 10;

    v4f acc[4] = {};
    v8s ra0, ra1, rb0, rb1;

    {
        int hi = hh - PAD, wi = ww - PAD;
        v8s z = {0, 0, 0, 0, 0, 0, 0, 0};
        ra0 = z; ra1 = z;
        if ((unsigned)hi < 32u && (unsigned)wi < 32u) {
            const short* sa = &Xn[(ib + (hi << 5) + wi) * 256 + scol];
            ra0 = *(const v8s*)&sa[0];
            ra1 = *(const v8s*)&sa[8];
        }
        const short* sb = &Wr[((size_t)0 * 256 + o0 + srow) * 256 + scol];
        rb0 = *(const v8s*)&sb[0];
        rb1 = *(const v8s*)&sb[8];
    }

    for (int k0 = 0; k0 < K; k0 += 64) {
        if (k0) __syncthreads();
        *(v8s*)&As[srow][scol]     = ra0;
        *(v8s*)&As[srow][scol + 8] = ra1;
        *(v8s*)&Bs[srow][scol]     = rb0;
        *(v8s*)&Bs[srow][scol + 8] = rb1;
        __syncthreads();
        int kn = k0 + 64;
        if (kn < K) {
            int khkw = kn >> 8;
            int kh = khkw / KS, kw = khkw % KS;
            int hi = hh + kh - PAD, wi = ww + kw - PAD;
            int aci = (kn & 255) + scol;
            v8s z = {0, 0, 0, 0, 0, 0, 0, 0};
            ra0 = z; ra1 = z;
            if ((unsigned)hi < 32u && (unsigned)wi < 32u) {
                const short* sa = &Xn[(ib + (hi << 5) + wi) * 256 + aci];
                ra0 = *(const v8s*)&sa[0];
                ra1 = *(const v8s*)&sa[8];
            }
            const short* sb = &Wr[((size_t)khkw * 256 + o0 + srow) * 256 + (kn & 255) + scol];
            rb0 = *(const v8s*)&sb[0];
            rb1 = *(const v8s*)&sb[8];
        }
#pragma unroll
        for (int kk = 0; kk < 2; ++kk) {
            v8s a = *(const v8s*)&As[wv * 16 + l15][kk * 32 + quad * 8];
#pragma unroll
            for (int nt = 0; nt < 4; ++nt) {
                v8s b = *(const v8s*)&Bs[nt * 16 + l15][kk * 32 + quad * 8];
                acc[nt] = __builtin_amdgcn_mfma_f32_16x16x32_bf16(a, b, acc[nt], 0, 0, 0);
            }
        }
    }

#pragma unroll
    for (int nt = 0; nt < 4; ++nt)
#pragma unroll
        for (int r = 0; r < 4; ++r) {
            int pp = p0 + wv * 16 + quad * 4 + r;
            int oo = o0 + nt * 16 + l15;
            Y[(size_t)pp * 256 + oo] = __float2bfloat16(acc[nt][r]);
        }
}

// merged conv: z=0 -> 3x3 (q branch), z=1 -> 5x5 (kv branch)
__global__ __launch_bounds__(256) void mconv2(
    const short* __restrict__ Xa, const short* __restrict__ Wa, bf16* __restrict__ Ya,
    const short* __restrict__ Xb, const short* __restrict__ Wb, bf16* __restrict__ Yb)
{
    __shared__ short As[64][72], Bs[64][72];
    if (blockIdx.z == 0) mconv_core<3, 1>(Xa, Wa, Ya, As, Bs);
    else                 mconv_core<5, 2>(Xb, Wb, Yb, As, Bs);
}

// ---------------------------------------------------------------------------
// MFMA flash attention core, LDS-staged K/V tiles (fixed full coverage):
//  each thread stages 16 shorts per buffer (two v8s), covering the full
//  64x64 tile with 256 threads, + next-tile register prefetch.
//  Softmax identical to r13 (deferred li, gated max-tree, setprio).
// ---------------------------------------------------------------------------
static __device__ __forceinline__ void attn_core(
    const bf16* __restrict__ QK, const bf16* __restrict__ V,
    bf16* __restrict__ Out, int b, int h, int n0,
    short Ps[4][16][72], short Ks[64][72], short Vs[64][72])
{
    int t = threadIdx.x, lane = t & 63, wv = t >> 6;
    int l15 = lane & 15, quad = lane >> 4;
    int srow = t >> 2, scol = (t & 3) * 16;

    const short* qk = (const short*)QK;
    const short* vp = (const short*)V + ((size_t)b * 256 + h * 64) * 1024;

    size_t qrow = ((size_t)b * 1024 + n0 + wv * 16 + l15) * 512 + h * 64;
    v8s qf0 = *(const v8s*)&qk[qrow + quad * 8];
    v8s qf1 = *(const v8s*)&qk[qrow + 32 + quad * 8];

    v4f oacc[4] = {};
    float mi[4], li[4], nmiSC[4];
#pragma unroll
    for (int r = 0; r < 4; ++r) { mi[r] = -1e30f; li[r] = 0.f; nmiSC[r] = 0.f; }
    const float SC = 0.18033688011112042f;  // 0.125 * log2(e)

    // staging source addresses (thread t covers row srow, cols scol..scol+15)
    const short* kbase = &qk[((size_t)b * 1024 + srow) * 512 + 256 + h * 64 + scol];
    const short* vbase = vp + (size_t)srow * 1024 + scol;

    // prefetch tile m0=0 (two v8s per buffer = full 16-short coverage)
    v8s rk0 = *(const v8s*)&kbase[0], rk1 = *(const v8s*)&kbase[8];
    v8s rv0 = *(const v8s*)&vbase[0], rv1 = *(const v8s*)&vbase[8];

    for (int m0 = 0; m0 < 1024; m0 += 64) {
        if (m0) __syncthreads();
        *(v8s*)&Ks[srow][scol]     = rk0;
        *(v8s*)&Ks[srow][scol + 8] = rk1;
        *(v8s*)&Vs[srow][scol]     = rv0;
        *(v8s*)&Vs[srow][scol + 8] = rv1;
        __syncthreads();
        if (m0 + 64 < 1024) {
            rk0 = *(const v8s*)&kbase[(size_t)(m0 + 64) * 512];
            rk1 = *(const v8s*)&kbase[(size_t)(m0 + 64) * 512 + 8];
            rv0 = *(const v8s*)&vbase[m0 + 64];
            rv1 = *(const v8s*)&vbase[m0 + 72];
        }

        // 1) QK^T from LDS K fragments
        v4f sacc[4];
        __builtin_amdgcn_s_setprio(1);
#pragma unroll
        for (int ct = 0; ct < 4; ++ct) {
            v8s kf0 = *(const v8s*)&Ks[ct * 16 + l15][quad * 8];
            v8s kf1 = *(const v8s*)&Ks[ct * 16 + l15][32 + quad * 8];
            v4f z = {0.f, 0.f, 0.f, 0.f};
            z = __builtin_amdgcn_mfma_f32_16x16x32_bf16(qf0, kf0, z, 0, 0, 0);
            z = __builtin_amdgcn_mfma_f32_16x16x32_bf16(qf1, kf1, z, 0, 0, 0);
            sacc[ct] = z;
        }
        __builtin_amdgcn_s_setprio(0);

        // 2) per-lane partial max; full tree + rescale only if any row grows
        float pr[4];
#pragma unroll
        for (int r = 0; r < 4; ++r)
            pr[r] = fmaxf(fmaxf(sacc[0][r], sacc[1][r]),
                          fmaxf(sacc[2][r], sacc[3][r]));
        bool grow = (pr[0] > mi[0]) | (pr[1] > mi[1]) |
                    (pr[2] > mi[2]) | (pr[3] > mi[3]);
        if (__any(grow)) {
#pragma unroll
            for (int mk = 1; mk <= 8; mk <<= 1)
#pragma unroll
                for (int r = 0; r < 4; ++r)
                    pr[r] = fmaxf(pr[r], __shfl_xor(pr[r], mk));
#pragma unroll
            for (int r = 0; r < 4; ++r) {
                float mn = fmaxf(mi[r], pr[r]);
                float al = exp2f((mi[r] - mn) * SC);
                mi[r] = mn;
                nmiSC[r] = -mn * SC;
                li[r] *= al;
#pragma unroll
                for (int dt = 0; dt < 4; ++dt) oacc[dt][r] *= al;
            }
        }

        // 3) exp + accumulate per-lane li partial + stage P to LDS
#pragma unroll
        for (int ct = 0; ct < 4; ++ct)
#pragma unroll
            for (int r = 0; r < 4; ++r) {
                float pvv = exp2f(fmaf(sacc[ct][r], SC, nmiSC[r]));
                li[r] += pvv;
                Ps[wv][quad * 4 + r][ct * 16 + l15] = (short)f2us(pvv);
            }

        // 4) PV from LDS V fragments
        v8s pf0 = *(const v8s*)&Ps[wv][l15][quad * 8];
        v8s pf1 = *(const v8s*)&Ps[wv][l15][32 + quad * 8];
        __builtin_amdgcn_s_setprio(1);
#pragma unroll
        for (int dt = 0; dt < 4; ++dt) {
            v8s vf0 = *(const v8s*)&Vs[dt * 16 + l15][quad * 8];
            v8s vf1 = *(const v8s*)&Vs[dt * 16 + l15][32 + quad * 8];
            oacc[dt] = __builtin_amdgcn_mfma_f32_16x16x32_bf16(pf0, vf0, oacc[dt], 0, 0, 0);
            oacc[dt] = __builtin_amdgcn_mfma_f32_16x16x32_bf16(pf1, vf1, oacc[dt], 0, 0, 0);
        }
        __builtin_amdgcn_s_setprio(0);
    }

    // deferred li reduction (once, instead of per-iteration)
#pragma unroll
    for (int mk = 1; mk <= 8; mk <<= 1)
#pragma unroll
        for (int r = 0; r < 4; ++r)
            li[r] += __shfl_xor(li[r], mk);

    float linv[4];
#pragma unroll
    for (int r = 0; r < 4; ++r) linv[r] = 1.0f / li[r];
    size_t pb = (size_t)b * 1024 + n0 + wv * 16;
#pragma unroll
    for (int dt = 0; dt < 4; ++dt)
#pragma unroll
        for (int r = 0; r < 4; ++r)
            Out[(pb + quad * 4 + r) * 256 + h * 64 + dt * 16 + l15] =
                __float2bfloat16(oacc[dt][r] * linv[r]);
}

// XCD-swizzled attention: flat 1D grid of NG*16 blocks; all 16 n0-tiles of
// one (b,h[,branch]) group land on one XCD so its 256KB K/V stays L2-hot.
// NG = number of (h, b[, branch]) groups (must be divisible by 8).
template <int NG>
__global__ __launch_bounds__(256) void attn_swz(
    const bf16* __restrict__ QK0, const bf16* __restrict__ V0, bf16* __restrict__ O0,
    const bf16* __restrict__ QK1, const bf16* __restrict__ V1, bf16* __restrict__ O1)
{
    __shared__ short Ps[4][16][72];
    __shared__ short Ks[64][72], Vs[64][72];
    int i = blockIdx.x;
    int xcd = i & 7, idx = i >> 3;
    int g = xcd * (NG / 8) + (idx >> 4);     // group id, bijective remap
    int n0 = (idx & 15) * 64;
    int h = g & 3, zz = g >> 2;
    int b = zz & 7;
    if (zz < 8) attn_core(QK0, V0, O0, b, h, n0, Ps, Ks, Vs);
    else        attn_core(QK1, V1, O1, b, h, n0, Ps, Ks, Vs);
}

// ---------------------------------------------------------------------------
static __device__ __forceinline__ void ln_row(
    const bf16* __restrict__ X, const bf16* __restrict__ g,
    const bf16* __restrict__ be, bf16* __restrict__ Y, size_t p)
{
    int lane = threadIdx.x & 63;
    const ushort4 u = *(const ushort4*)(X + p * 256 + lane * 4);
    float v0 = us2f(u.x), v1 = us2f(u.y), v2 = us2f(u.z), v3 = us2f(u.w);
    float s = v0 + v1 + v2 + v3;
    float ss = v0 * v0 + v1 * v1 + v2 * v2 + v3 * v3;
#pragma unroll
    for (int off = 32; off; off >>= 1) {
        s  += __shfl_xor(s, off);
        ss += __shfl_xor(ss, off);
    }
    float mu   = s * (1.0f / 256.0f);
    float var  = ss * (1.0f / 256.0f) - mu * mu;
    float rstd = rsqrtf(fmaxf(var, 0.0f) + 1e-5f);
    const ushort4 gu = *(const ushort4*)((const unsigned short*)g + lane * 4);
    const ushort4 bu = *(const ushort4*)((const unsigned short*)be + lane * 4);
    ushort4 o;
    o.x = f2us((v0 - mu) * rstd * us2f(gu.x) + us2f(bu.x));
    o.y = f2us((v1 - mu) * rstd * us2f(gu.y) + us2f(bu.y));
    o.z = f2us((v2 - mu) * rstd * us2f(gu.z) + us2f(bu.z));
    o.w = f2us((v3 - mu) * rstd * us2f(gu.w) + us2f(bu.w));
    *(ushort4*)(Y + p * 256 + lane * 4) = o;
}

__global__ __launch_bounds__(256) void ln_nhwc(
    const bf16* __restrict__ X, const bf16* __restrict__ g,
    const bf16* __restrict__ be, bf16* __restrict__ Y)
{
    int wv = threadIdx.x >> 6;
    ln_row(X, g, be, Y, (size_t)blockIdx.x * 4 + wv);
}

// merged LN for both branches: blocks [0,2048) -> set0, [2048,4096) -> set1
__global__ __launch_bounds__(256) void ln_nhwc2(
    const bf16* __restrict__ X0, const bf16* __restrict__ g0,
    const bf16* __restrict__ b0, bf16* __restrict__ Y0,
    const bf16* __restrict__ X1, const bf16* __restrict__ g1,
    const bf16* __restrict__ b1, bf16* __restrict__ Y1)
{
    int wv = threadIdx.x >> 6;
    int sel = blockIdx.x >> 11;
    size_t p = (size_t)(blockIdx.x & 2047) * 4 + wv;
    if (sel == 0) ln_row(X0, g0, b0, Y0, p);
    else          ln_row(X1, g1, b1, Y1, p);
}

// ---------------------------------------------------------------------------
__global__ __launch_bounds__(256) void dwgelu_nhwc(
    const bf16* __restrict__ H, const bf16* __restrict__ Wr,
    bf16* __restrict__ Y)
{
    int idx = blockIdx.x * 256 + threadIdx.x;
    int p = idx >> 7, c8 = (idx & 127) * 8;
    int hw = p & 1023, hh = hw >> 5, ww = hw & 31;
    size_t ib = ((size_t)(p >> 10)) << 10;
    float acc[8] = {};
#pragma unroll
    for (int kh = 0; kh < 3; ++kh)
#pragma unroll
        for (int kw = 0; kw < 3; ++kw) {
            int hi = hh + kh - 1, wi = ww + kw - 1;
            if ((unsigned)hi < 32u && (unsigned)wi < 32u) {
                v8s hv = *(const v8s*)((const short*)H + (ib + (hi << 5) + wi) * 1024 + c8);
                v8s wvv = *(const v8s*)((const short*)Wr + (kh * 3 + kw) * 1024 + c8);
#pragma unroll
                for (int j = 0; j < 8; ++j)
                    acc[j] = fmaf(us2f((unsigned short)wvv[j]),
                                  us2f((unsigned short)hv[j]), acc[j]);
            }
        }
    short ov[8];
#pragma unroll
    for (int j = 0; j < 8; ++j) {
        float x = acc[j];
        ov[j] = (short)f2us(0.5f * x * (1.0f + erff(x * 0.70710678118654752f)));
    }
    v8s o = {ov[0], ov[1], ov[2], ov[3], ov[4], ov[5], ov[6], ov[7]};
    *(v8s*)((short*)Y + (size_t)p * 1024 + c8) = o;
}

// ---------------------------------------------------------------------------
extern "C" void kernel_launch(void* const* d_in, const int* in_sizes, int n_in,
                              void* d_out, int out_size, void* d_ws, size_t ws_size,
                              hipStream_t stream)
{
    static const int  lidx[20] = {4,5,6,7,8,9,10,11,12,13,14,15,16,17,18,19,20,21,22,24};
    static const unsigned lsz[20] = {256,256,256,256,256,256,256,256,256,256,
                                     196608,65536,196608,65536,
                                     65536,65536,65536,65536,262144,262144};
    CvtArgs args;
    unsigned pre[21]; pre[0] = 0;
    for (int i = 0; i < 20; ++i) {
        args.src[i] = d_in[lidx[i]];
        pre[i + 1] = pre[i] + lsz[i];
    }
    for (int i = 0; i < 21; ++i) args.off[i] = pre[i];
    const unsigned ltot = pre[20];

    int*  flag  = (int*)d_ws;
    bf16* canon = (bf16*)d_ws + 128;
    bf16* cn[25];
    for (int i = 0; i < 20; ++i) cn[lidx[i]] = canon + pre[i];

    bf16* Wr3  = canon + ltot;
    bf16* Wr5  = Wr3 + 589824;
    bf16* Wdwr = Wr5 + 1638400;
    const size_t SZ = 2097152;
    bf16* slab = Wdwr + 9216;
    bf16* qb   = slab + 0 * SZ;                    // q_branch -> x (NHWC)
    bf16* kvb  = slab + 1 * SZ;
    bf16* t0   = slab + 2 * SZ;                    // branch-0 scratch
    bf16* q    = slab + 3 * SZ;
    bf16* kv   = slab + 4 * SZ;
    bf16* QKb  = slab + 5 * SZ;                    // 2 slots: [8192][512]
    bf16* Vb   = slab + 7 * SZ;                    // 1 slot: CHW
    bf16* t1   = slab + 8 * SZ;                    // branch-1 scratch
    bf16* QK2  = slab + 9 * SZ;                    // 2 slots (branch 1)
    bf16* V2   = slab + 11 * SZ;                   // 1 slot (branch 1)
    bf16* aopT = slab + 9 * SZ;                    // pre-SA reuse of QK2
    bf16* dopT = slab + 10 * SZ;
    bf16* hb   = slab + 3 * SZ;                    // LeFF: slots 3-6 (q..QKb dead)
    bf16* h2   = slab + 7 * SZ;                    // LeFF: slots 7-10 (Vb..QK2 dead)
    float* out = (float*)d_out;

    dim3 blk(256);
    auto S = [](const bf16* p) { return (const short*)p; };

    detect_kernel<<<1, 64, 0, stream>>>((const unsigned short*)d_in[4], flag);
    cvt_lin<<<ltot / 256, blk, 0, stream>>>(args, flag, canon);
    tcvt2<<<dim3(16, 4, 16), blk, 0, stream>>>(d_in[0], d_in[1], flag, aopT, dopT);
    repack_all<<<8740, blk, 0, stream>>>(d_in[2], d_in[3], d_in[23], flag, Wr3, Wr5, Wdwr);

    // both branch convs in one launch (z=0: 3x3->qb, z=1: 5x5->kvb)
    mconv2<<<dim3(128, 4, 2), blk, 0, stream>>>(S(aopT), (const short*)Wr3, qb,
                                                S(dopT), (const short*)Wr5, kvb);

    // merged self-attention pipelines (q branch = set0, kv branch = set1)
    ln_nhwc2<<<4096, blk, 0, stream>>>(qb, cn[4], cn[5], t0,
                                       kvb, cn[6], cn[7], t1);
    GA3 P;
    P.g[0] = GA{S(cn[14]), S(t0), QKb, nullptr, Vb, nullptr, 256, 3, 0};
    P.g[1] = GA{S(cn[16]), S(t1), QK2, nullptr, V2, nullptr, 256, 3, 0};
    P.g[2] = P.g[1];
    mgemm_z<<<dim3(12, 128, 2), blk, 0, stream>>>(P);

    attn_swz<64><<<1024, blk, 0, stream>>>(QKb, Vb, t0, QK2, V2, t1);

    P.g[0] = GA{S(t0), S(cn[15]), qb, nullptr, nullptr, qb, 256, 0, 256};
    P.g[1] = GA{S(t1), S(cn[17]), kvb, nullptr, nullptr, kvb, 256, 0, 256};
    P.g[2] = P.g[1];
    mgemm_z<<<dim3(128, 4, 2), blk, 0, stream>>>(P);

    ln_nhwc2<<<4096, blk, 0, stream>>>(qb, cn[8], cn[9], q,
                                       kvb, cn[10], cn[11], kv);

    // cross attention: 3 projection GEMMs in one launch
    P.g[0] = GA{S(cn[18]), S(q),  QKb, nullptr, nullptr, nullptr, 256, 4, 0};
    P.g[1] = GA{S(cn[19]), S(kv), QKb, nullptr, nullptr, nullptr, 256, 4, 256};
    P.g[2] = GA{S(cn[20]), S(kv), Vb,  nullptr, nullptr, nullptr, 256, 1, 256};
    mgemm_z<<<dim3(4, 128, 3), blk, 0, stream>>>(P);

    attn_swz<32><<<512, blk, 0, stream>>>(QKb, Vb, t0, QKb, Vb, t0);
    mgemm<<<dim3(128, 4), blk, 0, stream>>>(S(t0), S(cn[21]), qb, nullptr, nullptr, qb, 256, 0, 256);

    // LeFF
    ln_nhwc<<<2048, blk, 0, stream>>>(qb, cn[12], cn[13], t0);
    mgemm<<<dim3(128, 16), blk, 0, stream>>>(S(t0), S(cn[22]), hb, nullptr, nullptr, nullptr, 256, 0, 1024);
    dwgelu_nhwc<<<4096, blk, 0, stream>>>(hb, Wdwr, h2);
    mgemm<<<dim3(4, 128), blk, 0, stream>>>(S(cn[24]), S(h2), nullptr, out, nullptr, qb, 1024, 2, 256);
}

// Round 6
// 428.100 us; speedup vs baseline: 1.3541x; 1.0235x over previous
//
#include <hip/hip_runtime.h>
#include <hip/hip_bf16.h>

// DCSA block, round 16: conv LDS-traffic + balance attack.
// r15 post-mortem: attention LDS staging worked (525->438). mconv2 now top
// real dispatch (92us, MfmaUtil 16%, occ 28%). Theory: (a) fragment-read LDS
// traffic dominates the K-loop (10 b128/wave/K-step; B fragments duplicated
// across all 4 waves), (b) z-major grid leaves CUs running the 5x5 tail at
// half occupancy after the 3x3 blocks retire at step 36/100.
// Fix: 128mx64n conv tile (acc[2][4] per wave -> 1.67x less LDS read per
// output, half B-staging VMEM per output) + flat interleaved grid (each CU
// gets one 3x3 + one 5x5). Attention/GEMM/LN unchanged from r15.

using bf16 = __hip_bfloat16;
typedef short v8s __attribute__((ext_vector_type(8)));
typedef float v4f  __attribute__((ext_vector_type(4)));

static __device__ __forceinline__ float bf2f(bf16 x) { return __bfloat162float(x); }
static __device__ __forceinline__ float us2f(unsigned short u)
{ union { unsigned int i; float f; } x; x.i = ((unsigned)u) << 16; return x.f; }
static __device__ __forceinline__ unsigned short f2us(float f)
{ bf16 h = __float2bfloat16(f); return *(unsigned short*)&h; }
static __device__ __forceinline__ float ldi(const void* p, size_t i, int isbf)
{ return isbf ? bf2f(((const bf16*)p)[i]) : ((const float*)p)[i]; }

// ---------------------------------------------------------------------------
__global__ void detect_kernel(const unsigned short* p, int* flag)
{
    if (threadIdx.x == 0 && blockIdx.x == 0)
        *flag = (p[0] == 0x3F80) ? 1 : 0;
}

// ---------------------------------------------------------------------------
struct CvtArgs { const void* src[20]; unsigned off[21]; };

__global__ __launch_bounds__(256) void cvt_lin(CvtArgs a, const int* __restrict__ flag,
                                               bf16* __restrict__ dst)
{
    unsigned e = blockIdx.x * 256u + threadIdx.x;
    int isbf = *flag;
    int s = 0;
    while (e >= a.off[s + 1]) ++s;
    dst[e] = __float2bfloat16(ldi(a.src[s], e - a.off[s], isbf));
}

// ---------------------------------------------------------------------------
// merged NCHW->NHWC transpose for both feature maps (z<8: aop, z>=8: dop)
__global__ __launch_bounds__(256) void tcvt2(const void* __restrict__ s0,
                                             const void* __restrict__ s1,
                                             const int* __restrict__ flag,
                                             bf16* __restrict__ d0,
                                             bf16* __restrict__ d1)
{
    __shared__ float T[64][65];
    const void* src = (blockIdx.z < 8) ? s0 : s1;
    bf16* dst       = (blockIdx.z < 8) ? d0 : d1;
    int hw0 = blockIdx.x * 64, c0 = blockIdx.y * 64, b = blockIdx.z & 7;
    int t = threadIdx.x, isbf = *flag;
    int c = t >> 2, x16 = (t & 3) * 16;
    size_t sbase = ((size_t)b * 256 + c0 + c) * 1024 + hw0 + x16;
#pragma unroll
    for (int j = 0; j < 16; ++j) T[c][x16 + j] = ldi(src, sbase + j, isbf);
    __syncthreads();
    int hw = t >> 2, c16 = (t & 3) * 16;
    bf16* dp = dst + ((size_t)(b << 10) + hw0 + hw) * 256 + c0 + c16;
#pragma unroll
    for (int j = 0; j < 16; ++j) dp[j] = __float2bfloat16(T[c16 + j][hw]);
}

// ---------------------------------------------------------------------------
// merged weight repack: conv3 (589824) + conv5 (1638400) + dw (9216)
__global__ __launch_bounds__(256) void repack_all(
    const void* __restrict__ W3, const void* __restrict__ W5,
    const void* __restrict__ Wdw, const int* __restrict__ flag,
    bf16* __restrict__ R3, bf16* __restrict__ R5, bf16* __restrict__ Rdw)
{
    int idx = blockIdx.x * 256 + threadIdx.x;
    int isbf = *flag;
    if (idx < 589824) {
        int ci = idx & 255, o = (idx >> 8) & 255, khkw = idx >> 16;
        int kh = khkw / 3, kw = khkw % 3;
        R3[idx] = __float2bfloat16(
            ldi(W3, (((size_t)o * 256 + ci) * 3 + kh) * 3 + kw, isbf));
    } else if (idx < 2228224) {
        int j = idx - 589824;
        int ci = j & 255, o = (j >> 8) & 255, khkw = j >> 16;
        int kh = khkw / 5, kw = khkw % 5;
        R5[j] = __float2bfloat16(
            ldi(W5, (((size_t)o * 256 + ci) * 5 + kh) * 5 + kw, isbf));
    } else {
        int j = idx - 2228224;
        int c = j & 1023, tap = j >> 10;
        Rdw[j] = __float2bfloat16(ldi(Wdw, (size_t)c * 9 + tap, isbf));
    }
}

// ---------------------------------------------------------------------------
// MFMA GEMM core, 64x64 tile, BK=64, 4 waves, register-prefetch pipeline.
// MA:[M][K], MB:[N][K] k-contig.
// modes: 0 NHWC(+R) / 1 CHW / 2 CHW-fp32+R / 3 qkv-split / 4 QK col-offset
// ---------------------------------------------------------------------------
static __device__ __forceinline__ void mgemm_core(
    const short* __restrict__ MA, const short* __restrict__ MB,
    bf16* __restrict__ Yb, float* __restrict__ Yf, bf16* __restrict__ Y2,
    const bf16* __restrict__ R, int K, int mode, int Ochan,
    short As[64][72], short Bs[64][72])
{
    int m0 = blockIdx.x * 64, n0 = blockIdx.y * 64;
    int t = threadIdx.x, lane = t & 63, wv = t >> 6;
    int l15 = lane & 15, quad = lane >> 4;
    int srow = t >> 2, scol = (t & 3) * 16;

    const short* pa = &MA[(size_t)(m0 + srow) * K + scol];
    const short* pb = &MB[(size_t)(n0 + srow) * K + scol];

    v4f acc[4] = {};
    v8s ra0 = *(const v8s*)&pa[0], ra1 = *(const v8s*)&pa[8];
    v8s rb0 = *(const v8s*)&pb[0], rb1 = *(const v8s*)&pb[8];

    for (int k0 = 0; k0 < K; k0 += 64) {
        if (k0) __syncthreads();
        *(v8s*)&As[srow][scol]     = ra0;
        *(v8s*)&As[srow][scol + 8] = ra1;
        *(v8s*)&Bs[srow][scol]     = rb0;
        *(v8s*)&Bs[srow][scol + 8] = rb1;
        __syncthreads();
        if (k0 + 64 < K) {
            ra0 = *(const v8s*)&pa[k0 + 64];
            ra1 = *(const v8s*)&pa[k0 + 72];
            rb0 = *(const v8s*)&pb[k0 + 64];
            rb1 = *(const v8s*)&pb[k0 + 72];
        }
#pragma unroll
        for (int kk = 0; kk < 2; ++kk) {
            v8s a = *(const v8s*)&As[wv * 16 + l15][kk * 32 + quad * 8];
#pragma unroll
            for (int nt = 0; nt < 4; ++nt) {
                v8s b = *(const v8s*)&Bs[nt * 16 + l15][kk * 32 + quad * 8];
                acc[nt] = __builtin_amdgcn_mfma_f32_16x16x32_bf16(a, b, acc[nt], 0, 0, 0);
            }
        }
    }

#pragma unroll
    for (int nt = 0; nt < 4; ++nt)
#pragma unroll
        for (int r = 0; r < 4; ++r) {
            int mm = m0 + wv * 16 + quad * 4 + r;
            int nn = n0 + nt * 16 + l15;
            float v = acc[nt][r];
            if (mode == 0) {
                size_t off = (size_t)mm * Ochan + nn;
                if (R) v += bf2f(R[off]);
                Yb[off] = __float2bfloat16(v);
            } else if (mode == 1) {
                Yb[((size_t)(nn >> 10) * Ochan + mm) * 1024 + (nn & 1023)] =
                    __float2bfloat16(v);
            } else if (mode == 2) {
                Yf[((size_t)(nn >> 10) * Ochan + mm) * 1024 + (nn & 1023)] =
                    v + bf2f(R[(size_t)nn * 256 + mm]);
            } else if (mode == 3) {
                if (mm < 512) Yb[(size_t)nn * 512 + mm] = __float2bfloat16(v);
                else Y2[((size_t)(nn >> 10) * 256 + (mm - 512)) * 1024 + (nn & 1023)] =
                         __float2bfloat16(v);
            } else {
                Yb[(size_t)nn * 512 + Ochan + mm] = __float2bfloat16(v);
            }
        }
}

__global__ __launch_bounds__(256) void mgemm(
    const short* __restrict__ MA, const short* __restrict__ MB,
    bf16* __restrict__ Yb, float* __restrict__ Yf, bf16* __restrict__ Y2,
    const bf16* __restrict__ R, int K, int mode, int Ochan)
{
    __shared__ short As[64][72], Bs[64][72];
    mgemm_core(MA, MB, Yb, Yf, Y2, R, K, mode, Ochan, As, Bs);
}

// z-dispatched merged GEMM (up to 3 independent problems, same x/y grid)
struct GA { const short* A; const short* B; bf16* Yb; float* Yf; bf16* Y2;
            const bf16* R; int K; int mode; int Oc; };
struct GA3 { GA g[3]; };

__global__ __launch_bounds__(256) void mgemm_z(GA3 P)
{
    __shared__ short As[64][72], Bs[64][72];
    const GA& a = P.g[blockIdx.z];
    mgemm_core(a.A, a.B, a.Yb, a.Yf, a.Y2, a.R, a.K, a.mode, a.Oc, As, Bs);
}

// ---------------------------------------------------------------------------
// MFMA conv core, 128m x 64n tile, BK=64, 4 waves (each 32m x 64n, acc[2][4]),
// im2col A staging, register prefetch. 1.67x less LDS fragment traffic per
// output than the 64x64 tile.
// ---------------------------------------------------------------------------
template <int KS, int PAD>
static __device__ __forceinline__ void mconv128_core(
    const short* __restrict__ Xn, const short* __restrict__ Wr,
    bf16* __restrict__ Y, short As[128][72], short Bs[64][72],
    int p0, int o0)
{
    const int K = 256 * KS * KS;
    int t = threadIdx.x, lane = t & 63, wv = t >> 6;
    int l15 = lane & 15, quad = lane >> 4;
    int arow = t >> 1, acol = (t & 1) * 32;   // A: 128 rows x 64 cols, 32 sh/thread
    int brow = t >> 2, bcol = (t & 3) * 16;   // B: 64 rows x 64 cols, 16 sh/thread

    int p  = p0 + arow;
    int hw = p & 1023, hh = hw >> 5, ww = hw & 31;
    size_t ib = ((size_t)(p >> 10)) << 10;

    v4f acc[2][4] = {};
    v8s ra0, ra1, ra2, ra3, rb0, rb1;

    {
        int hi = hh - PAD, wi = ww - PAD;
        v8s z = {0, 0, 0, 0, 0, 0, 0, 0};
        ra0 = z; ra1 = z; ra2 = z; ra3 = z;
        if ((unsigned)hi < 32u && (unsigned)wi < 32u) {
            const short* sa = &Xn[(ib + (hi << 5) + wi) * 256 + acol];
            ra0 = *(const v8s*)&sa[0];  ra1 = *(const v8s*)&sa[8];
            ra2 = *(const v8s*)&sa[16]; ra3 = *(const v8s*)&sa[24];
        }
        const short* sb = &Wr[(size_t)(o0 + brow) * 256 + bcol];
        rb0 = *(const v8s*)&sb[0];
        rb1 = *(const v8s*)&sb[8];
    }

    for (int k0 = 0; k0 < K; k0 += 64) {
        if (k0) __syncthreads();
        *(v8s*)&As[arow][acol]      = ra0;
        *(v8s*)&As[arow][acol + 8]  = ra1;
        *(v8s*)&As[arow][acol + 16] = ra2;
        *(v8s*)&As[arow][acol + 24] = ra3;
        *(v8s*)&Bs[brow][bcol]      = rb0;
        *(v8s*)&Bs[brow][bcol + 8]  = rb1;
        __syncthreads();
        int kn = k0 + 64;
        if (kn < K) {
            int khkw = kn >> 8;
            int kh = khkw / KS, kw = khkw % KS;
            int hi = hh + kh - PAD, wi = ww + kw - PAD;
            int aci = (kn & 255) + acol;
            v8s z = {0, 0, 0, 0, 0, 0, 0, 0};
            ra0 = z; ra1 = z; ra2 = z; ra3 = z;
            if ((unsigned)hi < 32u && (unsigned)wi < 32u) {
                const short* sa = &Xn[(ib + (hi << 5) + wi) * 256 + aci];
                ra0 = *(const v8s*)&sa[0];  ra1 = *(const v8s*)&sa[8];
                ra2 = *(const v8s*)&sa[16]; ra3 = *(const v8s*)&sa[24];
            }
            const short* sb = &Wr[((size_t)khkw * 256 + o0 + brow) * 256 + (kn & 255) + bcol];
            rb0 = *(const v8s*)&sb[0];
            rb1 = *(const v8s*)&sb[8];
        }
#pragma unroll
        for (int kk = 0; kk < 2; ++kk) {
            v8s a0 = *(const v8s*)&As[wv * 32 + l15][kk * 32 + quad * 8];
            v8s a1 = *(const v8s*)&As[wv * 32 + 16 + l15][kk * 32 + quad * 8];
#pragma unroll
            for (int nt = 0; nt < 4; ++nt) {
                v8s b = *(const v8s*)&Bs[nt * 16 + l15][kk * 32 + quad * 8];
                acc[0][nt] = __builtin_amdgcn_mfma_f32_16x16x32_bf16(a0, b, acc[0][nt], 0, 0, 0);
                acc[1][nt] = __builtin_amdgcn_mfma_f32_16x16x32_bf16(a1, b, acc[1][nt], 0, 0, 0);
            }
        }
    }

#pragma unroll
    for (int mt = 0; mt < 2; ++mt)
#pragma unroll
        for (int nt = 0; nt < 4; ++nt)
#pragma unroll
            for (int r = 0; r < 4; ++r) {
                int pp = p0 + wv * 32 + mt * 16 + quad * 4 + r;
                int oo = o0 + nt * 16 + l15;
                Y[(size_t)pp * 256 + oo] = __float2bfloat16(acc[mt][nt][r]);
            }
}

// merged conv, flat interleaved grid of 512 wgs:
// wg < 256 -> 3x3 (q branch), wg >= 256 -> 5x5 (kv branch); each CU gets
// one of each (dispatch round-robins wg -> CU), so the 3x3's early finish
// leaves the 5x5 with the whole CU instead of stranding half the grid.
__global__ __launch_bounds__(256) void mconv2(
    const short* __restrict__ Xa, const short* __restrict__ Wa, bf16* __restrict__ Ya,
    const short* __restrict__ Xb, const short* __restrict__ Wb, bf16* __restrict__ Yb)
{
    __shared__ short As[128][72];
    __shared__ short Bs[64][72];
    int wg = blockIdx.x;
    int type = wg >> 8, xy = wg & 255;
    int p0 = (xy & 63) * 128, o0 = (xy >> 6) * 64;
    if (type == 0) mconv128_core<3, 1>(Xa, Wa, Ya, As, Bs, p0, o0);
    else           mconv128_core<5, 2>(Xb, Wb, Yb, As, Bs, p0, o0);
}

// ---------------------------------------------------------------------------
// MFMA flash attention core, LDS-staged K/V tiles (verified r15).
// ---------------------------------------------------------------------------
static __device__ __forceinline__ void attn_core(
    const bf16* __restrict__ QK, const bf16* __restrict__ V,
    bf16* __restrict__ Out, int b, int h, int n0,
    short Ps[4][16][72], short Ks[64][72], short Vs[64][72])
{
    int t = threadIdx.x, lane = t & 63, wv = t >> 6;
    int l15 = lane & 15, quad = lane >> 4;
    int srow = t >> 2, scol = (t & 3) * 16;

    const short* qk = (const short*)QK;
    const short* vp = (const short*)V + ((size_t)b * 256 + h * 64) * 1024;

    size_t qrow = ((size_t)b * 1024 + n0 + wv * 16 + l15) * 512 + h * 64;
    v8s qf0 = *(const v8s*)&qk[qrow + quad * 8];
    v8s qf1 = *(const v8s*)&qk[qrow + 32 + quad * 8];

    v4f oacc[4] = {};
    float mi[4], li[4], nmiSC[4];
#pragma unroll
    for (int r = 0; r < 4; ++r) { mi[r] = -1e30f; li[r] = 0.f; nmiSC[r] = 0.f; }
    const float SC = 0.18033688011112042f;  // 0.125 * log2(e)

    const short* kbase = &qk[((size_t)b * 1024 + srow) * 512 + 256 + h * 64 + scol];
    const short* vbase = vp + (size_t)srow * 1024 + scol;

    v8s rk0 = *(const v8s*)&kbase[0], rk1 = *(const v8s*)&kbase[8];
    v8s rv0 = *(const v8s*)&vbase[0], rv1 = *(const v8s*)&vbase[8];

    for (int m0 = 0; m0 < 1024; m0 += 64) {
        if (m0) __syncthreads();
        *(v8s*)&Ks[srow][scol]     = rk0;
        *(v8s*)&Ks[srow][scol + 8] = rk1;
        *(v8s*)&Vs[srow][scol]     = rv0;
        *(v8s*)&Vs[srow][scol + 8] = rv1;
        __syncthreads();
        if (m0 + 64 < 1024) {
            rk0 = *(const v8s*)&kbase[(size_t)(m0 + 64) * 512];
            rk1 = *(const v8s*)&kbase[(size_t)(m0 + 64) * 512 + 8];
            rv0 = *(const v8s*)&vbase[m0 + 64];
            rv1 = *(const v8s*)&vbase[m0 + 72];
        }

        v4f sacc[4];
        __builtin_amdgcn_s_setprio(1);
#pragma unroll
        for (int ct = 0; ct < 4; ++ct) {
            v8s kf0 = *(const v8s*)&Ks[ct * 16 + l15][quad * 8];
            v8s kf1 = *(const v8s*)&Ks[ct * 16 + l15][32 + quad * 8];
            v4f z = {0.f, 0.f, 0.f, 0.f};
            z = __builtin_amdgcn_mfma_f32_16x16x32_bf16(qf0, kf0, z, 0, 0, 0);
            z = __builtin_amdgcn_mfma_f32_16x16x32_bf16(qf1, kf1, z, 0, 0, 0);
            sacc[ct] = z;
        }
        __builtin_amdgcn_s_setprio(0);

        float pr[4];
#pragma unroll
        for (int r = 0; r < 4; ++r)
            pr[r] = fmaxf(fmaxf(sacc[0][r], sacc[1][r]),
                          fmaxf(sacc[2][r], sacc[3][r]));
        bool grow = (pr[0] > mi[0]) | (pr[1] > mi[1]) |
                    (pr[2] > mi[2]) | (pr[3] > mi[3]);
        if (__any(grow)) {
#pragma unroll
            for (int mk = 1; mk <= 8; mk <<= 1)
#pragma unroll
                for (int r = 0; r < 4; ++r)
                    pr[r] = fmaxf(pr[r], __shfl_xor(pr[r], mk));
#pragma unroll
            for (int r = 0; r < 4; ++r) {
                float mn = fmaxf(mi[r], pr[r]);
                float al = exp2f((mi[r] - mn) * SC);
                mi[r] = mn;
                nmiSC[r] = -mn * SC;
                li[r] *= al;
#pragma unroll
                for (int dt = 0; dt < 4; ++dt) oacc[dt][r] *= al;
            }
        }

#pragma unroll
        for (int ct = 0; ct < 4; ++ct)
#pragma unroll
            for (int r = 0; r < 4; ++r) {
                float pvv = exp2f(fmaf(sacc[ct][r], SC, nmiSC[r]));
                li[r] += pvv;
                Ps[wv][quad * 4 + r][ct * 16 + l15] = (short)f2us(pvv);
            }

        v8s pf0 = *(const v8s*)&Ps[wv][l15][quad * 8];
        v8s pf1 = *(const v8s*)&Ps[wv][l15][32 + quad * 8];
        __builtin_amdgcn_s_setprio(1);
#pragma unroll
        for (int dt = 0; dt < 4; ++dt) {
            v8s vf0 = *(const v8s*)&Vs[dt * 16 + l15][quad * 8];
            v8s vf1 = *(const v8s*)&Vs[dt * 16 + l15][32 + quad * 8];
            oacc[dt] = __builtin_amdgcn_mfma_f32_16x16x32_bf16(pf0, vf0, oacc[dt], 0, 0, 0);
            oacc[dt] = __builtin_amdgcn_mfma_f32_16x16x32_bf16(pf1, vf1, oacc[dt], 0, 0, 0);
        }
        __builtin_amdgcn_s_setprio(0);
    }

#pragma unroll
    for (int mk = 1; mk <= 8; mk <<= 1)
#pragma unroll
        for (int r = 0; r < 4; ++r)
            li[r] += __shfl_xor(li[r], mk);

    float linv[4];
#pragma unroll
    for (int r = 0; r < 4; ++r) linv[r] = 1.0f / li[r];
    size_t pb = (size_t)b * 1024 + n0 + wv * 16;
#pragma unroll
    for (int dt = 0; dt < 4; ++dt)
#pragma unroll
        for (int r = 0; r < 4; ++r)
            Out[(pb + quad * 4 + r) * 256 + h * 64 + dt * 16 + l15] =
                __float2bfloat16(oacc[dt][r] * linv[r]);
}

// XCD-swizzled attention: flat 1D grid of NG*16 blocks; all 16 n0-tiles of
// one (b,h[,branch]) group land on one XCD so its 256KB K/V stays L2-hot.
// NG = number of (h, b[, branch]) groups (must be divisible by 8).
template <int NG>
__global__ __launch_bounds__(256) void attn_swz(
    const bf16* __restrict__ QK0, const bf16* __restrict__ V0, bf16* __restrict__ O0,
    const bf16* __restrict__ QK1, const bf16* __restrict__ V1, bf16* __restrict__ O1)
{
    __shared__ short Ps[4][16][72];
    __shared__ short Ks[64][72], Vs[64][72];
    int i = blockIdx.x;
    int xcd = i & 7, idx = i >> 3;
    int g = xcd * (NG / 8) + (idx >> 4);     // group id, bijective remap
    int n0 = (idx & 15) * 64;
    int h = g & 3, zz = g >> 2;
    int b = zz & 7;
    if (zz < 8) attn_core(QK0, V0, O0, b, h, n0, Ps, Ks, Vs);
    else        attn_core(QK1, V1, O1, b, h, n0, Ps, Ks, Vs);
}

// ---------------------------------------------------------------------------
static __device__ __forceinline__ void ln_row(
    const bf16* __restrict__ X, const bf16* __restrict__ g,
    const bf16* __restrict__ be, bf16* __restrict__ Y, size_t p)
{
    int lane = threadIdx.x & 63;
    const ushort4 u = *(const ushort4*)(X + p * 256 + lane * 4);
    float v0 = us2f(u.x), v1 = us2f(u.y), v2 = us2f(u.z), v3 = us2f(u.w);
    float s = v0 + v1 + v2 + v3;
    float ss = v0 * v0 + v1 * v1 + v2 * v2 + v3 * v3;
#pragma unroll
    for (int off = 32; off; off >>= 1) {
        s  += __shfl_xor(s, off);
        ss += __shfl_xor(ss, off);
    }
    float mu   = s * (1.0f / 256.0f);
    float var  = ss * (1.0f / 256.0f) - mu * mu;
    float rstd = rsqrtf(fmaxf(var, 0.0f) + 1e-5f);
    const ushort4 gu = *(const ushort4*)((const unsigned short*)g + lane * 4);
    const ushort4 bu = *(const ushort4*)((const unsigned short*)be + lane * 4);
    ushort4 o;
    o.x = f2us((v0 - mu) * rstd * us2f(gu.x) + us2f(bu.x));
    o.y = f2us((v1 - mu) * rstd * us2f(gu.y) + us2f(bu.y));
    o.z = f2us((v2 - mu) * rstd * us2f(gu.z) + us2f(bu.z));
    o.w = f2us((v3 - mu) * rstd * us2f(gu.w) + us2f(bu.w));
    *(ushort4*)(Y + p * 256 + lane * 4) = o;
}

__global__ __launch_bounds__(256) void ln_nhwc(
    const bf16* __restrict__ X, const bf16* __restrict__ g,
    const bf16* __restrict__ be, bf16* __restrict__ Y)
{
    int wv = threadIdx.x >> 6;
    ln_row(X, g, be, Y, (size_t)blockIdx.x * 4 + wv);
}

// merged LN for both branches: blocks [0,2048) -> set0, [2048,4096) -> set1
__global__ __launch_bounds__(256) void ln_nhwc2(
    const bf16* __restrict__ X0, const bf16* __restrict__ g0,
    const bf16* __restrict__ b0, bf16* __restrict__ Y0,
    const bf16* __restrict__ X1, const bf16* __restrict__ g1,
    const bf16* __restrict__ b1, bf16* __restrict__ Y1)
{
    int wv = threadIdx.x >> 6;
    int sel = blockIdx.x >> 11;
    size_t p = (size_t)(blockIdx.x & 2047) * 4 + wv;
    if (sel == 0) ln_row(X0, g0, b0, Y0, p);
    else          ln_row(X1, g1, b1, Y1, p);
}

// ---------------------------------------------------------------------------
__global__ __launch_bounds__(256) void dwgelu_nhwc(
    const bf16* __restrict__ H, const bf16* __restrict__ Wr,
    bf16* __restrict__ Y)
{
    int idx = blockIdx.x * 256 + threadIdx.x;
    int p = idx >> 7, c8 = (idx & 127) * 8;
    int hw = p & 1023, hh = hw >> 5, ww = hw & 31;
    size_t ib = ((size_t)(p >> 10)) << 10;
    float acc[8] = {};
#pragma unroll
    for (int kh = 0; kh < 3; ++kh)
#pragma unroll
        for (int kw = 0; kw < 3; ++kw) {
            int hi = hh + kh - 1, wi = ww + kw - 1;
            if ((unsigned)hi < 32u && (unsigned)wi < 32u) {
                v8s hv = *(const v8s*)((const short*)H + (ib + (hi << 5) + wi) * 1024 + c8);
                v8s wvv = *(const v8s*)((const short*)Wr + (kh * 3 + kw) * 1024 + c8);
#pragma unroll
                for (int j = 0; j < 8; ++j)
                    acc[j] = fmaf(us2f((unsigned short)wvv[j]),
                                  us2f((unsigned short)hv[j]), acc[j]);
            }
        }
    short ov[8];
#pragma unroll
    for (int j = 0; j < 8; ++j) {
        float x = acc[j];
        ov[j] = (short)f2us(0.5f * x * (1.0f + erff(x * 0.70710678118654752f)));
    }
    v8s o = {ov[0], ov[1], ov[2], ov[3], ov[4], ov[5], ov[6], ov[7]};
    *(v8s*)((short*)Y + (size_t)p * 1024 + c8) = o;
}

// ---------------------------------------------------------------------------
extern "C" void kernel_launch(void* const* d_in, const int* in_sizes, int n_in,
                              void* d_out, int out_size, void* d_ws, size_t ws_size,
                              hipStream_t stream)
{
    static const int  lidx[20] = {4,5,6,7,8,9,10,11,12,13,14,15,16,17,18,19,20,21,22,24};
    static const unsigned lsz[20] = {256,256,256,256,256,256,256,256,256,256,
                                     196608,65536,196608,65536,
                                     65536,65536,65536,65536,262144,262144};
    CvtArgs args;
    unsigned pre[21]; pre[0] = 0;
    for (int i = 0; i < 20; ++i) {
        args.src[i] = d_in[lidx[i]];
        pre[i + 1] = pre[i] + lsz[i];
    }
    for (int i = 0; i < 21; ++i) args.off[i] = pre[i];
    const unsigned ltot = pre[20];

    int*  flag  = (int*)d_ws;
    bf16* canon = (bf16*)d_ws + 128;
    bf16* cn[25];
    for (int i = 0; i < 20; ++i) cn[lidx[i]] = canon + pre[i];

    bf16* Wr3  = canon + ltot;
    bf16* Wr5  = Wr3 + 589824;
    bf16* Wdwr = Wr5 + 1638400;
    const size_t SZ = 2097152;
    bf16* slab = Wdwr + 9216;
    bf16* qb   = slab + 0 * SZ;                    // q_branch -> x (NHWC)
    bf16* kvb  = slab + 1 * SZ;
    bf16* t0   = slab + 2 * SZ;                    // branch-0 scratch
    bf16* q    = slab + 3 * SZ;
    bf16* kv   = slab + 4 * SZ;
    bf16* QKb  = slab + 5 * SZ;                    // 2 slots: [8192][512]
    bf16* Vb   = slab + 7 * SZ;                    // 1 slot: CHW
    bf16* t1   = slab + 8 * SZ;                    // branch-1 scratch
    bf16* QK2  = slab + 9 * SZ;                    // 2 slots (branch 1)
    bf16* V2   = slab + 11 * SZ;                   // 1 slot (branch 1)
    bf16* aopT = slab + 9 * SZ;                    // pre-SA reuse of QK2
    bf16* dopT = slab + 10 * SZ;
    bf16* hb   = slab + 3 * SZ;                    // LeFF: slots 3-6 (q..QKb dead)
    bf16* h2   = slab + 7 * SZ;                    // LeFF: slots 7-10 (Vb..QK2 dead)
    float* out = (float*)d_out;

    dim3 blk(256);
    auto S = [](const bf16* p) { return (const short*)p; };

    detect_kernel<<<1, 64, 0, stream>>>((const unsigned short*)d_in[4], flag);
    cvt_lin<<<ltot / 256, blk, 0, stream>>>(args, flag, canon);
    tcvt2<<<dim3(16, 4, 16), blk, 0, stream>>>(d_in[0], d_in[1], flag, aopT, dopT);
    repack_all<<<8740, blk, 0, stream>>>(d_in[2], d_in[3], d_in[23], flag, Wr3, Wr5, Wdwr);

    // both branch convs, flat interleaved grid (wg<256: 3x3->qb, else 5x5->kvb)
    mconv2<<<512, blk, 0, stream>>>(S(aopT), (const short*)Wr3, qb,
                                    S(dopT), (const short*)Wr5, kvb);

    // merged self-attention pipelines (q branch = set0, kv branch = set1)
    ln_nhwc2<<<4096, blk, 0, stream>>>(qb, cn[4], cn[5], t0,
                                       kvb, cn[6], cn[7], t1);
    GA3 P;
    P.g[0] = GA{S(cn[14]), S(t0), QKb, nullptr, Vb, nullptr, 256, 3, 0};
    P.g[1] = GA{S(cn[16]), S(t1), QK2, nullptr, V2, nullptr, 256, 3, 0};
    P.g[2] = P.g[1];
    mgemm_z<<<dim3(12, 128, 2), blk, 0, stream>>>(P);

    attn_swz<64><<<1024, blk, 0, stream>>>(QKb, Vb, t0, QK2, V2, t1);

    P.g[0] = GA{S(t0), S(cn[15]), qb, nullptr, nullptr, qb, 256, 0, 256};
    P.g[1] = GA{S(t1), S(cn[17]), kvb, nullptr, nullptr, kvb, 256, 0, 256};
    P.g[2] = P.g[1];
    mgemm_z<<<dim3(128, 4, 2), blk, 0, stream>>>(P);

    ln_nhwc2<<<4096, blk, 0, stream>>>(qb, cn[8], cn[9], q,
                                       kvb, cn[10], cn[11], kv);

    // cross attention: 3 projection GEMMs in one launch
    P.g[0] = GA{S(cn[18]), S(q),  QKb, nullptr, nullptr, nullptr, 256, 4, 0};
    P.g[1] = GA{S(cn[19]), S(kv), QKb, nullptr, nullptr, nullptr, 256, 4, 256};
    P.g[2] = GA{S(cn[20]), S(kv), Vb,  nullptr, nullptr, nullptr, 256, 1, 256};
    mgemm_z<<<dim3(4, 128, 3), blk, 0, stream>>>(P);

    attn_swz<32><<<512, blk, 0, stream>>>(QKb, Vb, t0, QKb, Vb, t0);
    mgemm<<<dim3(128, 4), blk, 0, stream>>>(S(t0), S(cn[21]), qb, nullptr, nullptr, qb, 256, 0, 256);

    // LeFF
    ln_nhwc<<<2048, blk, 0, stream>>>(qb, cn[12], cn[13], t0);
    mgemm<<<dim3(128, 16), blk, 0, stream>>>(S(t0), S(cn[22]), hb, nullptr, nullptr, nullptr, 256, 0, 1024);
    dwgelu_nhwc<<<4096, blk, 0, stream>>>(hb, Wdwr, h2);
    mgemm<<<dim3(4, 128), blk, 0, stream>>>(S(cn[24]), S(h2), nullptr, out, nullptr, qb, 1024, 2, 256);
}

// Round 7
// 416.612 us; speedup vs baseline: 1.3914x; 1.0276x over previous
//
#include <hip/hip_runtime.h>
#include <hip/hip_bf16.h>

// DCSA block, round 17: conv split-K for occupancy + tail balance.
// r16 post-mortem: 128x64 tile improved per-wave efficiency but halved the
// grid to 512 wgs = 2 blocks/CU (occ 28->14%), and the 3x3 (36 K-steps)
// retires early leaving its CU running the 5x5 (100 K-steps) alone.
// Fix: split the 5x5 into two K-halves (50 steps each) writing fp32 partials;
// small add+cvt kernel merges them into kvb. Grid 768 = 3 blocks/CU with
// per-CU schedule {36,50,50}. Everything else unchanged from r16.

using bf16 = __hip_bfloat16;
typedef short v8s __attribute__((ext_vector_type(8)));
typedef float v4f  __attribute__((ext_vector_type(4)));

static __device__ __forceinline__ float bf2f(bf16 x) { return __bfloat162float(x); }
static __device__ __forceinline__ float us2f(unsigned short u)
{ union { unsigned int i; float f; } x; x.i = ((unsigned)u) << 16; return x.f; }
static __device__ __forceinline__ unsigned short f2us(float f)
{ bf16 h = __float2bfloat16(f); return *(unsigned short*)&h; }
static __device__ __forceinline__ float ldi(const void* p, size_t i, int isbf)
{ return isbf ? bf2f(((const bf16*)p)[i]) : ((const float*)p)[i]; }

// ---------------------------------------------------------------------------
__global__ void detect_kernel(const unsigned short* p, int* flag)
{
    if (threadIdx.x == 0 && blockIdx.x == 0)
        *flag = (p[0] == 0x3F80) ? 1 : 0;
}

// ---------------------------------------------------------------------------
struct CvtArgs { const void* src[20]; unsigned off[21]; };

__global__ __launch_bounds__(256) void cvt_lin(CvtArgs a, const int* __restrict__ flag,
                                               bf16* __restrict__ dst)
{
    unsigned e = blockIdx.x * 256u + threadIdx.x;
    int isbf = *flag;
    int s = 0;
    while (e >= a.off[s + 1]) ++s;
    dst[e] = __float2bfloat16(ldi(a.src[s], e - a.off[s], isbf));
}

// ---------------------------------------------------------------------------
// merged NCHW->NHWC transpose for both feature maps (z<8: aop, z>=8: dop)
__global__ __launch_bounds__(256) void tcvt2(const void* __restrict__ s0,
                                             const void* __restrict__ s1,
                                             const int* __restrict__ flag,
                                             bf16* __restrict__ d0,
                                             bf16* __restrict__ d1)
{
    __shared__ float T[64][65];
    const void* src = (blockIdx.z < 8) ? s0 : s1;
    bf16* dst       = (blockIdx.z < 8) ? d0 : d1;
    int hw0 = blockIdx.x * 64, c0 = blockIdx.y * 64, b = blockIdx.z & 7;
    int t = threadIdx.x, isbf = *flag;
    int c = t >> 2, x16 = (t & 3) * 16;
    size_t sbase = ((size_t)b * 256 + c0 + c) * 1024 + hw0 + x16;
#pragma unroll
    for (int j = 0; j < 16; ++j) T[c][x16 + j] = ldi(src, sbase + j, isbf);
    __syncthreads();
    int hw = t >> 2, c16 = (t & 3) * 16;
    bf16* dp = dst + ((size_t)(b << 10) + hw0 + hw) * 256 + c0 + c16;
#pragma unroll
    for (int j = 0; j < 16; ++j) dp[j] = __float2bfloat16(T[c16 + j][hw]);
}

// ---------------------------------------------------------------------------
// merged weight repack: conv3 (589824) + conv5 (1638400) + dw (9216)
__global__ __launch_bounds__(256) void repack_all(
    const void* __restrict__ W3, const void* __restrict__ W5,
    const void* __restrict__ Wdw, const int* __restrict__ flag,
    bf16* __restrict__ R3, bf16* __restrict__ R5, bf16* __restrict__ Rdw)
{
    int idx = blockIdx.x * 256 + threadIdx.x;
    int isbf = *flag;
    if (idx < 589824) {
        int ci = idx & 255, o = (idx >> 8) & 255, khkw = idx >> 16;
        int kh = khkw / 3, kw = khkw % 3;
        R3[idx] = __float2bfloat16(
            ldi(W3, (((size_t)o * 256 + ci) * 3 + kh) * 3 + kw, isbf));
    } else if (idx < 2228224) {
        int j = idx - 589824;
        int ci = j & 255, o = (j >> 8) & 255, khkw = j >> 16;
        int kh = khkw / 5, kw = khkw % 5;
        R5[j] = __float2bfloat16(
            ldi(W5, (((size_t)o * 256 + ci) * 5 + kh) * 5 + kw, isbf));
    } else {
        int j = idx - 2228224;
        int c = j & 1023, tap = j >> 10;
        Rdw[j] = __float2bfloat16(ldi(Wdw, (size_t)c * 9 + tap, isbf));
    }
}

// ---------------------------------------------------------------------------
// MFMA GEMM core, 64x64 tile, BK=64, 4 waves, register-prefetch pipeline.
// MA:[M][K], MB:[N][K] k-contig.
// modes: 0 NHWC(+R) / 1 CHW / 2 CHW-fp32+R / 3 qkv-split / 4 QK col-offset
// ---------------------------------------------------------------------------
static __device__ __forceinline__ void mgemm_core(
    const short* __restrict__ MA, const short* __restrict__ MB,
    bf16* __restrict__ Yb, float* __restrict__ Yf, bf16* __restrict__ Y2,
    const bf16* __restrict__ R, int K, int mode, int Ochan,
    short As[64][72], short Bs[64][72])
{
    int m0 = blockIdx.x * 64, n0 = blockIdx.y * 64;
    int t = threadIdx.x, lane = t & 63, wv = t >> 6;
    int l15 = lane & 15, quad = lane >> 4;
    int srow = t >> 2, scol = (t & 3) * 16;

    const short* pa = &MA[(size_t)(m0 + srow) * K + scol];
    const short* pb = &MB[(size_t)(n0 + srow) * K + scol];

    v4f acc[4] = {};
    v8s ra0 = *(const v8s*)&pa[0], ra1 = *(const v8s*)&pa[8];
    v8s rb0 = *(const v8s*)&pb[0], rb1 = *(const v8s*)&pb[8];

    for (int k0 = 0; k0 < K; k0 += 64) {
        if (k0) __syncthreads();
        *(v8s*)&As[srow][scol]     = ra0;
        *(v8s*)&As[srow][scol + 8] = ra1;
        *(v8s*)&Bs[srow][scol]     = rb0;
        *(v8s*)&Bs[srow][scol + 8] = rb1;
        __syncthreads();
        if (k0 + 64 < K) {
            ra0 = *(const v8s*)&pa[k0 + 64];
            ra1 = *(const v8s*)&pa[k0 + 72];
            rb0 = *(const v8s*)&pb[k0 + 64];
            rb1 = *(const v8s*)&pb[k0 + 72];
        }
#pragma unroll
        for (int kk = 0; kk < 2; ++kk) {
            v8s a = *(const v8s*)&As[wv * 16 + l15][kk * 32 + quad * 8];
#pragma unroll
            for (int nt = 0; nt < 4; ++nt) {
                v8s b = *(const v8s*)&Bs[nt * 16 + l15][kk * 32 + quad * 8];
                acc[nt] = __builtin_amdgcn_mfma_f32_16x16x32_bf16(a, b, acc[nt], 0, 0, 0);
            }
        }
    }

#pragma unroll
    for (int nt = 0; nt < 4; ++nt)
#pragma unroll
        for (int r = 0; r < 4; ++r) {
            int mm = m0 + wv * 16 + quad * 4 + r;
            int nn = n0 + nt * 16 + l15;
            float v = acc[nt][r];
            if (mode == 0) {
                size_t off = (size_t)mm * Ochan + nn;
                if (R) v += bf2f(R[off]);
                Yb[off] = __float2bfloat16(v);
            } else if (mode == 1) {
                Yb[((size_t)(nn >> 10) * Ochan + mm) * 1024 + (nn & 1023)] =
                    __float2bfloat16(v);
            } else if (mode == 2) {
                Yf[((size_t)(nn >> 10) * Ochan + mm) * 1024 + (nn & 1023)] =
                    v + bf2f(R[(size_t)nn * 256 + mm]);
            } else if (mode == 3) {
                if (mm < 512) Yb[(size_t)nn * 512 + mm] = __float2bfloat16(v);
                else Y2[((size_t)(nn >> 10) * 256 + (mm - 512)) * 1024 + (nn & 1023)] =
                         __float2bfloat16(v);
            } else {
                Yb[(size_t)nn * 512 + Ochan + mm] = __float2bfloat16(v);
            }
        }
}

__global__ __launch_bounds__(256) void mgemm(
    const short* __restrict__ MA, const short* __restrict__ MB,
    bf16* __restrict__ Yb, float* __restrict__ Yf, bf16* __restrict__ Y2,
    const bf16* __restrict__ R, int K, int mode, int Ochan)
{
    __shared__ short As[64][72], Bs[64][72];
    mgemm_core(MA, MB, Yb, Yf, Y2, R, K, mode, Ochan, As, Bs);
}

// z-dispatched merged GEMM (up to 3 independent problems, same x/y grid)
struct GA { const short* A; const short* B; bf16* Yb; float* Yf; bf16* Y2;
            const bf16* R; int K; int mode; int Oc; };
struct GA3 { GA g[3]; };

__global__ __launch_bounds__(256) void mgemm_z(GA3 P)
{
    __shared__ short As[64][72], Bs[64][72];
    const GA& a = P.g[blockIdx.z];
    mgemm_core(a.A, a.B, a.Yb, a.Yf, a.Y2, a.R, a.K, a.mode, a.Oc, As, Bs);
}

// ---------------------------------------------------------------------------
// MFMA conv core, 128m x 64n tile, BK=64, 4 waves (each 32m x 64n, acc[2][4]),
// im2col A staging, register prefetch, generalized K range [kbeg, kend).
// Output: Y (bf16) if Yf==nullptr, else fp32 partial to Yf.
// ---------------------------------------------------------------------------
template <int KS, int PAD>
static __device__ __forceinline__ void mconv128_core(
    const short* __restrict__ Xn, const short* __restrict__ Wr,
    bf16* __restrict__ Y, float* __restrict__ Yf,
    short As[128][72], short Bs[64][72],
    int p0, int o0, int kbeg, int kend)
{
    int t = threadIdx.x, lane = t & 63, wv = t >> 6;
    int l15 = lane & 15, quad = lane >> 4;
    int arow = t >> 1, acol = (t & 1) * 32;   // A: 128 rows x 64 cols, 32 sh/thread
    int brow = t >> 2, bcol = (t & 3) * 16;   // B: 64 rows x 64 cols, 16 sh/thread

    int p  = p0 + arow;
    int hw = p & 1023, hh = hw >> 5, ww = hw & 31;
    size_t ib = ((size_t)(p >> 10)) << 10;

    v4f acc[2][4] = {};
    v8s ra0, ra1, ra2, ra3, rb0, rb1;

    {
        int khkw = kbeg >> 8;
        int kh = khkw / KS, kw = khkw % KS;
        int hi = hh + kh - PAD, wi = ww + kw - PAD;
        int aci = (kbeg & 255) + acol;
        v8s z = {0, 0, 0, 0, 0, 0, 0, 0};
        ra0 = z; ra1 = z; ra2 = z; ra3 = z;
        if ((unsigned)hi < 32u && (unsigned)wi < 32u) {
            const short* sa = &Xn[(ib + (hi << 5) + wi) * 256 + aci];
            ra0 = *(const v8s*)&sa[0];  ra1 = *(const v8s*)&sa[8];
            ra2 = *(const v8s*)&sa[16]; ra3 = *(const v8s*)&sa[24];
        }
        const short* sb = &Wr[((size_t)khkw * 256 + o0 + brow) * 256 + (kbeg & 255) + bcol];
        rb0 = *(const v8s*)&sb[0];
        rb1 = *(const v8s*)&sb[8];
    }

    for (int k0 = kbeg; k0 < kend; k0 += 64) {
        if (k0 != kbeg) __syncthreads();
        *(v8s*)&As[arow][acol]      = ra0;
        *(v8s*)&As[arow][acol + 8]  = ra1;
        *(v8s*)&As[arow][acol + 16] = ra2;
        *(v8s*)&As[arow][acol + 24] = ra3;
        *(v8s*)&Bs[brow][bcol]      = rb0;
        *(v8s*)&Bs[brow][bcol + 8]  = rb1;
        __syncthreads();
        int kn = k0 + 64;
        if (kn < kend) {
            int khkw = kn >> 8;
            int kh = khkw / KS, kw = khkw % KS;
            int hi = hh + kh - PAD, wi = ww + kw - PAD;
            int aci = (kn & 255) + acol;
            v8s z = {0, 0, 0, 0, 0, 0, 0, 0};
            ra0 = z; ra1 = z; ra2 = z; ra3 = z;
            if ((unsigned)hi < 32u && (unsigned)wi < 32u) {
                const short* sa = &Xn[(ib + (hi << 5) + wi) * 256 + aci];
                ra0 = *(const v8s*)&sa[0];  ra1 = *(const v8s*)&sa[8];
                ra2 = *(const v8s*)&sa[16]; ra3 = *(const v8s*)&sa[24];
            }
            const short* sb = &Wr[((size_t)khkw * 256 + o0 + brow) * 256 + (kn & 255) + bcol];
            rb0 = *(const v8s*)&sb[0];
            rb1 = *(const v8s*)&sb[8];
        }
#pragma unroll
        for (int kk = 0; kk < 2; ++kk) {
            v8s a0 = *(const v8s*)&As[wv * 32 + l15][kk * 32 + quad * 8];
            v8s a1 = *(const v8s*)&As[wv * 32 + 16 + l15][kk * 32 + quad * 8];
#pragma unroll
            for (int nt = 0; nt < 4; ++nt) {
                v8s b = *(const v8s*)&Bs[nt * 16 + l15][kk * 32 + quad * 8];
                acc[0][nt] = __builtin_amdgcn_mfma_f32_16x16x32_bf16(a0, b, acc[0][nt], 0, 0, 0);
                acc[1][nt] = __builtin_amdgcn_mfma_f32_16x16x32_bf16(a1, b, acc[1][nt], 0, 0, 0);
            }
        }
    }

#pragma unroll
    for (int mt = 0; mt < 2; ++mt)
#pragma unroll
        for (int nt = 0; nt < 4; ++nt)
#pragma unroll
            for (int r = 0; r < 4; ++r) {
                int pp = p0 + wv * 32 + mt * 16 + quad * 4 + r;
                int oo = o0 + nt * 16 + l15;
                if (Yf) Yf[(size_t)pp * 256 + oo] = acc[mt][nt][r];
                else    Y[(size_t)pp * 256 + oo] = __float2bfloat16(acc[mt][nt][r]);
            }
}

// merged conv, flat grid of 768 wgs (3 blocks/CU):
//   wg <  256: 3x3 full-K (36 steps) -> bf16 qb
//   wg >= 256: 5x5 K-half (50 steps each) -> fp32 partial P0/P1
// Per-CU schedule {36,50,50} steps: balanced tails, 3 blocks resident.
__global__ __launch_bounds__(256) void mconv2(
    const short* __restrict__ Xa, const short* __restrict__ Wa, bf16* __restrict__ Ya,
    const short* __restrict__ Xb, const short* __restrict__ Wb,
    float* __restrict__ P0, float* __restrict__ P1)
{
    __shared__ short As[128][72];
    __shared__ short Bs[64][72];
    int wg = blockIdx.x;
    if (wg < 256) {
        int xy = wg;
        mconv128_core<3, 1>(Xa, Wa, Ya, nullptr, As, Bs,
                            (xy & 63) * 128, (xy >> 6) * 64, 0, 2304);
    } else {
        int j = wg - 256;
        int half = j >> 8, xy = j & 255;
        float* Pf = half ? P1 : P0;
        mconv128_core<5, 2>(Xb, Wb, nullptr, Pf, As, Bs,
                            (xy & 63) * 128, (xy >> 6) * 64,
                            half * 3200, half * 3200 + 3200);
    }
}

// add fp32 partials -> bf16 (kvb = P0 + P1), 4 elems/thread
__global__ __launch_bounds__(256) void addcvt(
    const float* __restrict__ A, const float* __restrict__ B,
    bf16* __restrict__ Y)
{
    int i = (blockIdx.x * 256 + threadIdx.x) * 4;
    float4 a = *(const float4*)&A[i];
    float4 b = *(const float4*)&B[i];
    ushort4 o;
    o.x = f2us(a.x + b.x);
    o.y = f2us(a.y + b.y);
    o.z = f2us(a.z + b.z);
    o.w = f2us(a.w + b.w);
    *(ushort4*)((unsigned short*)Y + i) = o;
}

// ---------------------------------------------------------------------------
// MFMA flash attention core, LDS-staged K/V tiles (verified r15).
// ---------------------------------------------------------------------------
static __device__ __forceinline__ void attn_core(
    const bf16* __restrict__ QK, const bf16* __restrict__ V,
    bf16* __restrict__ Out, int b, int h, int n0,
    short Ps[4][16][72], short Ks[64][72], short Vs[64][72])
{
    int t = threadIdx.x, lane = t & 63, wv = t >> 6;
    int l15 = lane & 15, quad = lane >> 4;
    int srow = t >> 2, scol = (t & 3) * 16;

    const short* qk = (const short*)QK;
    const short* vp = (const short*)V + ((size_t)b * 256 + h * 64) * 1024;

    size_t qrow = ((size_t)b * 1024 + n0 + wv * 16 + l15) * 512 + h * 64;
    v8s qf0 = *(const v8s*)&qk[qrow + quad * 8];
    v8s qf1 = *(const v8s*)&qk[qrow + 32 + quad * 8];

    v4f oacc[4] = {};
    float mi[4], li[4], nmiSC[4];
#pragma unroll
    for (int r = 0; r < 4; ++r) { mi[r] = -1e30f; li[r] = 0.f; nmiSC[r] = 0.f; }
    const float SC = 0.18033688011112042f;  // 0.125 * log2(e)

    const short* kbase = &qk[((size_t)b * 1024 + srow) * 512 + 256 + h * 64 + scol];
    const short* vbase = vp + (size_t)srow * 1024 + scol;

    v8s rk0 = *(const v8s*)&kbase[0], rk1 = *(const v8s*)&kbase[8];
    v8s rv0 = *(const v8s*)&vbase[0], rv1 = *(const v8s*)&vbase[8];

    for (int m0 = 0; m0 < 1024; m0 += 64) {
        if (m0) __syncthreads();
        *(v8s*)&Ks[srow][scol]     = rk0;
        *(v8s*)&Ks[srow][scol + 8] = rk1;
        *(v8s*)&Vs[srow][scol]     = rv0;
        *(v8s*)&Vs[srow][scol + 8] = rv1;
        __syncthreads();
        if (m0 + 64 < 1024) {
            rk0 = *(const v8s*)&kbase[(size_t)(m0 + 64) * 512];
            rk1 = *(const v8s*)&kbase[(size_t)(m0 + 64) * 512 + 8];
            rv0 = *(const v8s*)&vbase[m0 + 64];
            rv1 = *(const v8s*)&vbase[m0 + 72];
        }

        v4f sacc[4];
        __builtin_amdgcn_s_setprio(1);
#pragma unroll
        for (int ct = 0; ct < 4; ++ct) {
            v8s kf0 = *(const v8s*)&Ks[ct * 16 + l15][quad * 8];
            v8s kf1 = *(const v8s*)&Ks[ct * 16 + l15][32 + quad * 8];
            v4f z = {0.f, 0.f, 0.f, 0.f};
            z = __builtin_amdgcn_mfma_f32_16x16x32_bf16(qf0, kf0, z, 0, 0, 0);
            z = __builtin_amdgcn_mfma_f32_16x16x32_bf16(qf1, kf1, z, 0, 0, 0);
            sacc[ct] = z;
        }
        __builtin_amdgcn_s_setprio(0);

        float pr[4];
#pragma unroll
        for (int r = 0; r < 4; ++r)
            pr[r] = fmaxf(fmaxf(sacc[0][r], sacc[1][r]),
                          fmaxf(sacc[2][r], sacc[3][r]));
        bool grow = (pr[0] > mi[0]) | (pr[1] > mi[1]) |
                    (pr[2] > mi[2]) | (pr[3] > mi[3]);
        if (__any(grow)) {
#pragma unroll
            for (int mk = 1; mk <= 8; mk <<= 1)
#pragma unroll
                for (int r = 0; r < 4; ++r)
                    pr[r] = fmaxf(pr[r], __shfl_xor(pr[r], mk));
#pragma unroll
            for (int r = 0; r < 4; ++r) {
                float mn = fmaxf(mi[r], pr[r]);
                float al = exp2f((mi[r] - mn) * SC);
                mi[r] = mn;
                nmiSC[r] = -mn * SC;
                li[r] *= al;
#pragma unroll
                for (int dt = 0; dt < 4; ++dt) oacc[dt][r] *= al;
            }
        }

#pragma unroll
        for (int ct = 0; ct < 4; ++ct)
#pragma unroll
            for (int r = 0; r < 4; ++r) {
                float pvv = exp2f(fmaf(sacc[ct][r], SC, nmiSC[r]));
                li[r] += pvv;
                Ps[wv][quad * 4 + r][ct * 16 + l15] = (short)f2us(pvv);
            }

        v8s pf0 = *(const v8s*)&Ps[wv][l15][quad * 8];
        v8s pf1 = *(const v8s*)&Ps[wv][l15][32 + quad * 8];
        __builtin_amdgcn_s_setprio(1);
#pragma unroll
        for (int dt = 0; dt < 4; ++dt) {
            v8s vf0 = *(const v8s*)&Vs[dt * 16 + l15][quad * 8];
            v8s vf1 = *(const v8s*)&Vs[dt * 16 + l15][32 + quad * 8];
            oacc[dt] = __builtin_amdgcn_mfma_f32_16x16x32_bf16(pf0, vf0, oacc[dt], 0, 0, 0);
            oacc[dt] = __builtin_amdgcn_mfma_f32_16x16x32_bf16(pf1, vf1, oacc[dt], 0, 0, 0);
        }
        __builtin_amdgcn_s_setprio(0);
    }

#pragma unroll
    for (int mk = 1; mk <= 8; mk <<= 1)
#pragma unroll
        for (int r = 0; r < 4; ++r)
            li[r] += __shfl_xor(li[r], mk);

    float linv[4];
#pragma unroll
    for (int r = 0; r < 4; ++r) linv[r] = 1.0f / li[r];
    size_t pb = (size_t)b * 1024 + n0 + wv * 16;
#pragma unroll
    for (int dt = 0; dt < 4; ++dt)
#pragma unroll
        for (int r = 0; r < 4; ++r)
            Out[(pb + quad * 4 + r) * 256 + h * 64 + dt * 16 + l15] =
                __float2bfloat16(oacc[dt][r] * linv[r]);
}

// XCD-swizzled attention: flat 1D grid of NG*16 blocks; all 16 n0-tiles of
// one (b,h[,branch]) group land on one XCD so its 256KB K/V stays L2-hot.
// NG = number of (h, b[, branch]) groups (must be divisible by 8).
template <int NG>
__global__ __launch_bounds__(256) void attn_swz(
    const bf16* __restrict__ QK0, const bf16* __restrict__ V0, bf16* __restrict__ O0,
    const bf16* __restrict__ QK1, const bf16* __restrict__ V1, bf16* __restrict__ O1)
{
    __shared__ short Ps[4][16][72];
    __shared__ short Ks[64][72], Vs[64][72];
    int i = blockIdx.x;
    int xcd = i & 7, idx = i >> 3;
    int g = xcd * (NG / 8) + (idx >> 4);     // group id, bijective remap
    int n0 = (idx & 15) * 64;
    int h = g & 3, zz = g >> 2;
    int b = zz & 7;
    if (zz < 8) attn_core(QK0, V0, O0, b, h, n0, Ps, Ks, Vs);
    else        attn_core(QK1, V1, O1, b, h, n0, Ps, Ks, Vs);
}

// ---------------------------------------------------------------------------
static __device__ __forceinline__ void ln_row(
    const bf16* __restrict__ X, const bf16* __restrict__ g,
    const bf16* __restrict__ be, bf16* __restrict__ Y, size_t p)
{
    int lane = threadIdx.x & 63;
    const ushort4 u = *(const ushort4*)(X + p * 256 + lane * 4);
    float v0 = us2f(u.x), v1 = us2f(u.y), v2 = us2f(u.z), v3 = us2f(u.w);
    float s = v0 + v1 + v2 + v3;
    float ss = v0 * v0 + v1 * v1 + v2 * v2 + v3 * v3;
#pragma unroll
    for (int off = 32; off; off >>= 1) {
        s  += __shfl_xor(s, off);
        ss += __shfl_xor(ss, off);
    }
    float mu   = s * (1.0f / 256.0f);
    float var  = ss * (1.0f / 256.0f) - mu * mu;
    float rstd = rsqrtf(fmaxf(var, 0.0f) + 1e-5f);
    const ushort4 gu = *(const ushort4*)((const unsigned short*)g + lane * 4);
    const ushort4 bu = *(const ushort4*)((const unsigned short*)be + lane * 4);
    ushort4 o;
    o.x = f2us((v0 - mu) * rstd * us2f(gu.x) + us2f(bu.x));
    o.y = f2us((v1 - mu) * rstd * us2f(gu.y) + us2f(bu.y));
    o.z = f2us((v2 - mu) * rstd * us2f(gu.z) + us2f(bu.z));
    o.w = f2us((v3 - mu) * rstd * us2f(gu.w) + us2f(bu.w));
    *(ushort4*)(Y + p * 256 + lane * 4) = o;
}

__global__ __launch_bounds__(256) void ln_nhwc(
    const bf16* __restrict__ X, const bf16* __restrict__ g,
    const bf16* __restrict__ be, bf16* __restrict__ Y)
{
    int wv = threadIdx.x >> 6;
    ln_row(X, g, be, Y, (size_t)blockIdx.x * 4 + wv);
}

// merged LN for both branches: blocks [0,2048) -> set0, [2048,4096) -> set1
__global__ __launch_bounds__(256) void ln_nhwc2(
    const bf16* __restrict__ X0, const bf16* __restrict__ g0,
    const bf16* __restrict__ b0, bf16* __restrict__ Y0,
    const bf16* __restrict__ X1, const bf16* __restrict__ g1,
    const bf16* __restrict__ b1, bf16* __restrict__ Y1)
{
    int wv = threadIdx.x >> 6;
    int sel = blockIdx.x >> 11;
    size_t p = (size_t)(blockIdx.x & 2047) * 4 + wv;
    if (sel == 0) ln_row(X0, g0, b0, Y0, p);
    else          ln_row(X1, g1, b1, Y1, p);
}

// ---------------------------------------------------------------------------
__global__ __launch_bounds__(256) void dwgelu_nhwc(
    const bf16* __restrict__ H, const bf16* __restrict__ Wr,
    bf16* __restrict__ Y)
{
    int idx = blockIdx.x * 256 + threadIdx.x;
    int p = idx >> 7, c8 = (idx & 127) * 8;
    int hw = p & 1023, hh = hw >> 5, ww = hw & 31;
    size_t ib = ((size_t)(p >> 10)) << 10;
    float acc[8] = {};
#pragma unroll
    for (int kh = 0; kh < 3; ++kh)
#pragma unroll
        for (int kw = 0; kw < 3; ++kw) {
            int hi = hh + kh - 1, wi = ww + kw - 1;
            if ((unsigned)hi < 32u && (unsigned)wi < 32u) {
                v8s hv = *(const v8s*)((const short*)H + (ib + (hi << 5) + wi) * 1024 + c8);
                v8s wvv = *(const v8s*)((const short*)Wr + (kh * 3 + kw) * 1024 + c8);
#pragma unroll
                for (int j = 0; j < 8; ++j)
                    acc[j] = fmaf(us2f((unsigned short)wvv[j]),
                                  us2f((unsigned short)hv[j]), acc[j]);
            }
        }
    short ov[8];
#pragma unroll
    for (int j = 0; j < 8; ++j) {
        float x = acc[j];
        ov[j] = (short)f2us(0.5f * x * (1.0f + erff(x * 0.70710678118654752f)));
    }
    v8s o = {ov[0], ov[1], ov[2], ov[3], ov[4], ov[5], ov[6], ov[7]};
    *(v8s*)((short*)Y + (size_t)p * 1024 + c8) = o;
}

// ---------------------------------------------------------------------------
extern "C" void kernel_launch(void* const* d_in, const int* in_sizes, int n_in,
                              void* d_out, int out_size, void* d_ws, size_t ws_size,
                              hipStream_t stream)
{
    static const int  lidx[20] = {4,5,6,7,8,9,10,11,12,13,14,15,16,17,18,19,20,21,22,24};
    static const unsigned lsz[20] = {256,256,256,256,256,256,256,256,256,256,
                                     196608,65536,196608,65536,
                                     65536,65536,65536,65536,262144,262144};
    CvtArgs args;
    unsigned pre[21]; pre[0] = 0;
    for (int i = 0; i < 20; ++i) {
        args.src[i] = d_in[lidx[i]];
        pre[i + 1] = pre[i] + lsz[i];
    }
    for (int i = 0; i < 21; ++i) args.off[i] = pre[i];
    const unsigned ltot = pre[20];

    int*  flag  = (int*)d_ws;
    bf16* canon = (bf16*)d_ws + 128;
    bf16* cn[25];
    for (int i = 0; i < 20; ++i) cn[lidx[i]] = canon + pre[i];

    bf16* Wr3  = canon + ltot;
    bf16* Wr5  = Wr3 + 589824;
    bf16* Wdwr = Wr5 + 1638400;
    const size_t SZ = 2097152;
    bf16* slab = Wdwr + 9216;
    bf16* qb   = slab + 0 * SZ;                    // q_branch -> x (NHWC)
    bf16* kvb  = slab + 1 * SZ;
    bf16* t0   = slab + 2 * SZ;                    // branch-0 scratch
    bf16* q    = slab + 3 * SZ;
    bf16* kv   = slab + 4 * SZ;
    bf16* QKb  = slab + 5 * SZ;                    // 2 slots: [8192][512]
    bf16* Vb   = slab + 7 * SZ;                    // 1 slot: CHW
    bf16* t1   = slab + 8 * SZ;                    // branch-1 scratch
    bf16* QK2  = slab + 9 * SZ;                    // 2 slots (branch 1)
    bf16* V2   = slab + 11 * SZ;                   // 1 slot (branch 1)
    bf16* aopT = slab + 9 * SZ;                    // pre-SA reuse of QK2
    bf16* dopT = slab + 10 * SZ;
    bf16* hb   = slab + 3 * SZ;                    // LeFF: slots 3-6 (q..QKb dead)
    bf16* h2   = slab + 7 * SZ;                    // LeFF: slots 7-10 (Vb..QK2 dead)
    float* P0f = (float*)(slab + 2 * SZ);          // conv partials: slots 2-3
    float* P1f = (float*)(slab + 4 * SZ);          //                slots 4-5
    float* out = (float*)d_out;

    dim3 blk(256);
    auto S = [](const bf16* p) { return (const short*)p; };

    detect_kernel<<<1, 64, 0, stream>>>((const unsigned short*)d_in[4], flag);
    cvt_lin<<<ltot / 256, blk, 0, stream>>>(args, flag, canon);
    tcvt2<<<dim3(16, 4, 16), blk, 0, stream>>>(d_in[0], d_in[1], flag, aopT, dopT);
    repack_all<<<8740, blk, 0, stream>>>(d_in[2], d_in[3], d_in[23], flag, Wr3, Wr5, Wdwr);

    // both branch convs, flat grid of 768 (3x3 full-K + 2x 5x5 K-halves)
    mconv2<<<768, blk, 0, stream>>>(S(aopT), (const short*)Wr3, qb,
                                    S(dopT), (const short*)Wr5, P0f, P1f);
    addcvt<<<2048, blk, 0, stream>>>(P0f, P1f, kvb);

    // merged self-attention pipelines (q branch = set0, kv branch = set1)
    ln_nhwc2<<<4096, blk, 0, stream>>>(qb, cn[4], cn[5], t0,
                                       kvb, cn[6], cn[7], t1);
    GA3 P;
    P.g[0] = GA{S(cn[14]), S(t0), QKb, nullptr, Vb, nullptr, 256, 3, 0};
    P.g[1] = GA{S(cn[16]), S(t1), QK2, nullptr, V2, nullptr, 256, 3, 0};
    P.g[2] = P.g[1];
    mgemm_z<<<dim3(12, 128, 2), blk, 0, stream>>>(P);

    attn_swz<64><<<1024, blk, 0, stream>>>(QKb, Vb, t0, QK2, V2, t1);

    P.g[0] = GA{S(t0), S(cn[15]), qb, nullptr, nullptr, qb, 256, 0, 256};
    P.g[1] = GA{S(t1), S(cn[17]), kvb, nullptr, nullptr, kvb, 256, 0, 256};
    P.g[2] = P.g[1];
    mgemm_z<<<dim3(128, 4, 2), blk, 0, stream>>>(P);

    ln_nhwc2<<<4096, blk, 0, stream>>>(qb, cn[8], cn[9], q,
                                       kvb, cn[10], cn[11], kv);

    // cross attention: 3 projection GEMMs in one launch
    P.g[0] = GA{S(cn[18]), S(q),  QKb, nullptr, nullptr, nullptr, 256, 4, 0};
    P.g[1] = GA{S(cn[19]), S(kv), QKb, nullptr, nullptr, nullptr, 256, 4, 256};
    P.g[2] = GA{S(cn[20]), S(kv), Vb,  nullptr, nullptr, nullptr, 256, 1, 256};
    mgemm_z<<<dim3(4, 128, 3), blk, 0, stream>>>(P);

    attn_swz<32><<<512, blk, 0, stream>>>(QKb, Vb, t0, QKb, Vb, t0);
    mgemm<<<dim3(128, 4), blk, 0, stream>>>(S(t0), S(cn[21]), qb, nullptr, nullptr, qb, 256, 0, 256);

    // LeFF
    ln_nhwc<<<2048, blk, 0, stream>>>(qb, cn[12], cn[13], t0);
    mgemm<<<dim3(128, 16), blk, 0, stream>>>(S(t0), S(cn[22]), hb, nullptr, nullptr, nullptr, 256, 0, 1024);
    dwgelu_nhwc<<<4096, blk, 0, stream>>>(hb, Wdwr, h2);
    mgemm<<<dim3(4, 128), blk, 0, stream>>>(S(cn[24]), S(h2), nullptr, out, nullptr, qb, 1024, 2, 256);
}

// Round 8
// 410.481 us; speedup vs baseline: 1.4122x; 1.0149x over previous
//
#include <hip/hip_runtime.h>
#include <hip/hip_bf16.h>

// DCSA block, round 18: conv occupancy rebalance to 4 blocks/CU.
// r17 post-mortem: split-K validated (80->64.6us, occ 14->23%). Grid 768 =
// 3 blocks/CU with schedule {36,50,50} still leaves the CU 25% under its
// LDS/VGPR occupancy budget and has a 14-step 2-block tail.
// Fix: 5x5 split into THREE K-parts (33/33/34 steps, 64-aligned); 3x3 whole
// (36). Grid 1024 = 4 blocks/CU, per-CU schedule {36,33,33,34} -> all blocks
// retire within 3 steps. addcvt3 sums three fp32 partials. Rest unchanged.

using bf16 = __hip_bfloat16;
typedef short v8s __attribute__((ext_vector_type(8)));
typedef float v4f  __attribute__((ext_vector_type(4)));

static __device__ __forceinline__ float bf2f(bf16 x) { return __bfloat162float(x); }
static __device__ __forceinline__ float us2f(unsigned short u)
{ union { unsigned int i; float f; } x; x.i = ((unsigned)u) << 16; return x.f; }
static __device__ __forceinline__ unsigned short f2us(float f)
{ bf16 h = __float2bfloat16(f); return *(unsigned short*)&h; }
static __device__ __forceinline__ float ldi(const void* p, size_t i, int isbf)
{ return isbf ? bf2f(((const bf16*)p)[i]) : ((const float*)p)[i]; }

// ---------------------------------------------------------------------------
__global__ void detect_kernel(const unsigned short* p, int* flag)
{
    if (threadIdx.x == 0 && blockIdx.x == 0)
        *flag = (p[0] == 0x3F80) ? 1 : 0;
}

// ---------------------------------------------------------------------------
struct CvtArgs { const void* src[20]; unsigned off[21]; };

__global__ __launch_bounds__(256) void cvt_lin(CvtArgs a, const int* __restrict__ flag,
                                               bf16* __restrict__ dst)
{
    unsigned e = blockIdx.x * 256u + threadIdx.x;
    int isbf = *flag;
    int s = 0;
    while (e >= a.off[s + 1]) ++s;
    dst[e] = __float2bfloat16(ldi(a.src[s], e - a.off[s], isbf));
}

// ---------------------------------------------------------------------------
// merged NCHW->NHWC transpose for both feature maps (z<8: aop, z>=8: dop)
__global__ __launch_bounds__(256) void tcvt2(const void* __restrict__ s0,
                                             const void* __restrict__ s1,
                                             const int* __restrict__ flag,
                                             bf16* __restrict__ d0,
                                             bf16* __restrict__ d1)
{
    __shared__ float T[64][65];
    const void* src = (blockIdx.z < 8) ? s0 : s1;
    bf16* dst       = (blockIdx.z < 8) ? d0 : d1;
    int hw0 = blockIdx.x * 64, c0 = blockIdx.y * 64, b = blockIdx.z & 7;
    int t = threadIdx.x, isbf = *flag;
    int c = t >> 2, x16 = (t & 3) * 16;
    size_t sbase = ((size_t)b * 256 + c0 + c) * 1024 + hw0 + x16;
#pragma unroll
    for (int j = 0; j < 16; ++j) T[c][x16 + j] = ldi(src, sbase + j, isbf);
    __syncthreads();
    int hw = t >> 2, c16 = (t & 3) * 16;
    bf16* dp = dst + ((size_t)(b << 10) + hw0 + hw) * 256 + c0 + c16;
#pragma unroll
    for (int j = 0; j < 16; ++j) dp[j] = __float2bfloat16(T[c16 + j][hw]);
}

// ---------------------------------------------------------------------------
// merged weight repack: conv3 (589824) + conv5 (1638400) + dw (9216)
__global__ __launch_bounds__(256) void repack_all(
    const void* __restrict__ W3, const void* __restrict__ W5,
    const void* __restrict__ Wdw, const int* __restrict__ flag,
    bf16* __restrict__ R3, bf16* __restrict__ R5, bf16* __restrict__ Rdw)
{
    int idx = blockIdx.x * 256 + threadIdx.x;
    int isbf = *flag;
    if (idx < 589824) {
        int ci = idx & 255, o = (idx >> 8) & 255, khkw = idx >> 16;
        int kh = khkw / 3, kw = khkw % 3;
        R3[idx] = __float2bfloat16(
            ldi(W3, (((size_t)o * 256 + ci) * 3 + kh) * 3 + kw, isbf));
    } else if (idx < 2228224) {
        int j = idx - 589824;
        int ci = j & 255, o = (j >> 8) & 255, khkw = j >> 16;
        int kh = khkw / 5, kw = khkw % 5;
        R5[j] = __float2bfloat16(
            ldi(W5, (((size_t)o * 256 + ci) * 5 + kh) * 5 + kw, isbf));
    } else {
        int j = idx - 2228224;
        int c = j & 1023, tap = j >> 10;
        Rdw[j] = __float2bfloat16(ldi(Wdw, (size_t)c * 9 + tap, isbf));
    }
}

// ---------------------------------------------------------------------------
// MFMA GEMM core, 64x64 tile, BK=64, 4 waves, register-prefetch pipeline.
// MA:[M][K], MB:[N][K] k-contig.
// modes: 0 NHWC(+R) / 1 CHW / 2 CHW-fp32+R / 3 qkv-split / 4 QK col-offset
// ---------------------------------------------------------------------------
static __device__ __forceinline__ void mgemm_core(
    const short* __restrict__ MA, const short* __restrict__ MB,
    bf16* __restrict__ Yb, float* __restrict__ Yf, bf16* __restrict__ Y2,
    const bf16* __restrict__ R, int K, int mode, int Ochan,
    short As[64][72], short Bs[64][72])
{
    int m0 = blockIdx.x * 64, n0 = blockIdx.y * 64;
    int t = threadIdx.x, lane = t & 63, wv = t >> 6;
    int l15 = lane & 15, quad = lane >> 4;
    int srow = t >> 2, scol = (t & 3) * 16;

    const short* pa = &MA[(size_t)(m0 + srow) * K + scol];
    const short* pb = &MB[(size_t)(n0 + srow) * K + scol];

    v4f acc[4] = {};
    v8s ra0 = *(const v8s*)&pa[0], ra1 = *(const v8s*)&pa[8];
    v8s rb0 = *(const v8s*)&pb[0], rb1 = *(const v8s*)&pb[8];

    for (int k0 = 0; k0 < K; k0 += 64) {
        if (k0) __syncthreads();
        *(v8s*)&As[srow][scol]     = ra0;
        *(v8s*)&As[srow][scol + 8] = ra1;
        *(v8s*)&Bs[srow][scol]     = rb0;
        *(v8s*)&Bs[srow][scol + 8] = rb1;
        __syncthreads();
        if (k0 + 64 < K) {
            ra0 = *(const v8s*)&pa[k0 + 64];
            ra1 = *(const v8s*)&pa[k0 + 72];
            rb0 = *(const v8s*)&pb[k0 + 64];
            rb1 = *(const v8s*)&pb[k0 + 72];
        }
#pragma unroll
        for (int kk = 0; kk < 2; ++kk) {
            v8s a = *(const v8s*)&As[wv * 16 + l15][kk * 32 + quad * 8];
#pragma unroll
            for (int nt = 0; nt < 4; ++nt) {
                v8s b = *(const v8s*)&Bs[nt * 16 + l15][kk * 32 + quad * 8];
                acc[nt] = __builtin_amdgcn_mfma_f32_16x16x32_bf16(a, b, acc[nt], 0, 0, 0);
            }
        }
    }

#pragma unroll
    for (int nt = 0; nt < 4; ++nt)
#pragma unroll
        for (int r = 0; r < 4; ++r) {
            int mm = m0 + wv * 16 + quad * 4 + r;
            int nn = n0 + nt * 16 + l15;
            float v = acc[nt][r];
            if (mode == 0) {
                size_t off = (size_t)mm * Ochan + nn;
                if (R) v += bf2f(R[off]);
                Yb[off] = __float2bfloat16(v);
            } else if (mode == 1) {
                Yb[((size_t)(nn >> 10) * Ochan + mm) * 1024 + (nn & 1023)] =
                    __float2bfloat16(v);
            } else if (mode == 2) {
                Yf[((size_t)(nn >> 10) * Ochan + mm) * 1024 + (nn & 1023)] =
                    v + bf2f(R[(size_t)nn * 256 + mm]);
            } else if (mode == 3) {
                if (mm < 512) Yb[(size_t)nn * 512 + mm] = __float2bfloat16(v);
                else Y2[((size_t)(nn >> 10) * 256 + (mm - 512)) * 1024 + (nn & 1023)] =
                         __float2bfloat16(v);
            } else {
                Yb[(size_t)nn * 512 + Ochan + mm] = __float2bfloat16(v);
            }
        }
}

__global__ __launch_bounds__(256) void mgemm(
    const short* __restrict__ MA, const short* __restrict__ MB,
    bf16* __restrict__ Yb, float* __restrict__ Yf, bf16* __restrict__ Y2,
    const bf16* __restrict__ R, int K, int mode, int Ochan)
{
    __shared__ short As[64][72], Bs[64][72];
    mgemm_core(MA, MB, Yb, Yf, Y2, R, K, mode, Ochan, As, Bs);
}

// z-dispatched merged GEMM (up to 3 independent problems, same x/y grid)
struct GA { const short* A; const short* B; bf16* Yb; float* Yf; bf16* Y2;
            const bf16* R; int K; int mode; int Oc; };
struct GA3 { GA g[3]; };

__global__ __launch_bounds__(256) void mgemm_z(GA3 P)
{
    __shared__ short As[64][72], Bs[64][72];
    const GA& a = P.g[blockIdx.z];
    mgemm_core(a.A, a.B, a.Yb, a.Yf, a.Y2, a.R, a.K, a.mode, a.Oc, As, Bs);
}

// ---------------------------------------------------------------------------
// MFMA conv core, 128m x 64n tile, BK=64, 4 waves (each 32m x 64n, acc[2][4]),
// im2col A staging, register prefetch, generalized K range [kbeg, kend).
// Output: Y (bf16) if Yf==nullptr, else fp32 partial to Yf.
// ---------------------------------------------------------------------------
template <int KS, int PAD>
static __device__ __forceinline__ void mconv128_core(
    const short* __restrict__ Xn, const short* __restrict__ Wr,
    bf16* __restrict__ Y, float* __restrict__ Yf,
    short As[128][72], short Bs[64][72],
    int p0, int o0, int kbeg, int kend)
{
    int t = threadIdx.x, lane = t & 63, wv = t >> 6;
    int l15 = lane & 15, quad = lane >> 4;
    int arow = t >> 1, acol = (t & 1) * 32;   // A: 128 rows x 64 cols, 32 sh/thread
    int brow = t >> 2, bcol = (t & 3) * 16;   // B: 64 rows x 64 cols, 16 sh/thread

    int p  = p0 + arow;
    int hw = p & 1023, hh = hw >> 5, ww = hw & 31;
    size_t ib = ((size_t)(p >> 10)) << 10;

    v4f acc[2][4] = {};
    v8s ra0, ra1, ra2, ra3, rb0, rb1;

    {
        int khkw = kbeg >> 8;
        int kh = khkw / KS, kw = khkw % KS;
        int hi = hh + kh - PAD, wi = ww + kw - PAD;
        int aci = (kbeg & 255) + acol;
        v8s z = {0, 0, 0, 0, 0, 0, 0, 0};
        ra0 = z; ra1 = z; ra2 = z; ra3 = z;
        if ((unsigned)hi < 32u && (unsigned)wi < 32u) {
            const short* sa = &Xn[(ib + (hi << 5) + wi) * 256 + aci];
            ra0 = *(const v8s*)&sa[0];  ra1 = *(const v8s*)&sa[8];
            ra2 = *(const v8s*)&sa[16]; ra3 = *(const v8s*)&sa[24];
        }
        const short* sb = &Wr[((size_t)khkw * 256 + o0 + brow) * 256 + (kbeg & 255) + bcol];
        rb0 = *(const v8s*)&sb[0];
        rb1 = *(const v8s*)&sb[8];
    }

    for (int k0 = kbeg; k0 < kend; k0 += 64) {
        if (k0 != kbeg) __syncthreads();
        *(v8s*)&As[arow][acol]      = ra0;
        *(v8s*)&As[arow][acol + 8]  = ra1;
        *(v8s*)&As[arow][acol + 16] = ra2;
        *(v8s*)&As[arow][acol + 24] = ra3;
        *(v8s*)&Bs[brow][bcol]      = rb0;
        *(v8s*)&Bs[brow][bcol + 8]  = rb1;
        __syncthreads();
        int kn = k0 + 64;
        if (kn < kend) {
            int khkw = kn >> 8;
            int kh = khkw / KS, kw = khkw % KS;
            int hi = hh + kh - PAD, wi = ww + kw - PAD;
            int aci = (kn & 255) + acol;
            v8s z = {0, 0, 0, 0, 0, 0, 0, 0};
            ra0 = z; ra1 = z; ra2 = z; ra3 = z;
            if ((unsigned)hi < 32u && (unsigned)wi < 32u) {
                const short* sa = &Xn[(ib + (hi << 5) + wi) * 256 + aci];
                ra0 = *(const v8s*)&sa[0];  ra1 = *(const v8s*)&sa[8];
                ra2 = *(const v8s*)&sa[16]; ra3 = *(const v8s*)&sa[24];
            }
            const short* sb = &Wr[((size_t)khkw * 256 + o0 + brow) * 256 + (kn & 255) + bcol];
            rb0 = *(const v8s*)&sb[0];
            rb1 = *(const v8s*)&sb[8];
        }
#pragma unroll
        for (int kk = 0; kk < 2; ++kk) {
            v8s a0 = *(const v8s*)&As[wv * 32 + l15][kk * 32 + quad * 8];
            v8s a1 = *(const v8s*)&As[wv * 32 + 16 + l15][kk * 32 + quad * 8];
#pragma unroll
            for (int nt = 0; nt < 4; ++nt) {
                v8s b = *(const v8s*)&Bs[nt * 16 + l15][kk * 32 + quad * 8];
                acc[0][nt] = __builtin_amdgcn_mfma_f32_16x16x32_bf16(a0, b, acc[0][nt], 0, 0, 0);
                acc[1][nt] = __builtin_amdgcn_mfma_f32_16x16x32_bf16(a1, b, acc[1][nt], 0, 0, 0);
            }
        }
    }

#pragma unroll
    for (int mt = 0; mt < 2; ++mt)
#pragma unroll
        for (int nt = 0; nt < 4; ++nt)
#pragma unroll
            for (int r = 0; r < 4; ++r) {
                int pp = p0 + wv * 32 + mt * 16 + quad * 4 + r;
                int oo = o0 + nt * 16 + l15;
                if (Yf) Yf[(size_t)pp * 256 + oo] = acc[mt][nt][r];
                else    Y[(size_t)pp * 256 + oo] = __float2bfloat16(acc[mt][nt][r]);
            }
}

// merged conv, flat grid of 1024 wgs (4 blocks/CU):
//   wg <  256: 3x3 full-K (36 steps) -> bf16 qb
//   wg >= 256: 5x5 K-third (33/33/34 steps) -> fp32 partial P0/P1/P2
// Per-CU schedule {36,33,33,34}: all blocks retire within 3 steps of each
// other, 4 resident blocks for essentially the whole dispatch.
__global__ __launch_bounds__(256) void mconv2(
    const short* __restrict__ Xa, const short* __restrict__ Wa, bf16* __restrict__ Ya,
    const short* __restrict__ Xb, const short* __restrict__ Wb,
    float* __restrict__ P0, float* __restrict__ P1, float* __restrict__ P2)
{
    __shared__ short As[128][72];
    __shared__ short Bs[64][72];
    int wg = blockIdx.x;
    if (wg < 256) {
        mconv128_core<3, 1>(Xa, Wa, Ya, nullptr, As, Bs,
                            (wg & 63) * 128, (wg >> 6) * 64, 0, 2304);
    } else {
        int j = wg - 256;
        int part = j >> 8, xy = j & 255;
        float* Pf = (part == 0) ? P0 : (part == 1) ? P1 : P2;
        int kbeg = part * 2112;
        int kend = (part < 2) ? kbeg + 2112 : 6400;
        mconv128_core<5, 2>(Xb, Wb, nullptr, Pf, As, Bs,
                            (xy & 63) * 128, (xy >> 6) * 64, kbeg, kend);
    }
}

// add three fp32 partials -> bf16 (kvb = P0 + P1 + P2), 4 elems/thread
__global__ __launch_bounds__(256) void addcvt3(
    const float* __restrict__ A, const float* __restrict__ B,
    const float* __restrict__ C, bf16* __restrict__ Y)
{
    int i = (blockIdx.x * 256 + threadIdx.x) * 4;
    float4 a = *(const float4*)&A[i];
    float4 b = *(const float4*)&B[i];
    float4 c = *(const float4*)&C[i];
    ushort4 o;
    o.x = f2us(a.x + b.x + c.x);
    o.y = f2us(a.y + b.y + c.y);
    o.z = f2us(a.z + b.z + c.z);
    o.w = f2us(a.w + b.w + c.w);
    *(ushort4*)((unsigned short*)Y + i) = o;
}

// ---------------------------------------------------------------------------
// MFMA flash attention core, LDS-staged K/V tiles (verified r15).
// ---------------------------------------------------------------------------
static __device__ __forceinline__ void attn_core(
    const bf16* __restrict__ QK, const bf16* __restrict__ V,
    bf16* __restrict__ Out, int b, int h, int n0,
    short Ps[4][16][72], short Ks[64][72], short Vs[64][72])
{
    int t = threadIdx.x, lane = t & 63, wv = t >> 6;
    int l15 = lane & 15, quad = lane >> 4;
    int srow = t >> 2, scol = (t & 3) * 16;

    const short* qk = (const short*)QK;
    const short* vp = (const short*)V + ((size_t)b * 256 + h * 64) * 1024;

    size_t qrow = ((size_t)b * 1024 + n0 + wv * 16 + l15) * 512 + h * 64;
    v8s qf0 = *(const v8s*)&qk[qrow + quad * 8];
    v8s qf1 = *(const v8s*)&qk[qrow + 32 + quad * 8];

    v4f oacc[4] = {};
    float mi[4], li[4], nmiSC[4];
#pragma unroll
    for (int r = 0; r < 4; ++r) { mi[r] = -1e30f; li[r] = 0.f; nmiSC[r] = 0.f; }
    const float SC = 0.18033688011112042f;  // 0.125 * log2(e)

    const short* kbase = &qk[((size_t)b * 1024 + srow) * 512 + 256 + h * 64 + scol];
    const short* vbase = vp + (size_t)srow * 1024 + scol;

    v8s rk0 = *(const v8s*)&kbase[0], rk1 = *(const v8s*)&kbase[8];
    v8s rv0 = *(const v8s*)&vbase[0], rv1 = *(const v8s*)&vbase[8];

    for (int m0 = 0; m0 < 1024; m0 += 64) {
        if (m0) __syncthreads();
        *(v8s*)&Ks[srow][scol]     = rk0;
        *(v8s*)&Ks[srow][scol + 8] = rk1;
        *(v8s*)&Vs[srow][scol]     = rv0;
        *(v8s*)&Vs[srow][scol + 8] = rv1;
        __syncthreads();
        if (m0 + 64 < 1024) {
            rk0 = *(const v8s*)&kbase[(size_t)(m0 + 64) * 512];
            rk1 = *(const v8s*)&kbase[(size_t)(m0 + 64) * 512 + 8];
            rv0 = *(const v8s*)&vbase[m0 + 64];
            rv1 = *(const v8s*)&vbase[m0 + 72];
        }

        v4f sacc[4];
        __builtin_amdgcn_s_setprio(1);
#pragma unroll
        for (int ct = 0; ct < 4; ++ct) {
            v8s kf0 = *(const v8s*)&Ks[ct * 16 + l15][quad * 8];
            v8s kf1 = *(const v8s*)&Ks[ct * 16 + l15][32 + quad * 8];
            v4f z = {0.f, 0.f, 0.f, 0.f};
            z = __builtin_amdgcn_mfma_f32_16x16x32_bf16(qf0, kf0, z, 0, 0, 0);
            z = __builtin_amdgcn_mfma_f32_16x16x32_bf16(qf1, kf1, z, 0, 0, 0);
            sacc[ct] = z;
        }
        __builtin_amdgcn_s_setprio(0);

        float pr[4];
#pragma unroll
        for (int r = 0; r < 4; ++r)
            pr[r] = fmaxf(fmaxf(sacc[0][r], sacc[1][r]),
                          fmaxf(sacc[2][r], sacc[3][r]));
        bool grow = (pr[0] > mi[0]) | (pr[1] > mi[1]) |
                    (pr[2] > mi[2]) | (pr[3] > mi[3]);
        if (__any(grow)) {
#pragma unroll
            for (int mk = 1; mk <= 8; mk <<= 1)
#pragma unroll
                for (int r = 0; r < 4; ++r)
                    pr[r] = fmaxf(pr[r], __shfl_xor(pr[r], mk));
#pragma unroll
            for (int r = 0; r < 4; ++r) {
                float mn = fmaxf(mi[r], pr[r]);
                float al = exp2f((mi[r] - mn) * SC);
                mi[r] = mn;
                nmiSC[r] = -mn * SC;
                li[r] *= al;
#pragma unroll
                for (int dt = 0; dt < 4; ++dt) oacc[dt][r] *= al;
            }
        }

#pragma unroll
        for (int ct = 0; ct < 4; ++ct)
#pragma unroll
            for (int r = 0; r < 4; ++r) {
                float pvv = exp2f(fmaf(sacc[ct][r], SC, nmiSC[r]));
                li[r] += pvv;
                Ps[wv][quad * 4 + r][ct * 16 + l15] = (short)f2us(pvv);
            }

        v8s pf0 = *(const v8s*)&Ps[wv][l15][quad * 8];
        v8s pf1 = *(const v8s*)&Ps[wv][l15][32 + quad * 8];
        __builtin_amdgcn_s_setprio(1);
#pragma unroll
        for (int dt = 0; dt < 4; ++dt) {
            v8s vf0 = *(const v8s*)&Vs[dt * 16 + l15][quad * 8];
            v8s vf1 = *(const v8s*)&Vs[dt * 16 + l15][32 + quad * 8];
            oacc[dt] = __builtin_amdgcn_mfma_f32_16x16x32_bf16(pf0, vf0, oacc[dt], 0, 0, 0);
            oacc[dt] = __builtin_amdgcn_mfma_f32_16x16x32_bf16(pf1, vf1, oacc[dt], 0, 0, 0);
        }
        __builtin_amdgcn_s_setprio(0);
    }

#pragma unroll
    for (int mk = 1; mk <= 8; mk <<= 1)
#pragma unroll
        for (int r = 0; r < 4; ++r)
            li[r] += __shfl_xor(li[r], mk);

    float linv[4];
#pragma unroll
    for (int r = 0; r < 4; ++r) linv[r] = 1.0f / li[r];
    size_t pb = (size_t)b * 1024 + n0 + wv * 16;
#pragma unroll
    for (int dt = 0; dt < 4; ++dt)
#pragma unroll
        for (int r = 0; r < 4; ++r)
            Out[(pb + quad * 4 + r) * 256 + h * 64 + dt * 16 + l15] =
                __float2bfloat16(oacc[dt][r] * linv[r]);
}

// XCD-swizzled attention: flat 1D grid of NG*16 blocks; all 16 n0-tiles of
// one (b,h[,branch]) group land on one XCD so its 256KB K/V stays L2-hot.
// NG = number of (h, b[, branch]) groups (must be divisible by 8).
template <int NG>
__global__ __launch_bounds__(256) void attn_swz(
    const bf16* __restrict__ QK0, const bf16* __restrict__ V0, bf16* __restrict__ O0,
    const bf16* __restrict__ QK1, const bf16* __restrict__ V1, bf16* __restrict__ O1)
{
    __shared__ short Ps[4][16][72];
    __shared__ short Ks[64][72], Vs[64][72];
    int i = blockIdx.x;
    int xcd = i & 7, idx = i >> 3;
    int g = xcd * (NG / 8) + (idx >> 4);     // group id, bijective remap
    int n0 = (idx & 15) * 64;
    int h = g & 3, zz = g >> 2;
    int b = zz & 7;
    if (zz < 8) attn_core(QK0, V0, O0, b, h, n0, Ps, Ks, Vs);
    else        attn_core(QK1, V1, O1, b, h, n0, Ps, Ks, Vs);
}

// ---------------------------------------------------------------------------
static __device__ __forceinline__ void ln_row(
    const bf16* __restrict__ X, const bf16* __restrict__ g,
    const bf16* __restrict__ be, bf16* __restrict__ Y, size_t p)
{
    int lane = threadIdx.x & 63;
    const ushort4 u = *(const ushort4*)(X + p * 256 + lane * 4);
    float v0 = us2f(u.x), v1 = us2f(u.y), v2 = us2f(u.z), v3 = us2f(u.w);
    float s = v0 + v1 + v2 + v3;
    float ss = v0 * v0 + v1 * v1 + v2 * v2 + v3 * v3;
#pragma unroll
    for (int off = 32; off; off >>= 1) {
        s  += __shfl_xor(s, off);
        ss += __shfl_xor(ss, off);
    }
    float mu   = s * (1.0f / 256.0f);
    float var  = ss * (1.0f / 256.0f) - mu * mu;
    float rstd = rsqrtf(fmaxf(var, 0.0f) + 1e-5f);
    const ushort4 gu = *(const ushort4*)((const unsigned short*)g + lane * 4);
    const ushort4 bu = *(const ushort4*)((const unsigned short*)be + lane * 4);
    ushort4 o;
    o.x = f2us((v0 - mu) * rstd * us2f(gu.x) + us2f(bu.x));
    o.y = f2us((v1 - mu) * rstd * us2f(gu.y) + us2f(bu.y));
    o.z = f2us((v2 - mu) * rstd * us2f(gu.z) + us2f(bu.z));
    o.w = f2us((v3 - mu) * rstd * us2f(gu.w) + us2f(bu.w));
    *(ushort4*)(Y + p * 256 + lane * 4) = o;
}

__global__ __launch_bounds__(256) void ln_nhwc(
    const bf16* __restrict__ X, const bf16* __restrict__ g,
    const bf16* __restrict__ be, bf16* __restrict__ Y)
{
    int wv = threadIdx.x >> 6;
    ln_row(X, g, be, Y, (size_t)blockIdx.x * 4 + wv);
}

// merged LN for both branches: blocks [0,2048) -> set0, [2048,4096) -> set1
__global__ __launch_bounds__(256) void ln_nhwc2(
    const bf16* __restrict__ X0, const bf16* __restrict__ g0,
    const bf16* __restrict__ b0, bf16* __restrict__ Y0,
    const bf16* __restrict__ X1, const bf16* __restrict__ g1,
    const bf16* __restrict__ b1, bf16* __restrict__ Y1)
{
    int wv = threadIdx.x >> 6;
    int sel = blockIdx.x >> 11;
    size_t p = (size_t)(blockIdx.x & 2047) * 4 + wv;
    if (sel == 0) ln_row(X0, g0, b0, Y0, p);
    else          ln_row(X1, g1, b1, Y1, p);
}

// ---------------------------------------------------------------------------
__global__ __launch_bounds__(256) void dwgelu_nhwc(
    const bf16* __restrict__ H, const bf16* __restrict__ Wr,
    bf16* __restrict__ Y)
{
    int idx = blockIdx.x * 256 + threadIdx.x;
    int p = idx >> 7, c8 = (idx & 127) * 8;
    int hw = p & 1023, hh = hw >> 5, ww = hw & 31;
    size_t ib = ((size_t)(p >> 10)) << 10;
    float acc[8] = {};
#pragma unroll
    for (int kh = 0; kh < 3; ++kh)
#pragma unroll
        for (int kw = 0; kw < 3; ++kw) {
            int hi = hh + kh - 1, wi = ww + kw - 1;
            if ((unsigned)hi < 32u && (unsigned)wi < 32u) {
                v8s hv = *(const v8s*)((const short*)H + (ib + (hi << 5) + wi) * 1024 + c8);
                v8s wvv = *(const v8s*)((const short*)Wr + (kh * 3 + kw) * 1024 + c8);
#pragma unroll
                for (int j = 0; j < 8; ++j)
                    acc[j] = fmaf(us2f((unsigned short)wvv[j]),
                                  us2f((unsigned short)hv[j]), acc[j]);
            }
        }
    short ov[8];
#pragma unroll
    for (int j = 0; j < 8; ++j) {
        float x = acc[j];
        ov[j] = (short)f2us(0.5f * x * (1.0f + erff(x * 0.70710678118654752f)));
    }
    v8s o = {ov[0], ov[1], ov[2], ov[3], ov[4], ov[5], ov[6], ov[7]};
    *(v8s*)((short*)Y + (size_t)p * 1024 + c8) = o;
}

// ---------------------------------------------------------------------------
extern "C" void kernel_launch(void* const* d_in, const int* in_sizes, int n_in,
                              void* d_out, int out_size, void* d_ws, size_t ws_size,
                              hipStream_t stream)
{
    static const int  lidx[20] = {4,5,6,7,8,9,10,11,12,13,14,15,16,17,18,19,20,21,22,24};
    static const unsigned lsz[20] = {256,256,256,256,256,256,256,256,256,256,
                                     196608,65536,196608,65536,
                                     65536,65536,65536,65536,262144,262144};
    CvtArgs args;
    unsigned pre[21]; pre[0] = 0;
    for (int i = 0; i < 20; ++i) {
        args.src[i] = d_in[lidx[i]];
        pre[i + 1] = pre[i] + lsz[i];
    }
    for (int i = 0; i < 21; ++i) args.off[i] = pre[i];
    const unsigned ltot = pre[20];

    int*  flag  = (int*)d_ws;
    bf16* canon = (bf16*)d_ws + 128;
    bf16* cn[25];
    for (int i = 0; i < 20; ++i) cn[lidx[i]] = canon + pre[i];

    bf16* Wr3  = canon + ltot;
    bf16* Wr5  = Wr3 + 589824;
    bf16* Wdwr = Wr5 + 1638400;
    const size_t SZ = 2097152;
    bf16* slab = Wdwr + 9216;
    bf16* qb   = slab + 0 * SZ;                    // q_branch -> x (NHWC)
    bf16* kvb  = slab + 1 * SZ;
    bf16* t0   = slab + 2 * SZ;                    // branch-0 scratch
    bf16* q    = slab + 3 * SZ;
    bf16* kv   = slab + 4 * SZ;
    bf16* QKb  = slab + 5 * SZ;                    // 2 slots: [8192][512]
    bf16* Vb   = slab + 7 * SZ;                    // 1 slot: CHW
    bf16* t1   = slab + 8 * SZ;                    // branch-1 scratch
    bf16* QK2  = slab + 9 * SZ;                    // 2 slots (branch 1)
    bf16* V2   = slab + 11 * SZ;                   // 1 slot (branch 1)
    bf16* aopT = slab + 9 * SZ;                    // pre-SA reuse of QK2
    bf16* dopT = slab + 10 * SZ;
    bf16* hb   = slab + 3 * SZ;                    // LeFF: slots 3-6 (q..QKb dead)
    bf16* h2   = slab + 7 * SZ;                    // LeFF: slots 7-10 (Vb..QK2 dead)
    float* P0f = (float*)(slab + 2 * SZ);          // conv partials: slots 2-3
    float* P1f = (float*)(slab + 4 * SZ);          //                slots 4-5
    float* P2f = (float*)(slab + 6 * SZ);          //                slots 6-7
    float* out = (float*)d_out;

    dim3 blk(256);
    auto S = [](const bf16* p) { return (const short*)p; };

    detect_kernel<<<1, 64, 0, stream>>>((const unsigned short*)d_in[4], flag);
    cvt_lin<<<ltot / 256, blk, 0, stream>>>(args, flag, canon);
    tcvt2<<<dim3(16, 4, 16), blk, 0, stream>>>(d_in[0], d_in[1], flag, aopT, dopT);
    repack_all<<<8740, blk, 0, stream>>>(d_in[2], d_in[3], d_in[23], flag, Wr3, Wr5, Wdwr);

    // both branch convs, flat grid of 1024 (3x3 full-K + 3x 5x5 K-thirds)
    mconv2<<<1024, blk, 0, stream>>>(S(aopT), (const short*)Wr3, qb,
                                     S(dopT), (const short*)Wr5, P0f, P1f, P2f);
    addcvt3<<<2048, blk, 0, stream>>>(P0f, P1f, P2f, kvb);

    // merged self-attention pipelines (q branch = set0, kv branch = set1)
    ln_nhwc2<<<4096, blk, 0, stream>>>(qb, cn[4], cn[5], t0,
                                       kvb, cn[6], cn[7], t1);
    GA3 P;
    P.g[0] = GA{S(cn[14]), S(t0), QKb, nullptr, Vb, nullptr, 256, 3, 0};
    P.g[1] = GA{S(cn[16]), S(t1), QK2, nullptr, V2, nullptr, 256, 3, 0};
    P.g[2] = P.g[1];
    mgemm_z<<<dim3(12, 128, 2), blk, 0, stream>>>(P);

    attn_swz<64><<<1024, blk, 0, stream>>>(QKb, Vb, t0, QK2, V2, t1);

    P.g[0] = GA{S(t0), S(cn[15]), qb, nullptr, nullptr, qb, 256, 0, 256};
    P.g[1] = GA{S(t1), S(cn[17]), kvb, nullptr, nullptr, kvb, 256, 0, 256};
    P.g[2] = P.g[1];
    mgemm_z<<<dim3(128, 4, 2), blk, 0, stream>>>(P);

    ln_nhwc2<<<4096, blk, 0, stream>>>(qb, cn[8], cn[9], q,
                                       kvb, cn[10], cn[11], kv);

    // cross attention: 3 projection GEMMs in one launch
    P.g[0] = GA{S(cn[18]), S(q),  QKb, nullptr, nullptr, nullptr, 256, 4, 0};
    P.g[1] = GA{S(cn[19]), S(kv), QKb, nullptr, nullptr, nullptr, 256, 4, 256};
    P.g[2] = GA{S(cn[20]), S(kv), Vb,  nullptr, nullptr, nullptr, 256, 1, 256};
    mgemm_z<<<dim3(4, 128, 3), blk, 0, stream>>>(P);

    attn_swz<32><<<512, blk, 0, stream>>>(QKb, Vb, t0, QKb, Vb, t0);
    mgemm<<<dim3(128, 4), blk, 0, stream>>>(S(t0), S(cn[21]), qb, nullptr, nullptr, qb, 256, 0, 256);

    // LeFF
    ln_nhwc<<<2048, blk, 0, stream>>>(qb, cn[12], cn[13], t0);
    mgemm<<<dim3(128, 16), blk, 0, stream>>>(S(t0), S(cn[22]), hb, nullptr, nullptr, nullptr, 256, 0, 1024);
    dwgelu_nhwc<<<4096, blk, 0, stream>>>(hb, Wdwr, h2);
    mgemm<<<dim3(4, 128), blk, 0, stream>>>(S(cn[24]), S(h2), nullptr, out, nullptr, qb, 1024, 2, 256);
}

// Round 9
// 408.579 us; speedup vs baseline: 1.4188x; 1.0047x over previous
//
#include <hip/hip_runtime.h>
#include <hip/hip_bf16.h>

// DCSA block, round 19: conv LDS-bandwidth attack via squarer wave tiles.
// r18 post-mortem: occupancy rose 23->30% as designed but time 64.6->63us ->
// occupancy not the limiter. Arithmetic: 128x64 tile moves 72KB/block-K-step
// through the 128B/clk LDS port (31us floor, 63 measured). FLOP per LDS read
// scales with m*n/(m+n) of the WAVE tile. Fix: 128x128 block, 2x2 waves of
// 64x64 (acc[4][4]; per kk 4 A-frags + 4 B-frags = 8 b128 for 16 MFMA) ->
// 1.5x less LDS traffic per output (new floor ~20us). Grid 512 = 2 blocks/CU
// ({3x3:36, 5x5-third:33} per CU). fp32 partials + addcvt3 unchanged.

using bf16 = __hip_bfloat16;
typedef short v8s __attribute__((ext_vector_type(8)));
typedef float v4f  __attribute__((ext_vector_type(4)));

static __device__ __forceinline__ float bf2f(bf16 x) { return __bfloat162float(x); }
static __device__ __forceinline__ float us2f(unsigned short u)
{ union { unsigned int i; float f; } x; x.i = ((unsigned)u) << 16; return x.f; }
static __device__ __forceinline__ unsigned short f2us(float f)
{ bf16 h = __float2bfloat16(f); return *(unsigned short*)&h; }
static __device__ __forceinline__ float ldi(const void* p, size_t i, int isbf)
{ return isbf ? bf2f(((const bf16*)p)[i]) : ((const float*)p)[i]; }

// ---------------------------------------------------------------------------
__global__ void detect_kernel(const unsigned short* p, int* flag)
{
    if (threadIdx.x == 0 && blockIdx.x == 0)
        *flag = (p[0] == 0x3F80) ? 1 : 0;
}

// ---------------------------------------------------------------------------
struct CvtArgs { const void* src[20]; unsigned off[21]; };

__global__ __launch_bounds__(256) void cvt_lin(CvtArgs a, const int* __restrict__ flag,
                                               bf16* __restrict__ dst)
{
    unsigned e = blockIdx.x * 256u + threadIdx.x;
    int isbf = *flag;
    int s = 0;
    while (e >= a.off[s + 1]) ++s;
    dst[e] = __float2bfloat16(ldi(a.src[s], e - a.off[s], isbf));
}

// ---------------------------------------------------------------------------
// merged NCHW->NHWC transpose for both feature maps (z<8: aop, z>=8: dop)
__global__ __launch_bounds__(256) void tcvt2(const void* __restrict__ s0,
                                             const void* __restrict__ s1,
                                             const int* __restrict__ flag,
                                             bf16* __restrict__ d0,
                                             bf16* __restrict__ d1)
{
    __shared__ float T[64][65];
    const void* src = (blockIdx.z < 8) ? s0 : s1;
    bf16* dst       = (blockIdx.z < 8) ? d0 : d1;
    int hw0 = blockIdx.x * 64, c0 = blockIdx.y * 64, b = blockIdx.z & 7;
    int t = threadIdx.x, isbf = *flag;
    int c = t >> 2, x16 = (t & 3) * 16;
    size_t sbase = ((size_t)b * 256 + c0 + c) * 1024 + hw0 + x16;
#pragma unroll
    for (int j = 0; j < 16; ++j) T[c][x16 + j] = ldi(src, sbase + j, isbf);
    __syncthreads();
    int hw = t >> 2, c16 = (t & 3) * 16;
    bf16* dp = dst + ((size_t)(b << 10) + hw0 + hw) * 256 + c0 + c16;
#pragma unroll
    for (int j = 0; j < 16; ++j) dp[j] = __float2bfloat16(T[c16 + j][hw]);
}

// ---------------------------------------------------------------------------
// merged weight repack: conv3 (589824) + conv5 (1638400) + dw (9216)
__global__ __launch_bounds__(256) void repack_all(
    const void* __restrict__ W3, const void* __restrict__ W5,
    const void* __restrict__ Wdw, const int* __restrict__ flag,
    bf16* __restrict__ R3, bf16* __restrict__ R5, bf16* __restrict__ Rdw)
{
    int idx = blockIdx.x * 256 + threadIdx.x;
    int isbf = *flag;
    if (idx < 589824) {
        int ci = idx & 255, o = (idx >> 8) & 255, khkw = idx >> 16;
        int kh = khkw / 3, kw = khkw % 3;
        R3[idx] = __float2bfloat16(
            ldi(W3, (((size_t)o * 256 + ci) * 3 + kh) * 3 + kw, isbf));
    } else if (idx < 2228224) {
        int j = idx - 589824;
        int ci = j & 255, o = (j >> 8) & 255, khkw = j >> 16;
        int kh = khkw / 5, kw = khkw % 5;
        R5[j] = __float2bfloat16(
            ldi(W5, (((size_t)o * 256 + ci) * 5 + kh) * 5 + kw, isbf));
    } else {
        int j = idx - 2228224;
        int c = j & 1023, tap = j >> 10;
        Rdw[j] = __float2bfloat16(ldi(Wdw, (size_t)c * 9 + tap, isbf));
    }
}

// ---------------------------------------------------------------------------
// MFMA GEMM core, 64x64 tile, BK=64, 4 waves, register-prefetch pipeline.
// MA:[M][K], MB:[N][K] k-contig.
// modes: 0 NHWC(+R) / 1 CHW / 2 CHW-fp32+R / 3 qkv-split / 4 QK col-offset
// ---------------------------------------------------------------------------
static __device__ __forceinline__ void mgemm_core(
    const short* __restrict__ MA, const short* __restrict__ MB,
    bf16* __restrict__ Yb, float* __restrict__ Yf, bf16* __restrict__ Y2,
    const bf16* __restrict__ R, int K, int mode, int Ochan,
    short As[64][72], short Bs[64][72])
{
    int m0 = blockIdx.x * 64, n0 = blockIdx.y * 64;
    int t = threadIdx.x, lane = t & 63, wv = t >> 6;
    int l15 = lane & 15, quad = lane >> 4;
    int srow = t >> 2, scol = (t & 3) * 16;

    const short* pa = &MA[(size_t)(m0 + srow) * K + scol];
    const short* pb = &MB[(size_t)(n0 + srow) * K + scol];

    v4f acc[4] = {};
    v8s ra0 = *(const v8s*)&pa[0], ra1 = *(const v8s*)&pa[8];
    v8s rb0 = *(const v8s*)&pb[0], rb1 = *(const v8s*)&pb[8];

    for (int k0 = 0; k0 < K; k0 += 64) {
        if (k0) __syncthreads();
        *(v8s*)&As[srow][scol]     = ra0;
        *(v8s*)&As[srow][scol + 8] = ra1;
        *(v8s*)&Bs[srow][scol]     = rb0;
        *(v8s*)&Bs[srow][scol + 8] = rb1;
        __syncthreads();
        if (k0 + 64 < K) {
            ra0 = *(const v8s*)&pa[k0 + 64];
            ra1 = *(const v8s*)&pa[k0 + 72];
            rb0 = *(const v8s*)&pb[k0 + 64];
            rb1 = *(const v8s*)&pb[k0 + 72];
        }
#pragma unroll
        for (int kk = 0; kk < 2; ++kk) {
            v8s a = *(const v8s*)&As[wv * 16 + l15][kk * 32 + quad * 8];
#pragma unroll
            for (int nt = 0; nt < 4; ++nt) {
                v8s b = *(const v8s*)&Bs[nt * 16 + l15][kk * 32 + quad * 8];
                acc[nt] = __builtin_amdgcn_mfma_f32_16x16x32_bf16(a, b, acc[nt], 0, 0, 0);
            }
        }
    }

#pragma unroll
    for (int nt = 0; nt < 4; ++nt)
#pragma unroll
        for (int r = 0; r < 4; ++r) {
            int mm = m0 + wv * 16 + quad * 4 + r;
            int nn = n0 + nt * 16 + l15;
            float v = acc[nt][r];
            if (mode == 0) {
                size_t off = (size_t)mm * Ochan + nn;
                if (R) v += bf2f(R[off]);
                Yb[off] = __float2bfloat16(v);
            } else if (mode == 1) {
                Yb[((size_t)(nn >> 10) * Ochan + mm) * 1024 + (nn & 1023)] =
                    __float2bfloat16(v);
            } else if (mode == 2) {
                Yf[((size_t)(nn >> 10) * Ochan + mm) * 1024 + (nn & 1023)] =
                    v + bf2f(R[(size_t)nn * 256 + mm]);
            } else if (mode == 3) {
                if (mm < 512) Yb[(size_t)nn * 512 + mm] = __float2bfloat16(v);
                else Y2[((size_t)(nn >> 10) * 256 + (mm - 512)) * 1024 + (nn & 1023)] =
                         __float2bfloat16(v);
            } else {
                Yb[(size_t)nn * 512 + Ochan + mm] = __float2bfloat16(v);
            }
        }
}

__global__ __launch_bounds__(256) void mgemm(
    const short* __restrict__ MA, const short* __restrict__ MB,
    bf16* __restrict__ Yb, float* __restrict__ Yf, bf16* __restrict__ Y2,
    const bf16* __restrict__ R, int K, int mode, int Ochan)
{
    __shared__ short As[64][72], Bs[64][72];
    mgemm_core(MA, MB, Yb, Yf, Y2, R, K, mode, Ochan, As, Bs);
}

// z-dispatched merged GEMM (up to 3 independent problems, same x/y grid)
struct GA { const short* A; const short* B; bf16* Yb; float* Yf; bf16* Y2;
            const bf16* R; int K; int mode; int Oc; };
struct GA3 { GA g[3]; };

__global__ __launch_bounds__(256) void mgemm_z(GA3 P)
{
    __shared__ short As[64][72], Bs[64][72];
    const GA& a = P.g[blockIdx.z];
    mgemm_core(a.A, a.B, a.Yb, a.Yf, a.Y2, a.R, a.K, a.mode, a.Oc, As, Bs);
}

// ---------------------------------------------------------------------------
// MFMA conv core, 128m x 128n tile, BK=64, 4 waves as 2x2 of 64x64 each
// (acc[4][4]; per kk 4 A-frags + 4 B-frags = 8 b128 feed 16 MFMA -> 1.5x less
// LDS traffic per output than 128x64). im2col A staging, register prefetch,
// generalized K range [kbeg, kend). Output: bf16 Y if Yf==nullptr else fp32.
// ---------------------------------------------------------------------------
template <int KS, int PAD>
static __device__ __forceinline__ void mconv128_core(
    const short* __restrict__ Xn, const short* __restrict__ Wr,
    bf16* __restrict__ Y, float* __restrict__ Yf,
    short As[128][72], short Bs[128][72],
    int p0, int o0, int kbeg, int kend)
{
    int t = threadIdx.x, lane = t & 63, wv = t >> 6;
    int l15 = lane & 15, quad = lane >> 4;
    int wm = wv >> 1, wn = wv & 1;
    int srow = t >> 1, scol = (t & 1) * 32;   // A and B: 128 rows x 64 cols, 32 sh/thread

    int p  = p0 + srow;
    int hw = p & 1023, hh = hw >> 5, ww = hw & 31;
    size_t ib = ((size_t)(p >> 10)) << 10;

    v4f acc[4][4] = {};
    v8s ra[4], rb[4];

    // prefetch K-block at k0 into ra/rb
    auto ldk = [&](int k0) {
        int khkw = k0 >> 8;
        int kh = khkw / KS, kw = khkw % KS;
        int hi = hh + kh - PAD, wi = ww + kw - PAD;
        int aci = (k0 & 255) + scol;
        v8s z = {0, 0, 0, 0, 0, 0, 0, 0};
        ra[0] = z; ra[1] = z; ra[2] = z; ra[3] = z;
        if ((unsigned)hi < 32u && (unsigned)wi < 32u) {
            const short* sa = &Xn[(ib + (hi << 5) + wi) * 256 + aci];
            ra[0] = *(const v8s*)&sa[0];  ra[1] = *(const v8s*)&sa[8];
            ra[2] = *(const v8s*)&sa[16]; ra[3] = *(const v8s*)&sa[24];
        }
        const short* sb = &Wr[((size_t)khkw * 256 + o0 + srow) * 256 + (k0 & 255) + scol];
        rb[0] = *(const v8s*)&sb[0];  rb[1] = *(const v8s*)&sb[8];
        rb[2] = *(const v8s*)&sb[16]; rb[3] = *(const v8s*)&sb[24];
    };

    ldk(kbeg);

    for (int k0 = kbeg; k0 < kend; k0 += 64) {
        if (k0 != kbeg) __syncthreads();
        *(v8s*)&As[srow][scol]      = ra[0];
        *(v8s*)&As[srow][scol + 8]  = ra[1];
        *(v8s*)&As[srow][scol + 16] = ra[2];
        *(v8s*)&As[srow][scol + 24] = ra[3];
        *(v8s*)&Bs[srow][scol]      = rb[0];
        *(v8s*)&Bs[srow][scol + 8]  = rb[1];
        *(v8s*)&Bs[srow][scol + 16] = rb[2];
        *(v8s*)&Bs[srow][scol + 24] = rb[3];
        __syncthreads();
        if (k0 + 64 < kend) ldk(k0 + 64);
#pragma unroll
        for (int kk = 0; kk < 2; ++kk) {
            v8s af[4], bf[4];
#pragma unroll
            for (int i = 0; i < 4; ++i)
                af[i] = *(const v8s*)&As[wm * 64 + i * 16 + l15][kk * 32 + quad * 8];
#pragma unroll
            for (int i = 0; i < 4; ++i)
                bf[i] = *(const v8s*)&Bs[wn * 64 + i * 16 + l15][kk * 32 + quad * 8];
#pragma unroll
            for (int mt = 0; mt < 4; ++mt)
#pragma unroll
                for (int nt = 0; nt < 4; ++nt)
                    acc[mt][nt] = __builtin_amdgcn_mfma_f32_16x16x32_bf16(
                        af[mt], bf[nt], acc[mt][nt], 0, 0, 0);
        }
    }

#pragma unroll
    for (int mt = 0; mt < 4; ++mt)
#pragma unroll
        for (int nt = 0; nt < 4; ++nt)
#pragma unroll
            for (int r = 0; r < 4; ++r) {
                int pp = p0 + wm * 64 + mt * 16 + quad * 4 + r;
                int oo = o0 + wn * 64 + nt * 16 + l15;
                if (Yf) Yf[(size_t)pp * 256 + oo] = acc[mt][nt][r];
                else    Y[(size_t)pp * 256 + oo] = __float2bfloat16(acc[mt][nt][r]);
            }
}

// merged conv, flat grid of 512 wgs (2 blocks/CU, {36,33} step pairs):
//   wg <  128: 3x3 full-K (36 steps) -> bf16 qb           (128x128 tiles)
//   wg >= 128: 5x5 K-third (33/33/34 steps) -> fp32 P0/P1/P2
__global__ __launch_bounds__(256) void mconv2(
    const short* __restrict__ Xa, const short* __restrict__ Wa, bf16* __restrict__ Ya,
    const short* __restrict__ Xb, const short* __restrict__ Wb,
    float* __restrict__ P0, float* __restrict__ P1, float* __restrict__ P2)
{
    __shared__ short As[128][72];
    __shared__ short Bs[128][72];
    int wg = blockIdx.x;
    if (wg < 128) {
        mconv128_core<3, 1>(Xa, Wa, Ya, nullptr, As, Bs,
                            (wg & 63) * 128, (wg >> 6) * 128, 0, 2304);
    } else {
        int j = wg - 128;
        int part = j >> 7, xy = j & 127;
        float* Pf = (part == 0) ? P0 : (part == 1) ? P1 : P2;
        int kbeg = part * 2112;
        int kend = (part < 2) ? kbeg + 2112 : 6400;
        mconv128_core<5, 2>(Xb, Wb, nullptr, Pf, As, Bs,
                            (xy & 63) * 128, (xy >> 6) * 128, kbeg, kend);
    }
}

// add three fp32 partials -> bf16 (kvb = P0 + P1 + P2), 4 elems/thread
__global__ __launch_bounds__(256) void addcvt3(
    const float* __restrict__ A, const float* __restrict__ B,
    const float* __restrict__ C, bf16* __restrict__ Y)
{
    int i = (blockIdx.x * 256 + threadIdx.x) * 4;
    float4 a = *(const float4*)&A[i];
    float4 b = *(const float4*)&B[i];
    float4 c = *(const float4*)&C[i];
    ushort4 o;
    o.x = f2us(a.x + b.x + c.x);
    o.y = f2us(a.y + b.y + c.y);
    o.z = f2us(a.z + b.z + c.z);
    o.w = f2us(a.w + b.w + c.w);
    *(ushort4*)((unsigned short*)Y + i) = o;
}

// ---------------------------------------------------------------------------
// MFMA flash attention core, LDS-staged K/V tiles (verified r15).
// ---------------------------------------------------------------------------
static __device__ __forceinline__ void attn_core(
    const bf16* __restrict__ QK, const bf16* __restrict__ V,
    bf16* __restrict__ Out, int b, int h, int n0,
    short Ps[4][16][72], short Ks[64][72], short Vs[64][72])
{
    int t = threadIdx.x, lane = t & 63, wv = t >> 6;
    int l15 = lane & 15, quad = lane >> 4;
    int srow = t >> 2, scol = (t & 3) * 16;

    const short* qk = (const short*)QK;
    const short* vp = (const short*)V + ((size_t)b * 256 + h * 64) * 1024;

    size_t qrow = ((size_t)b * 1024 + n0 + wv * 16 + l15) * 512 + h * 64;
    v8s qf0 = *(const v8s*)&qk[qrow + quad * 8];
    v8s qf1 = *(const v8s*)&qk[qrow + 32 + quad * 8];

    v4f oacc[4] = {};
    float mi[4], li[4], nmiSC[4];
#pragma unroll
    for (int r = 0; r < 4; ++r) { mi[r] = -1e30f; li[r] = 0.f; nmiSC[r] = 0.f; }
    const float SC = 0.18033688011112042f;  // 0.125 * log2(e)

    const short* kbase = &qk[((size_t)b * 1024 + srow) * 512 + 256 + h * 64 + scol];
    const short* vbase = vp + (size_t)srow * 1024 + scol;

    v8s rk0 = *(const v8s*)&kbase[0], rk1 = *(const v8s*)&kbase[8];
    v8s rv0 = *(const v8s*)&vbase[0], rv1 = *(const v8s*)&vbase[8];

    for (int m0 = 0; m0 < 1024; m0 += 64) {
        if (m0) __syncthreads();
        *(v8s*)&Ks[srow][scol]     = rk0;
        *(v8s*)&Ks[srow][scol + 8] = rk1;
        *(v8s*)&Vs[srow][scol]     = rv0;
        *(v8s*)&Vs[srow][scol + 8] = rv1;
        __syncthreads();
        if (m0 + 64 < 1024) {
            rk0 = *(const v8s*)&kbase[(size_t)(m0 + 64) * 512];
            rk1 = *(const v8s*)&kbase[(size_t)(m0 + 64) * 512 + 8];
            rv0 = *(const v8s*)&vbase[m0 + 64];
            rv1 = *(const v8s*)&vbase[m0 + 72];
        }

        v4f sacc[4];
        __builtin_amdgcn_s_setprio(1);
#pragma unroll
        for (int ct = 0; ct < 4; ++ct) {
            v8s kf0 = *(const v8s*)&Ks[ct * 16 + l15][quad * 8];
            v8s kf1 = *(const v8s*)&Ks[ct * 16 + l15][32 + quad * 8];
            v4f z = {0.f, 0.f, 0.f, 0.f};
            z = __builtin_amdgcn_mfma_f32_16x16x32_bf16(qf0, kf0, z, 0, 0, 0);
            z = __builtin_amdgcn_mfma_f32_16x16x32_bf16(qf1, kf1, z, 0, 0, 0);
            sacc[ct] = z;
        }
        __builtin_amdgcn_s_setprio(0);

        float pr[4];
#pragma unroll
        for (int r = 0; r < 4; ++r)
            pr[r] = fmaxf(fmaxf(sacc[0][r], sacc[1][r]),
                          fmaxf(sacc[2][r], sacc[3][r]));
        bool grow = (pr[0] > mi[0]) | (pr[1] > mi[1]) |
                    (pr[2] > mi[2]) | (pr[3] > mi[3]);
        if (__any(grow)) {
#pragma unroll
            for (int mk = 1; mk <= 8; mk <<= 1)
#pragma unroll
                for (int r = 0; r < 4; ++r)
                    pr[r] = fmaxf(pr[r], __shfl_xor(pr[r], mk));
#pragma unroll
            for (int r = 0; r < 4; ++r) {
                float mn = fmaxf(mi[r], pr[r]);
                float al = exp2f((mi[r] - mn) * SC);
                mi[r] = mn;
                nmiSC[r] = -mn * SC;
                li[r] *= al;
#pragma unroll
                for (int dt = 0; dt < 4; ++dt) oacc[dt][r] *= al;
            }
        }

#pragma unroll
        for (int ct = 0; ct < 4; ++ct)
#pragma unroll
            for (int r = 0; r < 4; ++r) {
                float pvv = exp2f(fmaf(sacc[ct][r], SC, nmiSC[r]));
                li[r] += pvv;
                Ps[wv][quad * 4 + r][ct * 16 + l15] = (short)f2us(pvv);
            }

        v8s pf0 = *(const v8s*)&Ps[wv][l15][quad * 8];
        v8s pf1 = *(const v8s*)&Ps[wv][l15][32 + quad * 8];
        __builtin_amdgcn_s_setprio(1);
#pragma unroll
        for (int dt = 0; dt < 4; ++dt) {
            v8s vf0 = *(const v8s*)&Vs[dt * 16 + l15][quad * 8];
            v8s vf1 = *(const v8s*)&Vs[dt * 16 + l15][32 + quad * 8];
            oacc[dt] = __builtin_amdgcn_mfma_f32_16x16x32_bf16(pf0, vf0, oacc[dt], 0, 0, 0);
            oacc[dt] = __builtin_amdgcn_mfma_f32_16x16x32_bf16(pf1, vf1, oacc[dt], 0, 0, 0);
        }
        __builtin_amdgcn_s_setprio(0);
    }

#pragma unroll
    for (int mk = 1; mk <= 8; mk <<= 1)
#pragma unroll
        for (int r = 0; r < 4; ++r)
            li[r] += __shfl_xor(li[r], mk);

    float linv[4];
#pragma unroll
    for (int r = 0; r < 4; ++r) linv[r] = 1.0f / li[r];
    size_t pb = (size_t)b * 1024 + n0 + wv * 16;
#pragma unroll
    for (int dt = 0; dt < 4; ++dt)
#pragma unroll
        for (int r = 0; r < 4; ++r)
            Out[(pb + quad * 4 + r) * 256 + h * 64 + dt * 16 + l15] =
                __float2bfloat16(oacc[dt][r] * linv[r]);
}

// XCD-swizzled attention: flat 1D grid of NG*16 blocks; all 16 n0-tiles of
// one (b,h[,branch]) group land on one XCD so its 256KB K/V stays L2-hot.
// NG = number of (h, b[, branch]) groups (must be divisible by 8).
template <int NG>
__global__ __launch_bounds__(256) void attn_swz(
    const bf16* __restrict__ QK0, const bf16* __restrict__ V0, bf16* __restrict__ O0,
    const bf16* __restrict__ QK1, const bf16* __restrict__ V1, bf16* __restrict__ O1)
{
    __shared__ short Ps[4][16][72];
    __shared__ short Ks[64][72], Vs[64][72];
    int i = blockIdx.x;
    int xcd = i & 7, idx = i >> 3;
    int g = xcd * (NG / 8) + (idx >> 4);     // group id, bijective remap
    int n0 = (idx & 15) * 64;
    int h = g & 3, zz = g >> 2;
    int b = zz & 7;
    if (zz < 8) attn_core(QK0, V0, O0, b, h, n0, Ps, Ks, Vs);
    else        attn_core(QK1, V1, O1, b, h, n0, Ps, Ks, Vs);
}

// ---------------------------------------------------------------------------
static __device__ __forceinline__ void ln_row(
    const bf16* __restrict__ X, const bf16* __restrict__ g,
    const bf16* __restrict__ be, bf16* __restrict__ Y, size_t p)
{
    int lane = threadIdx.x & 63;
    const ushort4 u = *(const ushort4*)(X + p * 256 + lane * 4);
    float v0 = us2f(u.x), v1 = us2f(u.y), v2 = us2f(u.z), v3 = us2f(u.w);
    float s = v0 + v1 + v2 + v3;
    float ss = v0 * v0 + v1 * v1 + v2 * v2 + v3 * v3;
#pragma unroll
    for (int off = 32; off; off >>= 1) {
        s  += __shfl_xor(s, off);
        ss += __shfl_xor(ss, off);
    }
    float mu   = s * (1.0f / 256.0f);
    float var  = ss * (1.0f / 256.0f) - mu * mu;
    float rstd = rsqrtf(fmaxf(var, 0.0f) + 1e-5f);
    const ushort4 gu = *(const ushort4*)((const unsigned short*)g + lane * 4);
    const ushort4 bu = *(const ushort4*)((const unsigned short*)be + lane * 4);
    ushort4 o;
    o.x = f2us((v0 - mu) * rstd * us2f(gu.x) + us2f(bu.x));
    o.y = f2us((v1 - mu) * rstd * us2f(gu.y) + us2f(bu.y));
    o.z = f2us((v2 - mu) * rstd * us2f(gu.z) + us2f(bu.z));
    o.w = f2us((v3 - mu) * rstd * us2f(gu.w) + us2f(bu.w));
    *(ushort4*)(Y + p * 256 + lane * 4) = o;
}

__global__ __launch_bounds__(256) void ln_nhwc(
    const bf16* __restrict__ X, const bf16* __restrict__ g,
    const bf16* __restrict__ be, bf16* __restrict__ Y)
{
    int wv = threadIdx.x >> 6;
    ln_row(X, g, be, Y, (size_t)blockIdx.x * 4 + wv);
}

// merged LN for both branches: blocks [0,2048) -> set0, [2048,4096) -> set1
__global__ __launch_bounds__(256) void ln_nhwc2(
    const bf16* __restrict__ X0, const bf16* __restrict__ g0,
    const bf16* __restrict__ b0, bf16* __restrict__ Y0,
    const bf16* __restrict__ X1, const bf16* __restrict__ g1,
    const bf16* __restrict__ b1, bf16* __restrict__ Y1)
{
    int wv = threadIdx.x >> 6;
    int sel = blockIdx.x >> 11;
    size_t p = (size_t)(blockIdx.x & 2047) * 4 + wv;
    if (sel == 0) ln_row(X0, g0, b0, Y0, p);
    else          ln_row(X1, g1, b1, Y1, p);
}

// ---------------------------------------------------------------------------
__global__ __launch_bounds__(256) void dwgelu_nhwc(
    const bf16* __restrict__ H, const bf16* __restrict__ Wr,
    bf16* __restrict__ Y)
{
    int idx = blockIdx.x * 256 + threadIdx.x;
    int p = idx >> 7, c8 = (idx & 127) * 8;
    int hw = p & 1023, hh = hw >> 5, ww = hw & 31;
    size_t ib = ((size_t)(p >> 10)) << 10;
    float acc[8] = {};
#pragma unroll
    for (int kh = 0; kh < 3; ++kh)
#pragma unroll
        for (int kw = 0; kw < 3; ++kw) {
            int hi = hh + kh - 1, wi = ww + kw - 1;
            if ((unsigned)hi < 32u && (unsigned)wi < 32u) {
                v8s hv = *(const v8s*)((const short*)H + (ib + (hi << 5) + wi) * 1024 + c8);
                v8s wvv = *(const v8s*)((const short*)Wr + (kh * 3 + kw) * 1024 + c8);
#pragma unroll
                for (int j = 0; j < 8; ++j)
                    acc[j] = fmaf(us2f((unsigned short)wvv[j]),
                                  us2f((unsigned short)hv[j]), acc[j]);
            }
        }
    short ov[8];
#pragma unroll
    for (int j = 0; j < 8; ++j) {
        float x = acc[j];
        ov[j] = (short)f2us(0.5f * x * (1.0f + erff(x * 0.70710678118654752f)));
    }
    v8s o = {ov[0], ov[1], ov[2], ov[3], ov[4], ov[5], ov[6], ov[7]};
    *(v8s*)((short*)Y + (size_t)p * 1024 + c8) = o;
}

// ---------------------------------------------------------------------------
extern "C" void kernel_launch(void* const* d_in, const int* in_sizes, int n_in,
                              void* d_out, int out_size, void* d_ws, size_t ws_size,
                              hipStream_t stream)
{
    static const int  lidx[20] = {4,5,6,7,8,9,10,11,12,13,14,15,16,17,18,19,20,21,22,24};
    static const unsigned lsz[20] = {256,256,256,256,256,256,256,256,256,256,
                                     196608,65536,196608,65536,
                                     65536,65536,65536,65536,262144,262144};
    CvtArgs args;
    unsigned pre[21]; pre[0] = 0;
    for (int i = 0; i < 20; ++i) {
        args.src[i] = d_in[lidx[i]];
        pre[i + 1] = pre[i] + lsz[i];
    }
    for (int i = 0; i < 21; ++i) args.off[i] = pre[i];
    const unsigned ltot = pre[20];

    int*  flag  = (int*)d_ws;
    bf16* canon = (bf16*)d_ws + 128;
    bf16* cn[25];
    for (int i = 0; i < 20; ++i) cn[lidx[i]] = canon + pre[i];

    bf16* Wr3  = canon + ltot;
    bf16* Wr5  = Wr3 + 589824;
    bf16* Wdwr = Wr5 + 1638400;
    const size_t SZ = 2097152;
    bf16* slab = Wdwr + 9216;
    bf16* qb   = slab + 0 * SZ;                    // q_branch -> x (NHWC)
    bf16* kvb  = slab + 1 * SZ;
    bf16* t0   = slab + 2 * SZ;                    // branch-0 scratch
    bf16* q    = slab + 3 * SZ;
    bf16* kv   = slab + 4 * SZ;
    bf16* QKb  = slab + 5 * SZ;                    // 2 slots: [8192][512]
    bf16* Vb   = slab + 7 * SZ;                    // 1 slot: CHW
    bf16* t1   = slab + 8 * SZ;                    // branch-1 scratch
    bf16* QK2  = slab + 9 * SZ;                    // 2 slots (branch 1)
    bf16* V2   = slab + 11 * SZ;                   // 1 slot (branch 1)
    bf16* aopT = slab + 9 * SZ;                    // pre-SA reuse of QK2
    bf16* dopT = slab + 10 * SZ;
    bf16* hb   = slab + 3 * SZ;                    // LeFF: slots 3-6 (q..QKb dead)
    bf16* h2   = slab + 7 * SZ;                    // LeFF: slots 7-10 (Vb..QK2 dead)
    float* P0f = (float*)(slab + 2 * SZ);          // conv partials: slots 2-3
    float* P1f = (float*)(slab + 4 * SZ);          //                slots 4-5
    float* P2f = (float*)(slab + 6 * SZ);          //                slots 6-7
    float* out = (float*)d_out;

    dim3 blk(256);
    auto S = [](const bf16* p) { return (const short*)p; };

    detect_kernel<<<1, 64, 0, stream>>>((const unsigned short*)d_in[4], flag);
    cvt_lin<<<ltot / 256, blk, 0, stream>>>(args, flag, canon);
    tcvt2<<<dim3(16, 4, 16), blk, 0, stream>>>(d_in[0], d_in[1], flag, aopT, dopT);
    repack_all<<<8740, blk, 0, stream>>>(d_in[2], d_in[3], d_in[23], flag, Wr3, Wr5, Wdwr);

    // both branch convs, flat grid of 512 (128x128 tiles; 3x3 full-K + 3x 5x5 K-thirds)
    mconv2<<<512, blk, 0, stream>>>(S(aopT), (const short*)Wr3, qb,
                                    S(dopT), (const short*)Wr5, P0f, P1f, P2f);
    addcvt3<<<2048, blk, 0, stream>>>(P0f, P1f, P2f, kvb);

    // merged self-attention pipelines (q branch = set0, kv branch = set1)
    ln_nhwc2<<<4096, blk, 0, stream>>>(qb, cn[4], cn[5], t0,
                                       kvb, cn[6], cn[7], t1);
    GA3 P;
    P.g[0] = GA{S(cn[14]), S(t0), QKb, nullptr, Vb, nullptr, 256, 3, 0};
    P.g[1] = GA{S(cn[16]), S(t1), QK2, nullptr, V2, nullptr, 256, 3, 0};
    P.g[2] = P.g[1];
    mgemm_z<<<dim3(12, 128, 2), blk, 0, stream>>>(P);

    attn_swz<64><<<1024, blk, 0, stream>>>(QKb, Vb, t0, QK2, V2, t1);

    P.g[0] = GA{S(t0), S(cn[15]), qb, nullptr, nullptr, qb, 256, 0, 256};
    P.g[1] = GA{S(t1), S(cn[17]), kvb, nullptr, nullptr, kvb, 256, 0, 256};
    P.g[2] = P.g[1];
    mgemm_z<<<dim3(128, 4, 2), blk, 0, stream>>>(P);

    ln_nhwc2<<<4096, blk, 0, stream>>>(qb, cn[8], cn[9], q,
                                       kvb, cn[10], cn[11], kv);

    // cross attention: 3 projection GEMMs in one launch
    P.g[0] = GA{S(cn[18]), S(q),  QKb, nullptr, nullptr, nullptr, 256, 4, 0};
    P.g[1] = GA{S(cn[19]), S(kv), QKb, nullptr, nullptr, nullptr, 256, 4, 256};
    P.g[2] = GA{S(cn[20]), S(kv), Vb,  nullptr, nullptr, nullptr, 256, 1, 256};
    mgemm_z<<<dim3(4, 128, 3), blk, 0, stream>>>(P);

    attn_swz<32><<<512, blk, 0, stream>>>(QKb, Vb, t0, QKb, Vb, t0);
    mgemm<<<dim3(128, 4), blk, 0, stream>>>(S(t0), S(cn[21]), qb, nullptr, nullptr, qb, 256, 0, 256);

    // LeFF
    ln_nhwc<<<2048, blk, 0, stream>>>(qb, cn[12], cn[13], t0);
    mgemm<<<dim3(128, 16), blk, 0, stream>>>(S(t0), S(cn[22]), hb, nullptr, nullptr, nullptr, 256, 0, 1024);
    dwgelu_nhwc<<<4096, blk, 0, stream>>>(hb, Wdwr, h2);
    mgemm<<<dim3(4, 128), blk, 0, stream>>>(S(cn[24]), S(h2), nullptr, out, nullptr, qb, 1024, 2, 256);
}